// Round 2
// baseline (10245.576 us; speedup 1.0000x reference)
//
#include <hip/hip_runtime.h>
#include <hip/hip_bf16.h>
#include <math.h>

#define Bsz  64
#define Hd   2048
#define G3   6144
#define MELn 130
#define CHn  12
#define RHYn 3
#define Tn   32

__device__ __forceinline__ float sigf(float x) { return 1.0f / (1.0f + expf(-x)); }

// ---------------------------------------------------------------------------
// prep: transpose z1/z2 -> [128][64], condition -> [T][CH][64], init feedback idx
// ---------------------------------------------------------------------------
__global__ void prep_misc(const float* __restrict__ z1, const float* __restrict__ z2,
                          const float* __restrict__ cond,
                          float* __restrict__ z1t, float* __restrict__ z2t,
                          float* __restrict__ cond_t, int* __restrict__ rhy_idx,
                          int* __restrict__ mel_idx, int* __restrict__ cnts)
{
    int idx = blockIdx.x * 256 + threadIdx.x;
    if (idx < 128 * Bsz) {
        int j = idx >> 6, b = idx & 63;
        z1t[idx] = z1[b * 128 + j];
        z2t[idx] = z2[b * 128 + j];
    }
    if (idx < Tn * CHn * Bsz) {
        int t = idx / (CHn * Bsz);
        int r = idx - t * CHn * Bsz;
        int j = r >> 6, b = r & 63;
        cond_t[idx] = cond[b * (Tn * CHn) + t * CHn + j];
    }
    if (idx < Bsz) { rhy_idx[idx] = RHYn - 1; mel_idx[idx] = MELn - 1; }
    if (idx < 2) cnts[idx] = 0;
}

// ---------------------------------------------------------------------------
// h0 = tanh(z2 @ wi0.T + bi0), h1 = tanh(z1 @ wi1.T + bi1); output [j][b]
// ---------------------------------------------------------------------------
__global__ __launch_bounds__(256) void init_h_k(
    const float* __restrict__ z1t, const float* __restrict__ z2t,
    const float* __restrict__ wi0, const float* __restrict__ bi0,
    const float* __restrict__ wi1, const float* __restrict__ bi1,
    float* __restrict__ h0_out, float* __restrict__ h1_out)
{
    int lane = threadIdx.x & 63, wave = threadIdx.x >> 6;
    int j = blockIdx.x * 4 + wave;
    int which = blockIdx.y;
    const float* zt = which ? z1t : z2t;
    const float* wi = which ? wi1 : wi0;
    const float* bi = which ? bi1 : bi0;
    float* outh = which ? h1_out : h0_out;
    const float4* w4 = (const float4*)(wi + (size_t)j * 128);
    float acc = 0.f;
#pragma unroll 8
    for (int i = 0; i < 32; i++) {
        float4 w = w4[i];
        int k = i * 4;
        acc = fmaf(zt[(k + 0) * 64 + lane], w.x, acc);
        acc = fmaf(zt[(k + 1) * 64 + lane], w.y, acc);
        acc = fmaf(zt[(k + 2) * 64 + lane], w.z, acc);
        acc = fmaf(zt[(k + 3) * 64 + lane], w.w, acc);
    }
    outh[j * 64 + lane] = tanhf(acc + bi[j]);
}

// ---------------------------------------------------------------------------
// step-invariant ih parts (z-terms + bias), layout [row][64]
// ---------------------------------------------------------------------------
__global__ __launch_bounds__(256) void gi_const_k(
    const float* __restrict__ z1t, const float* __restrict__ z2t,
    const float* __restrict__ w_ih0, const float* __restrict__ b_ih0,
    const float* __restrict__ w_ih1, const float* __restrict__ b_ih1,
    float* __restrict__ gi0c, float* __restrict__ gi1c)
{
    int lane = threadIdx.x & 63, wave = threadIdx.x >> 6;
    int row = blockIdx.x * 4 + wave;
    int which = blockIdx.y;
    const float* zt; const float* w; float acc; float* dst;
    if (which == 0) { zt = z2t; w = w_ih0 + (size_t)row * 131 + RHYn;          acc = b_ih0[row]; dst = gi0c; }
    else            { zt = z1t; w = w_ih1 + (size_t)row * 273 + (MELn + RHYn); acc = b_ih1[row]; dst = gi1c; }
#pragma unroll 4
    for (int i = 0; i < 128; i++) acc = fmaf(zt[i * 64 + lane], w[i], acc);
    dst[(size_t)row * 64 + lane] = acc;
}

// ---------------------------------------------------------------------------
// 64x64 tile transpose: in [R][C] -> out [C][Rout] (Rout >= R allows padding)
// ---------------------------------------------------------------------------
__device__ __forceinline__ void transpose_body(
    const float* __restrict__ in, float* __restrict__ out, int R, int C, int Rout,
    int bx, int by, float* tile)
{
    int c0 = bx * 64, r0 = by * 64;
    int t = threadIdx.x;
    int cl = t & 63, rw = t >> 6;
#pragma unroll
    for (int i = 0; i < 16; ++i) {
        int rl = rw + i * 4;
        int r = r0 + rl, c = c0 + cl;
        float v = (r < R && c < C) ? in[(size_t)r * C + c] : 0.f;
        tile[rl * 65 + cl] = v;
    }
    __syncthreads();
#pragma unroll
    for (int i = 0; i < 16; ++i) {
        int c_loc = rw + i * 4;
        int r_loc = cl;
        int oc = c0 + c_loc, orow = r0 + r_loc;
        if (oc < C && orow < R)
            out[(size_t)oc * Rout + orow] = tile[r_loc * 65 + c_loc];
    }
}

__global__ __launch_bounds__(256) void transpose4_k(
    const float* __restrict__ a, const float* __restrict__ b,
    const float* __restrict__ c, const float* __restrict__ d,
    float* __restrict__ oa, float* __restrict__ ob,
    float* __restrict__ oc, float* __restrict__ od)
{
    __shared__ float tile[64 * 65];
    const float* in; float* out;
    switch (blockIdx.z) {
        case 0: in = a; out = oa; break;
        case 1: in = b; out = ob; break;
        case 2: in = c; out = oc; break;
        default: in = d; out = od; break;
    }
    transpose_body(in, out, G3, Hd, G3, blockIdx.x, blockIdx.y, tile);
}

__global__ __launch_bounds__(256) void transpose1_k(
    const float* __restrict__ in, float* __restrict__ out, int R, int C, int Rout)
{
    __shared__ float tile[64 * 65];
    transpose_body(in, out, R, C, Rout, blockIdx.x, blockIdx.y, tile);
}

// ---------------------------------------------------------------------------
// mm4_k: register-tiled k-split GEMM partial, 2 blocks/CU (2 waves/SIMD).
// Block 256 thr, tile 192 rows x 64 batch, thread 12r x 4b (48 fma/k/thread).
// grid (tiles, slots), tiles*slots == 512 -> 2 blocks/CU -> latency hiding.
// Per wave per k: 3 w-dwordx4 + 1 LDS b128; k-slot partition and per-(row,b)
// fma order identical to previous versions -> bit-identical partial sums.
// Fused two-matrix mode: tiles >= splitTile use (WTb, xb); part rows continue.
// ---------------------------------------------------------------------------
__global__ __launch_bounds__(256) void mm4_k(
    const float* __restrict__ WTa, const float* __restrict__ xa,
    const float* __restrict__ WTb, const float* __restrict__ xb,
    float* __restrict__ part, int splitTile, int kc, int partStride)
{
    __shared__ float xs[128 * 64];           // 32 KB: 128 k x 64 b slab
    int tid = threadIdx.x;
    int tile = blockIdx.x, slot = blockIdx.y;
    const float* WT; const float* x; int tLoc;
    if (tile < splitTile) { WT = WTa; x = xa; tLoc = tile; }
    else                  { WT = WTb; x = xb; tLoc = tile - splitTile; }
    int rg = tid & 15, bg = tid >> 4;        // 16 row-groups x 16 b-groups
    int r0 = tLoc * 192 + rg * 12;
    int b0 = bg * 4;
    int k0 = slot * kc;

    float acc[12][4];
#pragma unroll
    for (int i = 0; i < 12; i++)
#pragma unroll
        for (int j = 0; j < 4; j++) acc[i][j] = 0.f;

    int nPhase = kc >> 7;
    for (int ph = 0; ph < nPhase; ++ph) {
        int kp = k0 + ph * 128;
        __syncthreads();
        {
            const float4* src = (const float4*)(x + (size_t)kp * 64);
            float4* dst = (float4*)xs;
#pragma unroll
            for (int i = 0; i < 8; i++) dst[tid + i * 256] = src[tid + i * 256];
        }
        __syncthreads();
        const float* wp = WT + (size_t)kp * G3 + r0;
#pragma unroll 2
        for (int k = 0; k < 128; ++k) {
            float4 xv = *(const float4*)&xs[k * 64 + b0];
            float w[12];
            *(float4*)&w[0] = *(const float4*)(wp);
            *(float4*)&w[4] = *(const float4*)(wp + 4);
            *(float4*)&w[8] = *(const float4*)(wp + 8);
            wp += G3;
#pragma unroll
            for (int i = 0; i < 12; i++) {
                acc[i][0] = fmaf(w[i], xv.x, acc[i][0]);
                acc[i][1] = fmaf(w[i], xv.y, acc[i][1]);
                acc[i][2] = fmaf(w[i], xv.z, acc[i][2]);
                acc[i][3] = fmaf(w[i], xv.w, acc[i][3]);
            }
        }
    }

    size_t base = (size_t)slot * partStride + b0;
    int prow0 = tile * 192 + rg * 12;
#pragma unroll
    for (int i = 0; i < 12; i++)
        *(float4*)&part[base + (size_t)(prow0 + i) * 64] = *(float4*)&acc[i][0];
}

// ---------------------------------------------------------------------------
// rhythm epilogue + fused logits/log_softmax/argmax via last-block pattern.
// 512 blocks; each sums 16 k-slots + gate math -> h'. The last block to
// finish computes the 3-class rhythm output (bit-identical partial order to
// the old rhy_out_k) and resets the counter.
// ---------------------------------------------------------------------------
__global__ __launch_bounds__(256) void rhy_epi2(
    const float* __restrict__ part, const float* __restrict__ gi_c,
    const float* __restrict__ w_ih, const float* __restrict__ b_hh,
    const float* __restrict__ h_in, float* __restrict__ h_out,
    int* __restrict__ fb_idx, const float* __restrict__ wo0,
    const float* __restrict__ bo0, float* __restrict__ rlo_t,
    int* __restrict__ cnt)
{
    int tid = threadIdx.x;
    int b = tid & 63, jw = tid >> 6;
    int j = blockIdx.x * 4 + jw;
    float ar = 0.f, az = 0.f, an = 0.f;
#pragma unroll
    for (int s = 0; s < 16; s++) {
        int sb = s * 393216;
        ar += part[sb + j * 64 + b];
        az += part[sb + (j + 2048) * 64 + b];
        an += part[sb + (j + 4096) * 64 + b];
    }
    int oi = fb_idx[b];
    float gir = gi_c[j * 64 + b]            + w_ih[(size_t)j * 131 + oi];
    float giz = gi_c[(j + 2048) * 64 + b]   + w_ih[(size_t)(j + 2048) * 131 + oi];
    float gin = gi_c[(j + 4096) * 64 + b]   + w_ih[(size_t)(j + 4096) * 131 + oi];
    float rg = sigf(gir + ar + b_hh[j]);
    float ug = sigf(giz + az + b_hh[j + 2048]);
    float ng = tanhf(gin + rg * (an + b_hh[j + 4096]));
    float hp = h_in[j * 64 + b];
    h_out[j * 64 + b] = (1.f - ug) * ng + ug * hp;

    // ---- last-block fused rhythm output ----
    __shared__ int lastf;
    __shared__ float partl[12 * 64];
    __syncthreads();
    __threadfence();
    if (tid == 0) lastf = (atomicAdd(cnt, 1) == 511);
    __syncthreads();
    if (!lastf) return;
    __threadfence();   // acquire: invalidate stale caches before reading h_out

    int lane = tid & 63, chunk = tid >> 6;   // 4 waves = 4 k-chunks of 512
    const float* hc = h_out + chunk * 512 * 64;
#pragma unroll
    for (int c = 0; c < 3; c++) {
        const float* w = wo0 + c * Hd + chunk * 512;
        float acc = 0.f;
#pragma unroll 4
        for (int k = 0; k < 512; k++) acc = fmaf(hc[k * 64 + lane], w[k], acc);
        partl[(c * 4 + chunk) * 64 + lane] = acc;
    }
    __syncthreads();
    if (chunk == 0) {
        float l0 = partl[0 * 64 + lane] + partl[1 * 64 + lane] + partl[2 * 64 + lane] + partl[3 * 64 + lane] + bo0[0];
        float l1 = partl[4 * 64 + lane] + partl[5 * 64 + lane] + partl[6 * 64 + lane] + partl[7 * 64 + lane] + bo0[1];
        float l2 = partl[8 * 64 + lane] + partl[9 * 64 + lane] + partl[10 * 64 + lane] + partl[11 * 64 + lane] + bo0[2];
        int am; float mx;
        if (l0 >= l1 && l0 >= l2) { am = 0; mx = l0; }
        else if (l1 >= l2)        { am = 1; mx = l1; }
        else                      { am = 2; mx = l2; }
        float s = expf(l0 - mx) + expf(l1 - mx) + expf(l2 - mx);
        float ls = logf(s);
        rlo_t[lane * 3 + 0] = l0 - mx - ls;
        rlo_t[lane * 3 + 1] = l1 - mx - ls;
        rlo_t[lane * 3 + 2] = l2 - mx - ls;
        fb_idx[lane] = am;
    }
    __syncthreads();
    if (tid == 0) *cnt = 0;                  // exclusive owner; stream-ordered
}

// ---------------------------------------------------------------------------
// melody GRU1 epilogue: sum 16 slots + one-hot col + rank-15 corrections
// ---------------------------------------------------------------------------
__global__ __launch_bounds__(256) void mel1_epi(
    const float* __restrict__ part, const float* __restrict__ gi_c,
    const float* __restrict__ w_ih, const float* __restrict__ b_hh,
    const float* __restrict__ h_in, float* __restrict__ h_out,
    const int* __restrict__ mel_idx, const float* __restrict__ rlo,
    const float* __restrict__ cdt)
{
    int tid = threadIdx.x;
    int b = tid & 63, jw = tid >> 6;
    int j = blockIdx.x * 4 + jw;
    float ar = 0.f, az = 0.f, an = 0.f;
#pragma unroll
    for (int s = 0; s < 16; s++) {
        int sb = s * 393216;
        ar += part[sb + j * 64 + b];
        az += part[sb + (j + 2048) * 64 + b];
        an += part[sb + (j + 4096) * 64 + b];
    }
    int oi = mel_idx[b];
    float r0 = rlo[b * 3 + 0], r1 = rlo[b * 3 + 1], r2 = rlo[b * 3 + 2];
    float cd[12];
#pragma unroll
    for (int q = 0; q < 12; q++) cd[q] = cdt[q * 64 + b];
    float gi[3];
#pragma unroll
    for (int g = 0; g < 3; g++) {
        int row = j + g * 2048;
        const float* wrow = w_ih + (size_t)row * 273;
        float v = gi_c[row * 64 + b] + wrow[oi];
        v = fmaf(r0, wrow[130], v);
        v = fmaf(r1, wrow[131], v);
        v = fmaf(r2, wrow[132], v);
#pragma unroll
        for (int q = 0; q < 12; q++) v = fmaf(cd[q], wrow[261 + q], v);
        gi[g] = v;
    }
    float rg = sigf(gi[0] + ar + b_hh[j]);
    float ug = sigf(gi[1] + az + b_hh[j + 2048]);
    float ng = tanhf(gi[2] + rg * (an + b_hh[j + 4096]));
    float hp = h_in[j * 64 + b];
    h_out[j * 64 + b] = (1.f - ug) * ng + ug * hp;
}

// ---------------------------------------------------------------------------
// melody GRU2 epilogue: fused rows [0,6144)=gi (ih2 x ha'), [6144,12288)=gh
// ---------------------------------------------------------------------------
__global__ __launch_bounds__(256) void mel2_epi(
    const float* __restrict__ part, const float* __restrict__ b_ih,
    const float* __restrict__ b_hh, const float* __restrict__ hb_in,
    float* __restrict__ hb_out)
{
    int tid = threadIdx.x;
    int b = tid & 63, jw = tid >> 6;
    int j = blockIdx.x * 4 + jw;
    float air = 0.f, aiz = 0.f, ain = 0.f, ahr = 0.f, ahz = 0.f, ahn = 0.f;
#pragma unroll
    for (int s = 0; s < 8; s++) {
        int sb = s * 786432;
        air += part[sb + j * 64 + b];
        aiz += part[sb + (j + 2048) * 64 + b];
        ain += part[sb + (j + 4096) * 64 + b];
        ahr += part[sb + (j + 6144) * 64 + b];
        ahz += part[sb + (j + 8192) * 64 + b];
        ahn += part[sb + (j + 10240) * 64 + b];
    }
    float rg = sigf(air + b_ih[j] + ahr + b_hh[j]);
    float ug = sigf(aiz + b_ih[j + 2048] + ahz + b_hh[j + 2048]);
    float ng = tanhf(ain + b_ih[j + 4096] + rg * (ahn + b_hh[j + 4096]));
    float hp = hb_in[j * 64 + b];
    hb_out[j * 64 + b] = (1.f - ug) * ng + ug * hp;
}

// ---------------------------------------------------------------------------
// melody output: logits GEMM partials (exact mm2 layout, 32 blocks) + fused
// log_softmax/argmax in the last block (reads same 16-slot part layout).
// ---------------------------------------------------------------------------
__global__ __launch_bounds__(256) void mel_out_k(
    const float* __restrict__ WT, const float* __restrict__ x,
    float* __restrict__ part, const float* __restrict__ bo1,
    float* __restrict__ outp, int t, int* __restrict__ mel_idx,
    int* __restrict__ cnt)
{
    __shared__ float xs[128 * 64];
    int tid = threadIdx.x;
    int tile = blockIdx.x, slot = blockIdx.y;
    int rg = tid & 15, bg = tid >> 4;
    int r0 = tile * 128 + rg * 8;
    int b0 = bg * 4;
    int k0 = slot * 128;

    float acc[8][4];
#pragma unroll
    for (int i = 0; i < 8; i++)
#pragma unroll
        for (int j = 0; j < 4; j++) acc[i][j] = 0.f;

    bool fast = (r0 + 7 < MELn);
    {
        __syncthreads();
        {
            const float4* src = (const float4*)(x + (size_t)k0 * 64);
            float4* dst = (float4*)xs;
#pragma unroll
            for (int i = 0; i < 8; i++) dst[tid + i * 256] = src[tid + i * 256];
        }
        __syncthreads();
        if (fast) {
            const float* wp = WT + (size_t)k0 * 132 + r0;
#pragma unroll 4
            for (int k = 0; k < 128; ++k) {
                float4 xv = *(const float4*)&xs[k * 64 + b0];
                float w[8];
                *(float4*)&w[0] = *(const float4*)wp;
                *(float4*)&w[4] = *(const float4*)(wp + 4);
                wp += 132;
#pragma unroll
                for (int i = 0; i < 8; i++) {
                    acc[i][0] = fmaf(w[i], xv.x, acc[i][0]);
                    acc[i][1] = fmaf(w[i], xv.y, acc[i][1]);
                    acc[i][2] = fmaf(w[i], xv.z, acc[i][2]);
                    acc[i][3] = fmaf(w[i], xv.w, acc[i][3]);
                }
            }
        } else {
            for (int k = 0; k < 128; ++k) {
                float4 xv = *(const float4*)&xs[k * 64 + b0];
                const float* wrow = WT + (size_t)(k0 + k) * 132;
                float w[8];
#pragma unroll
                for (int i = 0; i < 8; i++) {
                    int rc = r0 + i; if (rc > MELn - 1) rc = MELn - 1;
                    w[i] = wrow[rc];
                }
#pragma unroll
                for (int i = 0; i < 8; i++) {
                    acc[i][0] = fmaf(w[i], xv.x, acc[i][0]);
                    acc[i][1] = fmaf(w[i], xv.y, acc[i][1]);
                    acc[i][2] = fmaf(w[i], xv.z, acc[i][2]);
                    acc[i][3] = fmaf(w[i], xv.w, acc[i][3]);
                }
            }
        }
    }

    size_t base = (size_t)slot * 8320 + b0;
#pragma unroll
    for (int i = 0; i < 8; i++) {
        int prow = tile * 128 + rg * 8 + i;
        int pc = prow < MELn ? prow : (MELn - 1);
        *(float4*)&part[base + (size_t)pc * 64] = *(float4*)acc[i];
    }

    // ---- last-block fused log_softmax + argmax ----
    __shared__ int lastf;
    __shared__ float vbuf[MELn * 64];
    __shared__ float mxs[64], lss[64];
    __syncthreads();
    __threadfence();
    if (tid == 0) lastf = (atomicAdd(cnt, 1) == 31);
    __syncthreads();
    if (!lastf) return;
    __threadfence();   // acquire

    for (int e = tid; e < MELn * 64; e += 256) {
        int row = e >> 6, b = e & 63;
        float v = bo1[row];
#pragma unroll
        for (int s = 0; s < 16; s++) v += part[s * 8320 + row * 64 + b];
        vbuf[e] = v;
    }
    __syncthreads();
    if (tid < 64) {
        int b = tid;
        float mx = -1e30f; int am = 0;
        for (int r = 0; r < MELn; r++) {
            float v = vbuf[r * 64 + b];
            if (v > mx) { mx = v; am = r; }      // first max (matches argmax)
        }
        float s = 0.f;
        for (int r = 0; r < MELn; r++) s += expf(vbuf[r * 64 + b] - mx);
        mxs[b] = mx; lss[b] = logf(s);
        mel_idx[b] = am;
    }
    __syncthreads();
    for (int e = tid; e < MELn * 64; e += 256) {
        int row = e >> 6, b = e & 63;
        outp[(size_t)b * Tn * MELn + t * MELn + row] = vbuf[e] - mxs[b] - lss[b];
    }
    __syncthreads();
    if (tid == 0) *cnt = 0;
}

// ---------------------------------------------------------------------------
extern "C" void kernel_launch(void* const* d_in, const int* in_sizes, int n_in,
                              void* d_out, int out_size, void* d_ws, size_t ws_size,
                              hipStream_t stream)
{
    (void)in_sizes; (void)n_in; (void)out_size; (void)ws_size;
    const float* z1    = (const float*)d_in[0];
    const float* z2    = (const float*)d_in[1];
    const float* cond  = (const float*)d_in[2];
    const float* w_ih0 = (const float*)d_in[3];
    const float* w_hh0 = (const float*)d_in[4];
    const float* b_ih0 = (const float*)d_in[5];
    const float* b_hh0 = (const float*)d_in[6];
    const float* w_ih1 = (const float*)d_in[7];
    const float* w_hh1 = (const float*)d_in[8];
    const float* b_ih1 = (const float*)d_in[9];
    const float* b_hh1 = (const float*)d_in[10];
    const float* w_ih2 = (const float*)d_in[11];
    const float* w_hh2 = (const float*)d_in[12];
    const float* b_ih2 = (const float*)d_in[13];
    const float* b_hh2 = (const float*)d_in[14];
    const float* wi0   = (const float*)d_in[15];
    const float* bi0   = (const float*)d_in[16];
    const float* wo0   = (const float*)d_in[17];
    const float* bo0   = (const float*)d_in[18];
    const float* wi1   = (const float*)d_in[19];
    const float* bi1   = (const float*)d_in[20];
    const float* wo1   = (const float*)d_in[21];
    const float* bo1   = (const float*)d_in[22];
    float* outp = (float*)d_out;
    float* ws = (float*)d_ws;

    // workspace layout (floats), ~232 MB
    size_t off = 0;
    float* WT0  = ws + off; off += 12582912;   // w_hh0^T [2048][6144]
    float* WT1  = ws + off; off += 12582912;   // w_hh1^T
    float* WTi2 = ws + off; off += 12582912;   // w_ih2^T
    float* WTh2 = ws + off; off += 12582912;   // w_hh2^T
    float* WTo1 = ws + off; off += 270336;     // wo1^T [2048][132] (padded)
    float* part = ws + off; off += 6291456;    // k-split partials (25 MB)
    float* hR[2] = { ws + off, ws + off + 131072 }; off += 262144;
    float* hA[2] = { ws + off, ws + off + 131072 }; off += 262144;
    float* hB[2] = { ws + off, ws + off + 131072 }; off += 262144;
    float* gi0c   = ws + off; off += 393216;
    float* gi1c   = ws + off; off += 393216;
    float* rlo    = ws + off; off += 6144;     // [32][64][3]
    float* cond_t = ws + off; off += 24576;
    float* z1t    = ws + off; off += 8192;
    float* z2t    = ws + off; off += 8192;
    int* rhy_idx  = (int*)(ws + off); off += 64;
    int* mel_idx  = (int*)(ws + off); off += 64;
    int* cnts     = (int*)(ws + off); off += 64;   // [0]=rhy, [1]=mel

    // ---- pre-pass ----
    prep_misc<<<96, 256, 0, stream>>>(z1, z2, cond, z1t, z2t, cond_t, rhy_idx, mel_idx, cnts);
    init_h_k<<<dim3(Hd / 4, 2), 256, 0, stream>>>(z1t, z2t, wi0, bi0, wi1, bi1, hR[0], hA[0]);
    gi_const_k<<<dim3(G3 / 4, 2), 256, 0, stream>>>(z1t, z2t, w_ih0, b_ih0, w_ih1, b_ih1, gi0c, gi1c);
    transpose4_k<<<dim3(32, 96, 4), 256, 0, stream>>>(w_hh0, w_hh1, w_ih2, w_hh2,
                                                      WT0, WT1, WTi2, WTh2);
    transpose1_k<<<dim3(32, 3), 256, 0, stream>>>(wo1, WTo1, MELn, Hd, 132);

    // ---- rhythm decoder ----
    for (int s = 0; s < Tn; s++) {
        const float* h_in = hR[s & 1];
        float* h_out = hR[(s + 1) & 1];
        // 32 tiles(192 rows) x 16 slots(kc=128) = 512 blocks, 2/CU
        mm4_k<<<dim3(32, 16), 256, 0, stream>>>(WT0, h_in, WT0, h_in, part,
                                                32, 128, 393216);
        rhy_epi2<<<512, 256, 0, stream>>>(part, gi0c, w_ih0, b_hh0, h_in, h_out,
                                          rhy_idx, wo0, bo0, rlo + s * 192, cnts + 0);
    }

    // ---- melody decoder ----
    for (int t = 0; t < Tn; t++) {
        const float* ha_in = hA[t & 1];
        float* ha_out = hA[(t + 1) & 1];
        mm4_k<<<dim3(32, 16), 256, 0, stream>>>(WT1, ha_in, WT1, ha_in, part,
                                                32, 128, 393216);
        mel1_epi<<<512, 256, 0, stream>>>(part, gi1c, w_ih1, b_hh1, ha_in, ha_out,
                                          mel_idx, rlo + t * 192, cond_t + t * (CHn * Bsz));
        const float* hb_in = (t == 0) ? (const float*)ha_out : (const float*)hB[t & 1];
        float* hb_out = hB[(t + 1) & 1];
        // fused: tiles 0..31 = WTi2 x ha_out, tiles 32..63 = WTh2 x hb_in
        // 64 tiles x 8 slots(kc=256) = 512 blocks, 2/CU
        mm4_k<<<dim3(64, 8), 256, 0, stream>>>(WTi2, ha_out, WTh2, hb_in, part,
                                               32, 256, 786432);
        mel2_epi<<<512, 256, 0, stream>>>(part, b_ih2, b_hh2, hb_in, hb_out);
        // logits GEMM (32 blocks) + last-block softmax/argmax
        mel_out_k<<<dim3(2, 16), 256, 0, stream>>>(WTo1, hb_out, part, bo1,
                                                   outp, t, mel_idx, cnts + 1);
    }
}

// Round 3
// 7858.158 us; speedup vs baseline: 1.3038x; 1.3038x over previous
//
#include <hip/hip_runtime.h>
#include <hip/hip_bf16.h>
#include <math.h>

#define Bsz  64
#define Hd   2048
#define G3   6144
#define MELn 130
#define CHn  12
#define RHYn 3
#define Tn   32

__device__ __forceinline__ float sigf(float x) { return 1.0f / (1.0f + expf(-x)); }

// ---------------------------------------------------------------------------
// prep: transpose z1/z2 -> [128][64], condition -> [T][CH][64], init feedback idx
// ---------------------------------------------------------------------------
__global__ void prep_misc(const float* __restrict__ z1, const float* __restrict__ z2,
                          const float* __restrict__ cond,
                          float* __restrict__ z1t, float* __restrict__ z2t,
                          float* __restrict__ cond_t, int* __restrict__ rhy_idx,
                          int* __restrict__ mel_idx)
{
    int idx = blockIdx.x * 256 + threadIdx.x;
    if (idx < 128 * Bsz) {
        int j = idx >> 6, b = idx & 63;
        z1t[idx] = z1[b * 128 + j];
        z2t[idx] = z2[b * 128 + j];
    }
    if (idx < Tn * CHn * Bsz) {
        int t = idx / (CHn * Bsz);
        int r = idx - t * CHn * Bsz;
        int j = r >> 6, b = r & 63;
        cond_t[idx] = cond[b * (Tn * CHn) + t * CHn + j];
    }
    if (idx < Bsz) { rhy_idx[idx] = RHYn - 1; mel_idx[idx] = MELn - 1; }
}

// ---------------------------------------------------------------------------
// h0 = tanh(z2 @ wi0.T + bi0), h1 = tanh(z1 @ wi1.T + bi1); output [j][b]
// ---------------------------------------------------------------------------
__global__ __launch_bounds__(256) void init_h_k(
    const float* __restrict__ z1t, const float* __restrict__ z2t,
    const float* __restrict__ wi0, const float* __restrict__ bi0,
    const float* __restrict__ wi1, const float* __restrict__ bi1,
    float* __restrict__ h0_out, float* __restrict__ h1_out)
{
    int lane = threadIdx.x & 63, wave = threadIdx.x >> 6;
    int j = blockIdx.x * 4 + wave;
    int which = blockIdx.y;
    const float* zt = which ? z1t : z2t;
    const float* wi = which ? wi1 : wi0;
    const float* bi = which ? bi1 : bi0;
    float* outh = which ? h1_out : h0_out;
    const float4* w4 = (const float4*)(wi + (size_t)j * 128);
    float acc = 0.f;
#pragma unroll 8
    for (int i = 0; i < 32; i++) {
        float4 w = w4[i];
        int k = i * 4;
        acc = fmaf(zt[(k + 0) * 64 + lane], w.x, acc);
        acc = fmaf(zt[(k + 1) * 64 + lane], w.y, acc);
        acc = fmaf(zt[(k + 2) * 64 + lane], w.z, acc);
        acc = fmaf(zt[(k + 3) * 64 + lane], w.w, acc);
    }
    outh[j * 64 + lane] = tanhf(acc + bi[j]);
}

// ---------------------------------------------------------------------------
// step-invariant ih parts (z-terms + bias), layout [row][64]
// ---------------------------------------------------------------------------
__global__ __launch_bounds__(256) void gi_const_k(
    const float* __restrict__ z1t, const float* __restrict__ z2t,
    const float* __restrict__ w_ih0, const float* __restrict__ b_ih0,
    const float* __restrict__ w_ih1, const float* __restrict__ b_ih1,
    float* __restrict__ gi0c, float* __restrict__ gi1c)
{
    int lane = threadIdx.x & 63, wave = threadIdx.x >> 6;
    int row = blockIdx.x * 4 + wave;
    int which = blockIdx.y;
    const float* zt; const float* w; float acc; float* dst;
    if (which == 0) { zt = z2t; w = w_ih0 + (size_t)row * 131 + RHYn;          acc = b_ih0[row]; dst = gi0c; }
    else            { zt = z1t; w = w_ih1 + (size_t)row * 273 + (MELn + RHYn); acc = b_ih1[row]; dst = gi1c; }
#pragma unroll 4
    for (int i = 0; i < 128; i++) acc = fmaf(zt[i * 64 + lane], w[i], acc);
    dst[(size_t)row * 64 + lane] = acc;
}

// ---------------------------------------------------------------------------
// 64x64 tile transpose: in [R][C] -> out [C][Rout] (Rout >= R allows padding)
// ---------------------------------------------------------------------------
__device__ __forceinline__ void transpose_body(
    const float* __restrict__ in, float* __restrict__ out, int R, int C, int Rout,
    int bx, int by, float* tile)
{
    int c0 = bx * 64, r0 = by * 64;
    int t = threadIdx.x;
    int cl = t & 63, rw = t >> 6;
#pragma unroll
    for (int i = 0; i < 16; ++i) {
        int rl = rw + i * 4;
        int r = r0 + rl, c = c0 + cl;
        float v = (r < R && c < C) ? in[(size_t)r * C + c] : 0.f;
        tile[rl * 65 + cl] = v;
    }
    __syncthreads();
#pragma unroll
    for (int i = 0; i < 16; ++i) {
        int c_loc = rw + i * 4;
        int r_loc = cl;
        int oc = c0 + c_loc, orow = r0 + r_loc;
        if (oc < C && orow < R)
            out[(size_t)oc * Rout + orow] = tile[r_loc * 65 + c_loc];
    }
}

__global__ __launch_bounds__(256) void transpose4_k(
    const float* __restrict__ a, const float* __restrict__ b,
    const float* __restrict__ c, const float* __restrict__ d,
    float* __restrict__ oa, float* __restrict__ ob,
    float* __restrict__ oc, float* __restrict__ od)
{
    __shared__ float tile[64 * 65];
    const float* in; float* out;
    switch (blockIdx.z) {
        case 0: in = a; out = oa; break;
        case 1: in = b; out = ob; break;
        case 2: in = c; out = oc; break;
        default: in = d; out = od; break;
    }
    transpose_body(in, out, G3, Hd, G3, blockIdx.x, blockIdx.y, tile);
}

__global__ __launch_bounds__(256) void transpose1_k(
    const float* __restrict__ in, float* __restrict__ out, int R, int C, int Rout)
{
    __shared__ float tile[64 * 65];
    transpose_body(in, out, R, C, Rout, blockIdx.x, blockIdx.y, tile);
}

// ---------------------------------------------------------------------------
// mm4_k: register-tiled k-split GEMM partial, 2 blocks/CU.
// Block 256 thr, tile 192 rows x 64 batch, thread 12r x 4b.
// grid (tiles, slots), tiles*slots == 512. Partial layout & summation order
// bit-identical to earlier versions.
// ---------------------------------------------------------------------------
__global__ __launch_bounds__(256) void mm4_k(
    const float* __restrict__ WTa, const float* __restrict__ xa,
    const float* __restrict__ WTb, const float* __restrict__ xb,
    float* __restrict__ part, int splitTile, int kc, int partStride)
{
    __shared__ float xs[128 * 64];           // 32 KB: 128 k x 64 b slab
    int tid = threadIdx.x;
    int tile = blockIdx.x, slot = blockIdx.y;
    const float* WT; const float* x; int tLoc;
    if (tile < splitTile) { WT = WTa; x = xa; tLoc = tile; }
    else                  { WT = WTb; x = xb; tLoc = tile - splitTile; }
    int rg = tid & 15, bg = tid >> 4;        // 16 row-groups x 16 b-groups
    int r0 = tLoc * 192 + rg * 12;
    int b0 = bg * 4;
    int k0 = slot * kc;

    float acc[12][4];
#pragma unroll
    for (int i = 0; i < 12; i++)
#pragma unroll
        for (int j = 0; j < 4; j++) acc[i][j] = 0.f;

    int nPhase = kc >> 7;
    for (int ph = 0; ph < nPhase; ++ph) {
        int kp = k0 + ph * 128;
        __syncthreads();
        {
            const float4* src = (const float4*)(x + (size_t)kp * 64);
            float4* dst = (float4*)xs;
#pragma unroll
            for (int i = 0; i < 8; i++) dst[tid + i * 256] = src[tid + i * 256];
        }
        __syncthreads();
        const float* wp = WT + (size_t)kp * G3 + r0;
#pragma unroll 2
        for (int k = 0; k < 128; ++k) {
            float4 xv = *(const float4*)&xs[k * 64 + b0];
            float w[12];
            *(float4*)&w[0] = *(const float4*)(wp);
            *(float4*)&w[4] = *(const float4*)(wp + 4);
            *(float4*)&w[8] = *(const float4*)(wp + 8);
            wp += G3;
#pragma unroll
            for (int i = 0; i < 12; i++) {
                acc[i][0] = fmaf(w[i], xv.x, acc[i][0]);
                acc[i][1] = fmaf(w[i], xv.y, acc[i][1]);
                acc[i][2] = fmaf(w[i], xv.z, acc[i][2]);
                acc[i][3] = fmaf(w[i], xv.w, acc[i][3]);
            }
        }
    }

    size_t base = (size_t)slot * partStride + b0;
    int prow0 = tile * 192 + rg * 12;
#pragma unroll
    for (int i = 0; i < 12; i++)
        *(float4*)&part[base + (size_t)(prow0 + i) * 64] = *(float4*)&acc[i][0];
}

// ---------------------------------------------------------------------------
// rhythm epilogue, phase-split:
//  phase 1: wave = slot-quarter; each wave-instr loads a contiguous 1 KB
//           (4 j-rows x 64 b) -> 4x fewer, perfectly-coalesced requests.
//  phase 2: barrier; exact old per-thread gate math from LDS wave-partials.
// ---------------------------------------------------------------------------
__global__ __launch_bounds__(256) void rhy_epi(
    const float* __restrict__ part, const float* __restrict__ gi_c,
    const float* __restrict__ w_ih, const float* __restrict__ b_hh,
    const float* __restrict__ h_in, float* __restrict__ h_out,
    const int* __restrict__ fb_idx)
{
    __shared__ float red[48 * 68];           // rows [(wv*4+jj)*3+g], stride 68
    int tid = threadIdx.x;
    int wv = tid >> 6, lane = tid & 63;
    int jj = lane >> 4, bq = lane & 15;
    int jbase = blockIdx.x * 4;

    float s0[4], s1[4], s2[4];
#pragma unroll
    for (int q = 0; q < 4; q++) { s0[q] = 0.f; s1[q] = 0.f; s2[q] = 0.f; }
#pragma unroll
    for (int ss = 0; ss < 4; ss++) {
        const float* p = part + (size_t)(wv * 4 + ss) * 393216
                       + (size_t)(jbase + jj) * 64 + bq * 4;
        float4 v0 = *(const float4*)(p);
        float4 v1 = *(const float4*)(p + 2048 * 64);
        float4 v2 = *(const float4*)(p + 4096 * 64);
        s0[0] += v0.x; s0[1] += v0.y; s0[2] += v0.z; s0[3] += v0.w;
        s1[0] += v1.x; s1[1] += v1.y; s1[2] += v1.z; s1[3] += v1.w;
        s2[0] += v2.x; s2[1] += v2.y; s2[2] += v2.z; s2[3] += v2.w;
    }
    int rbase = (wv * 4 + jj) * 3;
    *(float4*)&red[(rbase + 0) * 68 + bq * 4] = make_float4(s0[0], s0[1], s0[2], s0[3]);
    *(float4*)&red[(rbase + 1) * 68 + bq * 4] = make_float4(s1[0], s1[1], s1[2], s1[3]);
    *(float4*)&red[(rbase + 2) * 68 + bq * 4] = make_float4(s2[0], s2[1], s2[2], s2[3]);
    __syncthreads();

    int b = lane, jw = wv;
    int j = jbase + jw;
    float ar = 0.f, az = 0.f, an = 0.f;
#pragma unroll
    for (int ww = 0; ww < 4; ww++) {
        int rb = (ww * 4 + jw) * 3;
        ar += red[(rb + 0) * 68 + b];
        az += red[(rb + 1) * 68 + b];
        an += red[(rb + 2) * 68 + b];
    }
    int oi = fb_idx[b];
    float gir = gi_c[j * 64 + b]            + w_ih[(size_t)j * 131 + oi];
    float giz = gi_c[(j + 2048) * 64 + b]   + w_ih[(size_t)(j + 2048) * 131 + oi];
    float gin = gi_c[(j + 4096) * 64 + b]   + w_ih[(size_t)(j + 4096) * 131 + oi];
    float rg = sigf(gir + ar + b_hh[j]);
    float ug = sigf(giz + az + b_hh[j + 2048]);
    float ng = tanhf(gin + rg * (an + b_hh[j + 4096]));
    float hp = h_in[j * 64 + b];
    h_out[j * 64 + b] = (1.f - ug) * ng + ug * hp;
}

// ---------------------------------------------------------------------------
// fused rhythm logits (3 classes) + log_softmax + argmax; 1 block, 768 thr
// ---------------------------------------------------------------------------
__global__ __launch_bounds__(768) void rhy_out_k(
    const float* __restrict__ h, const float* __restrict__ wo0,
    const float* __restrict__ bo0, float* __restrict__ rlo_t, int* __restrict__ rhy_idx)
{
    __shared__ float partl[12 * 64];
    int tid = threadIdx.x, lane = tid & 63, wave = tid >> 6;
    int c = wave >> 2, chunk = wave & 3;
    const float* w = wo0 + c * Hd + chunk * 512;
    const float* hc = h + chunk * 512 * 64;
    float acc = 0.f;
#pragma unroll 4
    for (int k = 0; k < 512; k++) acc = fmaf(hc[k * 64 + lane], w[k], acc);
    partl[wave * 64 + lane] = acc;
    __syncthreads();
    if (wave == 0) {
        float l0 = partl[0 * 64 + lane] + partl[1 * 64 + lane] + partl[2 * 64 + lane] + partl[3 * 64 + lane] + bo0[0];
        float l1 = partl[4 * 64 + lane] + partl[5 * 64 + lane] + partl[6 * 64 + lane] + partl[7 * 64 + lane] + bo0[1];
        float l2 = partl[8 * 64 + lane] + partl[9 * 64 + lane] + partl[10 * 64 + lane] + partl[11 * 64 + lane] + bo0[2];
        int am; float mx;
        if (l0 >= l1 && l0 >= l2) { am = 0; mx = l0; }
        else if (l1 >= l2)        { am = 1; mx = l1; }
        else                      { am = 2; mx = l2; }
        float s = expf(l0 - mx) + expf(l1 - mx) + expf(l2 - mx);
        float ls = logf(s);
        rlo_t[lane * 3 + 0] = l0 - mx - ls;
        rlo_t[lane * 3 + 1] = l1 - mx - ls;
        rlo_t[lane * 3 + 2] = l2 - mx - ls;
        rhy_idx[lane] = am;
    }
}

// ---------------------------------------------------------------------------
// melody GRU1 epilogue, phase-split reduce + rank-15 corrections
// ---------------------------------------------------------------------------
__global__ __launch_bounds__(256) void mel1_epi(
    const float* __restrict__ part, const float* __restrict__ gi_c,
    const float* __restrict__ w_ih, const float* __restrict__ b_hh,
    const float* __restrict__ h_in, float* __restrict__ h_out,
    const int* __restrict__ mel_idx, const float* __restrict__ rlo,
    const float* __restrict__ cdt)
{
    __shared__ float red[48 * 68];
    int tid = threadIdx.x;
    int wv = tid >> 6, lane = tid & 63;
    int jj = lane >> 4, bq = lane & 15;
    int jbase = blockIdx.x * 4;

    float s0[4], s1[4], s2[4];
#pragma unroll
    for (int q = 0; q < 4; q++) { s0[q] = 0.f; s1[q] = 0.f; s2[q] = 0.f; }
#pragma unroll
    for (int ss = 0; ss < 4; ss++) {
        const float* p = part + (size_t)(wv * 4 + ss) * 393216
                       + (size_t)(jbase + jj) * 64 + bq * 4;
        float4 v0 = *(const float4*)(p);
        float4 v1 = *(const float4*)(p + 2048 * 64);
        float4 v2 = *(const float4*)(p + 4096 * 64);
        s0[0] += v0.x; s0[1] += v0.y; s0[2] += v0.z; s0[3] += v0.w;
        s1[0] += v1.x; s1[1] += v1.y; s1[2] += v1.z; s1[3] += v1.w;
        s2[0] += v2.x; s2[1] += v2.y; s2[2] += v2.z; s2[3] += v2.w;
    }
    int rbase = (wv * 4 + jj) * 3;
    *(float4*)&red[(rbase + 0) * 68 + bq * 4] = make_float4(s0[0], s0[1], s0[2], s0[3]);
    *(float4*)&red[(rbase + 1) * 68 + bq * 4] = make_float4(s1[0], s1[1], s1[2], s1[3]);
    *(float4*)&red[(rbase + 2) * 68 + bq * 4] = make_float4(s2[0], s2[1], s2[2], s2[3]);
    __syncthreads();

    int b = lane, jw = wv;
    int j = jbase + jw;
    float ar = 0.f, az = 0.f, an = 0.f;
#pragma unroll
    for (int ww = 0; ww < 4; ww++) {
        int rb = (ww * 4 + jw) * 3;
        ar += red[(rb + 0) * 68 + b];
        az += red[(rb + 1) * 68 + b];
        an += red[(rb + 2) * 68 + b];
    }
    int oi = mel_idx[b];
    float r0 = rlo[b * 3 + 0], r1 = rlo[b * 3 + 1], r2 = rlo[b * 3 + 2];
    float cd[12];
#pragma unroll
    for (int q = 0; q < 12; q++) cd[q] = cdt[q * 64 + b];
    float gi[3];
#pragma unroll
    for (int g = 0; g < 3; g++) {
        int row = j + g * 2048;
        const float* wrow = w_ih + (size_t)row * 273;
        float v = gi_c[row * 64 + b] + wrow[oi];
        v = fmaf(r0, wrow[130], v);
        v = fmaf(r1, wrow[131], v);
        v = fmaf(r2, wrow[132], v);
#pragma unroll
        for (int q = 0; q < 12; q++) v = fmaf(cd[q], wrow[261 + q], v);
        gi[g] = v;
    }
    float rg = sigf(gi[0] + ar + b_hh[j]);
    float ug = sigf(gi[1] + az + b_hh[j + 2048]);
    float ng = tanhf(gi[2] + rg * (an + b_hh[j + 4096]));
    float hp = h_in[j * 64 + b];
    h_out[j * 64 + b] = (1.f - ug) * ng + ug * hp;
}

// ---------------------------------------------------------------------------
// melody GRU2 epilogue, phase-split: 8 slots x 6 gate-rows
// ---------------------------------------------------------------------------
__global__ __launch_bounds__(256) void mel2_epi(
    const float* __restrict__ part, const float* __restrict__ b_ih,
    const float* __restrict__ b_hh, const float* __restrict__ hb_in,
    float* __restrict__ hb_out)
{
    __shared__ float red[96 * 68];           // 26 KB
    int tid = threadIdx.x;
    int wv = tid >> 6, lane = tid & 63;
    int jj = lane >> 4, bq = lane & 15;
    int jbase = blockIdx.x * 4;

    float s[6][4];
#pragma unroll
    for (int g = 0; g < 6; g++)
#pragma unroll
        for (int q = 0; q < 4; q++) s[g][q] = 0.f;
#pragma unroll
    for (int ss = 0; ss < 2; ss++) {
        const float* p = part + (size_t)(wv * 2 + ss) * 786432
                       + (size_t)(jbase + jj) * 64 + bq * 4;
#pragma unroll
        for (int g = 0; g < 6; g++) {
            float4 v = *(const float4*)(p + (size_t)g * 2048 * 64);
            s[g][0] += v.x; s[g][1] += v.y; s[g][2] += v.z; s[g][3] += v.w;
        }
    }
    int rbase = (wv * 4 + jj) * 6;
#pragma unroll
    for (int g = 0; g < 6; g++)
        *(float4*)&red[(rbase + g) * 68 + bq * 4] = make_float4(s[g][0], s[g][1], s[g][2], s[g][3]);
    __syncthreads();

    int b = lane, jw = wv;
    int j = jbase + jw;
    float air = 0.f, aiz = 0.f, ain = 0.f, ahr = 0.f, ahz = 0.f, ahn = 0.f;
#pragma unroll
    for (int ww = 0; ww < 4; ww++) {
        int rb = (ww * 4 + jw) * 6;
        air += red[(rb + 0) * 68 + b];
        aiz += red[(rb + 1) * 68 + b];
        ain += red[(rb + 2) * 68 + b];
        ahr += red[(rb + 3) * 68 + b];
        ahz += red[(rb + 4) * 68 + b];
        ahn += red[(rb + 5) * 68 + b];
    }
    float rg = sigf(air + b_ih[j] + ahr + b_hh[j]);
    float ug = sigf(aiz + b_ih[j + 2048] + ahz + b_hh[j + 2048]);
    float ng = tanhf(ain + b_ih[j + 4096] + rg * (ahn + b_hh[j + 4096]));
    float hp = hb_in[j * 64 + b];
    hb_out[j * 64 + b] = (1.f - ug) * ng + ug * hp;
}

// ---------------------------------------------------------------------------
// mm2_k: register-tiled k-split GEMM partial (wo1 logits GEMM, row-clamped).
// ---------------------------------------------------------------------------
__global__ __launch_bounds__(256) void mm2_k(
    const float* __restrict__ WTa, const float* __restrict__ xa,
    const float* __restrict__ WTb, const float* __restrict__ xb,
    float* __restrict__ part, int splitTile, int kc, int nrows, int wstride,
    int partStride)
{
    __shared__ float xs[128 * 64];
    int tid = threadIdx.x;
    int tile = blockIdx.x, slot = blockIdx.y;
    const float* WT; const float* x; int tLoc;
    if (tile < splitTile) { WT = WTa; x = xa; tLoc = tile; }
    else                  { WT = WTb; x = xb; tLoc = tile - splitTile; }
    int rg = tid & 15, bg = tid >> 4;
    int r0 = tLoc * 128 + rg * 8;
    int b0 = bg * 4;
    int k0 = slot * kc;

    float acc[8][4];
#pragma unroll
    for (int i = 0; i < 8; i++)
#pragma unroll
        for (int j = 0; j < 4; j++) acc[i][j] = 0.f;

    bool fast = (r0 + 7 < nrows);
    int nPhase = kc >> 7;
    for (int ph = 0; ph < nPhase; ++ph) {
        int kp = k0 + ph * 128;
        __syncthreads();
        {
            const float4* src = (const float4*)(x + (size_t)kp * 64);
            float4* dst = (float4*)xs;
#pragma unroll
            for (int i = 0; i < 8; i++) dst[tid + i * 256] = src[tid + i * 256];
        }
        __syncthreads();
        if (fast) {
            const float* wp = WT + (size_t)kp * wstride + r0;
#pragma unroll 4
            for (int k = 0; k < 128; ++k) {
                float4 xv = *(const float4*)&xs[k * 64 + b0];
                float w[8];
                *(float4*)&w[0] = *(const float4*)wp;
                *(float4*)&w[4] = *(const float4*)(wp + 4);
                wp += wstride;
#pragma unroll
                for (int i = 0; i < 8; i++) {
                    acc[i][0] = fmaf(w[i], xv.x, acc[i][0]);
                    acc[i][1] = fmaf(w[i], xv.y, acc[i][1]);
                    acc[i][2] = fmaf(w[i], xv.z, acc[i][2]);
                    acc[i][3] = fmaf(w[i], xv.w, acc[i][3]);
                }
            }
        } else {
            for (int k = 0; k < 128; ++k) {
                float4 xv = *(const float4*)&xs[k * 64 + b0];
                const float* wrow = WT + (size_t)(kp + k) * wstride;
                float w[8];
#pragma unroll
                for (int i = 0; i < 8; i++) {
                    int rc = r0 + i; if (rc > nrows - 1) rc = nrows - 1;
                    w[i] = wrow[rc];
                }
#pragma unroll
                for (int i = 0; i < 8; i++) {
                    acc[i][0] = fmaf(w[i], xv.x, acc[i][0]);
                    acc[i][1] = fmaf(w[i], xv.y, acc[i][1]);
                    acc[i][2] = fmaf(w[i], xv.z, acc[i][2]);
                    acc[i][3] = fmaf(w[i], xv.w, acc[i][3]);
                }
            }
        }
    }

    size_t base = (size_t)slot * partStride + b0;
#pragma unroll
    for (int i = 0; i < 8; i++) {
        int prow = tile * 128 + rg * 8 + i;
        int pc = prow < nrows ? prow : (nrows - 1);
        if (tile >= splitTile) pc = prow;
        *(float4*)&part[base + (size_t)pc * 64] = *(float4*)acc[i];
    }
}

// ---------------------------------------------------------------------------
// melody softmax: 130 classes from 16 partial slots (stride 8320), argmax fb
// ---------------------------------------------------------------------------
__global__ __launch_bounds__(256) void mel_smax(
    const float* __restrict__ part, const float* __restrict__ bo1,
    float* __restrict__ outp, int t, int* __restrict__ mel_idx)
{
    int b = blockIdx.x, tid = threadIdx.x;
    float v = -1e30f;
    if (tid < MELn) {
        v = bo1[tid];
#pragma unroll
        for (int s = 0; s < 16; s++) v += part[s * 8320 + tid * 64 + b];
    }
    __shared__ float smax[256];
    __shared__ int   sidx[256];
    __shared__ float ssum[256];
    smax[tid] = v; sidx[tid] = tid;
    __syncthreads();
    for (int s = 128; s > 0; s >>= 1) {
        if (tid < s) {
            float a = smax[tid], o = smax[tid + s];
            int ai = sidx[tid], oi = sidx[tid + s];
            if (o > a || (o == a && oi < ai)) { smax[tid] = o; sidx[tid] = oi; }
        }
        __syncthreads();
    }
    float mx = smax[0]; int am = sidx[0];
    ssum[tid] = (tid < MELn) ? expf(v - mx) : 0.f;
    __syncthreads();
    for (int s = 128; s > 0; s >>= 1) {
        if (tid < s) ssum[tid] += ssum[tid + s];
        __syncthreads();
    }
    float ls = logf(ssum[0]);
    if (tid < MELn) outp[(size_t)b * Tn * MELn + t * MELn + tid] = v - mx - ls;
    if (tid == 0) mel_idx[b] = am;
}

// ---------------------------------------------------------------------------
extern "C" void kernel_launch(void* const* d_in, const int* in_sizes, int n_in,
                              void* d_out, int out_size, void* d_ws, size_t ws_size,
                              hipStream_t stream)
{
    (void)in_sizes; (void)n_in; (void)out_size; (void)ws_size;
    const float* z1    = (const float*)d_in[0];
    const float* z2    = (const float*)d_in[1];
    const float* cond  = (const float*)d_in[2];
    const float* w_ih0 = (const float*)d_in[3];
    const float* w_hh0 = (const float*)d_in[4];
    const float* b_ih0 = (const float*)d_in[5];
    const float* b_hh0 = (const float*)d_in[6];
    const float* w_ih1 = (const float*)d_in[7];
    const float* w_hh1 = (const float*)d_in[8];
    const float* b_ih1 = (const float*)d_in[9];
    const float* b_hh1 = (const float*)d_in[10];
    const float* w_ih2 = (const float*)d_in[11];
    const float* w_hh2 = (const float*)d_in[12];
    const float* b_ih2 = (const float*)d_in[13];
    const float* b_hh2 = (const float*)d_in[14];
    const float* wi0   = (const float*)d_in[15];
    const float* bi0   = (const float*)d_in[16];
    const float* wo0   = (const float*)d_in[17];
    const float* bo0   = (const float*)d_in[18];
    const float* wi1   = (const float*)d_in[19];
    const float* bi1   = (const float*)d_in[20];
    const float* wo1   = (const float*)d_in[21];
    const float* bo1   = (const float*)d_in[22];
    float* outp = (float*)d_out;
    float* ws = (float*)d_ws;

    // workspace layout (floats), ~232 MB
    size_t off = 0;
    float* WT0  = ws + off; off += 12582912;   // w_hh0^T [2048][6144]
    float* WT1  = ws + off; off += 12582912;   // w_hh1^T
    float* WTi2 = ws + off; off += 12582912;   // w_ih2^T
    float* WTh2 = ws + off; off += 12582912;   // w_hh2^T
    float* WTo1 = ws + off; off += 270336;     // wo1^T [2048][132] (padded)
    float* part = ws + off; off += 6291456;    // k-split partials (25 MB)
    float* hR[2] = { ws + off, ws + off + 131072 }; off += 262144;
    float* hA[2] = { ws + off, ws + off + 131072 }; off += 262144;
    float* hB[2] = { ws + off, ws + off + 131072 }; off += 262144;
    float* gi0c   = ws + off; off += 393216;
    float* gi1c   = ws + off; off += 393216;
    float* rlo    = ws + off; off += 6144;     // [32][64][3]
    float* cond_t = ws + off; off += 24576;
    float* z1t    = ws + off; off += 8192;
    float* z2t    = ws + off; off += 8192;
    int* rhy_idx  = (int*)(ws + off); off += 64;
    int* mel_idx  = (int*)(ws + off); off += 64;

    // ---- pre-pass ----
    prep_misc<<<96, 256, 0, stream>>>(z1, z2, cond, z1t, z2t, cond_t, rhy_idx, mel_idx);
    init_h_k<<<dim3(Hd / 4, 2), 256, 0, stream>>>(z1t, z2t, wi0, bi0, wi1, bi1, hR[0], hA[0]);
    gi_const_k<<<dim3(G3 / 4, 2), 256, 0, stream>>>(z1t, z2t, w_ih0, b_ih0, w_ih1, b_ih1, gi0c, gi1c);
    transpose4_k<<<dim3(32, 96, 4), 256, 0, stream>>>(w_hh0, w_hh1, w_ih2, w_hh2,
                                                      WT0, WT1, WTi2, WTh2);
    transpose1_k<<<dim3(32, 3), 256, 0, stream>>>(wo1, WTo1, MELn, Hd, 132);

    // ---- rhythm decoder ----
    for (int s = 0; s < Tn; s++) {
        const float* h_in = hR[s & 1];
        float* h_out = hR[(s + 1) & 1];
        // 32 tiles(192 rows) x 16 slots(kc=128) = 512 blocks, 2/CU
        mm4_k<<<dim3(32, 16), 256, 0, stream>>>(WT0, h_in, WT0, h_in, part,
                                                32, 128, 393216);
        rhy_epi<<<512, 256, 0, stream>>>(part, gi0c, w_ih0, b_hh0, h_in, h_out, rhy_idx);
        rhy_out_k<<<1, 768, 0, stream>>>(h_out, wo0, bo0, rlo + s * 192, rhy_idx);
    }

    // ---- melody decoder ----
    for (int t = 0; t < Tn; t++) {
        const float* ha_in = hA[t & 1];
        float* ha_out = hA[(t + 1) & 1];
        mm4_k<<<dim3(32, 16), 256, 0, stream>>>(WT1, ha_in, WT1, ha_in, part,
                                                32, 128, 393216);
        mel1_epi<<<512, 256, 0, stream>>>(part, gi1c, w_ih1, b_hh1, ha_in, ha_out,
                                          mel_idx, rlo + t * 192, cond_t + t * (CHn * Bsz));
        const float* hb_in = (t == 0) ? (const float*)ha_out : (const float*)hB[t & 1];
        float* hb_out = hB[(t + 1) & 1];
        // fused: tiles 0..31 = WTi2 x ha_out, tiles 32..63 = WTh2 x hb_in
        mm4_k<<<dim3(64, 8), 256, 0, stream>>>(WTi2, ha_out, WTh2, hb_in, part,
                                               32, 256, 786432);
        mel2_epi<<<512, 256, 0, stream>>>(part, b_ih2, b_hh2, hb_in, hb_out);
        mm2_k<<<dim3(2, 16), 256, 0, stream>>>(WTo1, hb_out, WTo1, hb_out, part,
                                               2, 128, MELn, 132, 8320);
        mel_smax<<<Bsz, 256, 0, stream>>>(part, bo1, outp, t, mel_idx);
    }
}

// Round 4
// 7356.347 us; speedup vs baseline: 1.3928x; 1.0682x over previous
//
#include <hip/hip_runtime.h>
#include <hip/hip_bf16.h>
#include <math.h>

#define Bsz  64
#define Hd   2048
#define G3   6144
#define MELn 130
#define CHn  12
#define RHYn 3
#define Tn   32

__device__ __forceinline__ float sigf(float x) { return 1.0f / (1.0f + expf(-x)); }

// ---------------------------------------------------------------------------
// prep: transpose z1/z2 -> [128][64], condition -> [T][CH][64], init feedback idx
// ---------------------------------------------------------------------------
__global__ void prep_misc(const float* __restrict__ z1, const float* __restrict__ z2,
                          const float* __restrict__ cond,
                          float* __restrict__ z1t, float* __restrict__ z2t,
                          float* __restrict__ cond_t, int* __restrict__ rhy_idx,
                          int* __restrict__ mel_idx, int* __restrict__ cnts)
{
    int idx = blockIdx.x * 256 + threadIdx.x;
    if (idx < 128 * Bsz) {
        int j = idx >> 6, b = idx & 63;
        z1t[idx] = z1[b * 128 + j];
        z2t[idx] = z2[b * 128 + j];
    }
    if (idx < Tn * CHn * Bsz) {
        int t = idx / (CHn * Bsz);
        int r = idx - t * CHn * Bsz;
        int j = r >> 6, b = r & 63;
        cond_t[idx] = cond[b * (Tn * CHn) + t * CHn + j];
    }
    if (idx < Bsz) { rhy_idx[idx] = RHYn - 1; mel_idx[idx] = MELn - 1; }
    if (idx < 4) cnts[idx] = 0;
}

// ---------------------------------------------------------------------------
// h0 = tanh(z2 @ wi0.T + bi0), h1 = tanh(z1 @ wi1.T + bi1); output [j][b]
// ---------------------------------------------------------------------------
__global__ __launch_bounds__(256) void init_h_k(
    const float* __restrict__ z1t, const float* __restrict__ z2t,
    const float* __restrict__ wi0, const float* __restrict__ bi0,
    const float* __restrict__ wi1, const float* __restrict__ bi1,
    float* __restrict__ h0_out, float* __restrict__ h1_out)
{
    int lane = threadIdx.x & 63, wave = threadIdx.x >> 6;
    int j = blockIdx.x * 4 + wave;
    int which = blockIdx.y;
    const float* zt = which ? z1t : z2t;
    const float* wi = which ? wi1 : wi0;
    const float* bi = which ? bi1 : bi0;
    float* outh = which ? h1_out : h0_out;
    const float4* w4 = (const float4*)(wi + (size_t)j * 128);
    float acc = 0.f;
#pragma unroll 8
    for (int i = 0; i < 32; i++) {
        float4 w = w4[i];
        int k = i * 4;
        acc = fmaf(zt[(k + 0) * 64 + lane], w.x, acc);
        acc = fmaf(zt[(k + 1) * 64 + lane], w.y, acc);
        acc = fmaf(zt[(k + 2) * 64 + lane], w.z, acc);
        acc = fmaf(zt[(k + 3) * 64 + lane], w.w, acc);
    }
    outh[j * 64 + lane] = tanhf(acc + bi[j]);
}

// ---------------------------------------------------------------------------
// step-invariant ih parts (z-terms + bias), layout [row][64]
// ---------------------------------------------------------------------------
__global__ __launch_bounds__(256) void gi_const_k(
    const float* __restrict__ z1t, const float* __restrict__ z2t,
    const float* __restrict__ w_ih0, const float* __restrict__ b_ih0,
    const float* __restrict__ w_ih1, const float* __restrict__ b_ih1,
    float* __restrict__ gi0c, float* __restrict__ gi1c)
{
    int lane = threadIdx.x & 63, wave = threadIdx.x >> 6;
    int row = blockIdx.x * 4 + wave;
    int which = blockIdx.y;
    const float* zt; const float* w; float acc; float* dst;
    if (which == 0) { zt = z2t; w = w_ih0 + (size_t)row * 131 + RHYn;          acc = b_ih0[row]; dst = gi0c; }
    else            { zt = z1t; w = w_ih1 + (size_t)row * 273 + (MELn + RHYn); acc = b_ih1[row]; dst = gi1c; }
#pragma unroll 4
    for (int i = 0; i < 128; i++) acc = fmaf(zt[i * 64 + lane], w[i], acc);
    dst[(size_t)row * 64 + lane] = acc;
}

// ---------------------------------------------------------------------------
// 64x64 tile transpose: in [R][C] -> out [C][Rout] (Rout >= R allows padding)
// ---------------------------------------------------------------------------
__device__ __forceinline__ void transpose_body(
    const float* __restrict__ in, float* __restrict__ out, int R, int C, int Rout,
    int bx, int by, float* tile)
{
    int c0 = bx * 64, r0 = by * 64;
    int t = threadIdx.x;
    int cl = t & 63, rw = t >> 6;
#pragma unroll
    for (int i = 0; i < 16; ++i) {
        int rl = rw + i * 4;
        int r = r0 + rl, c = c0 + cl;
        float v = (r < R && c < C) ? in[(size_t)r * C + c] : 0.f;
        tile[rl * 65 + cl] = v;
    }
    __syncthreads();
#pragma unroll
    for (int i = 0; i < 16; ++i) {
        int c_loc = rw + i * 4;
        int r_loc = cl;
        int oc = c0 + c_loc, orow = r0 + r_loc;
        if (oc < C && orow < R)
            out[(size_t)oc * Rout + orow] = tile[r_loc * 65 + c_loc];
    }
}

__global__ __launch_bounds__(256) void transpose4_k(
    const float* __restrict__ a, const float* __restrict__ b,
    const float* __restrict__ c, const float* __restrict__ d,
    float* __restrict__ oa, float* __restrict__ ob,
    float* __restrict__ oc, float* __restrict__ od)
{
    __shared__ float tile[64 * 65];
    const float* in; float* out;
    switch (blockIdx.z) {
        case 0: in = a; out = oa; break;
        case 1: in = b; out = ob; break;
        case 2: in = c; out = oc; break;
        default: in = d; out = od; break;
    }
    transpose_body(in, out, G3, Hd, G3, blockIdx.x, blockIdx.y, tile);
}

__global__ __launch_bounds__(256) void transpose1_k(
    const float* __restrict__ in, float* __restrict__ out, int R, int C, int Rout)
{
    __shared__ float tile[64 * 65];
    transpose_body(in, out, R, C, Rout, blockIdx.x, blockIdx.y, tile);
}

// ---------------------------------------------------------------------------
// mm4 GEMM body (single matrix, kc=128, one phase). Partial layout identical
// to earlier rounds: part[slot*partStride + prow*64 + b].
// ---------------------------------------------------------------------------
__device__ __forceinline__ void mm4_body(
    const float* __restrict__ WT, const float* __restrict__ x,
    float* __restrict__ part, int tile, int slot, int partStride, float* xs)
{
    int tid = threadIdx.x;
    int rg = tid & 15, bg = tid >> 4;
    int r0 = tile * 192 + rg * 12;
    int b0 = bg * 4;
    int kp = slot * 128;

    float acc[12][4];
#pragma unroll
    for (int i = 0; i < 12; i++)
#pragma unroll
        for (int j = 0; j < 4; j++) acc[i][j] = 0.f;

    {
        const float4* src = (const float4*)(x + (size_t)kp * 64);
        float4* dst = (float4*)xs;
#pragma unroll
        for (int i = 0; i < 8; i++) dst[tid + i * 256] = src[tid + i * 256];
    }
    __syncthreads();
    const float* wp = WT + (size_t)kp * G3 + r0;
#pragma unroll 2
    for (int k = 0; k < 128; ++k) {
        float4 xv = *(const float4*)&xs[k * 64 + b0];
        float w[12];
        *(float4*)&w[0] = *(const float4*)(wp);
        *(float4*)&w[4] = *(const float4*)(wp + 4);
        *(float4*)&w[8] = *(const float4*)(wp + 8);
        wp += G3;
#pragma unroll
        for (int i = 0; i < 12; i++) {
            acc[i][0] = fmaf(w[i], xv.x, acc[i][0]);
            acc[i][1] = fmaf(w[i], xv.y, acc[i][1]);
            acc[i][2] = fmaf(w[i], xv.z, acc[i][2]);
            acc[i][3] = fmaf(w[i], xv.w, acc[i][3]);
        }
    }

    size_t base = (size_t)slot * partStride + b0;
    int prow0 = tile * 192 + rg * 12;
#pragma unroll
    for (int i = 0; i < 12; i++)
        *(float4*)&part[base + (size_t)(prow0 + i) * 64] = *(float4*)&acc[i][0];
}

// ---------------------------------------------------------------------------
// fused rhythm GEMM + previous-step logits/log_softmax/argmax.
// Blocks 0..511: GEMM partials (tile=flat&31, slot=flat>>5).
// Block 512 (if doOut): 3-class logits on x (= h of step s-1), bitwise
// identical chunk order to the old rhy_out_k.
// ---------------------------------------------------------------------------
__global__ __launch_bounds__(256) void mm4rhy_k(
    const float* __restrict__ WT, const float* __restrict__ x,
    float* __restrict__ part,
    const float* __restrict__ wo0, const float* __restrict__ bo0,
    float* __restrict__ rlo_t, int* __restrict__ rhy_idx, int doOut)
{
    __shared__ float smem[128 * 64];
    int flat = blockIdx.x, tid = threadIdx.x;
    if (flat < 512) {
        mm4_body(WT, x, part, flat & 31, flat >> 5, 393216, smem);
        return;
    }
    if (!doOut) return;
    int lane = tid & 63, wv = tid >> 6;      // wv = k-chunk of 512
    const float* hc = x + wv * 512 * 64;
    const float* w0 = wo0 + wv * 512;
    const float* w1 = wo0 + Hd + wv * 512;
    const float* w2 = wo0 + 2 * Hd + wv * 512;
    float a0 = 0.f, a1 = 0.f, a2 = 0.f;
#pragma unroll 4
    for (int k = 0; k < 512; k++) {
        float hv = hc[k * 64 + lane];
        a0 = fmaf(hv, w0[k], a0);
        a1 = fmaf(hv, w1[k], a1);
        a2 = fmaf(hv, w2[k], a2);
    }
    smem[(0 * 4 + wv) * 64 + lane] = a0;
    smem[(1 * 4 + wv) * 64 + lane] = a1;
    smem[(2 * 4 + wv) * 64 + lane] = a2;
    __syncthreads();
    if (wv == 0) {
        float l0 = smem[0 * 64 + lane] + smem[1 * 64 + lane] + smem[2 * 64 + lane] + smem[3 * 64 + lane] + bo0[0];
        float l1 = smem[4 * 64 + lane] + smem[5 * 64 + lane] + smem[6 * 64 + lane] + smem[7 * 64 + lane] + bo0[1];
        float l2 = smem[8 * 64 + lane] + smem[9 * 64 + lane] + smem[10 * 64 + lane] + smem[11 * 64 + lane] + bo0[2];
        int am; float mx;
        if (l0 >= l1 && l0 >= l2) { am = 0; mx = l0; }
        else if (l1 >= l2)        { am = 1; mx = l1; }
        else                      { am = 2; mx = l2; }
        float s = expf(l0 - mx) + expf(l1 - mx) + expf(l2 - mx);
        float ls = logf(s);
        rlo_t[lane * 3 + 0] = l0 - mx - ls;
        rlo_t[lane * 3 + 1] = l1 - mx - ls;
        rlo_t[lane * 3 + 2] = l2 - mx - ls;
        rhy_idx[lane] = am;
    }
}

// ---------------------------------------------------------------------------
// fused melody GRU1 GEMM + previous-step 130-class logits/softmax/argmax.
// Blocks 0..511: GEMM partials on (WT, x=ha). Blocks 512..527 (if doOut):
// logits GEMM on hb_prev (2 tiles x 8 slots, kc=256) into lpart; the last
// of the 16 (atomic counter, fenced) finalizes log_softmax + argmax + output.
// ---------------------------------------------------------------------------
__global__ __launch_bounds__(256) void mm4mel_k(
    const float* __restrict__ WT, const float* __restrict__ x,
    float* __restrict__ part,
    const float* __restrict__ WTo1, const float* __restrict__ hb_prev,
    float* __restrict__ lpart, const float* __restrict__ bo1,
    float* __restrict__ outp, int tprev, int* __restrict__ mel_idx,
    int* __restrict__ cnt, int doOut)
{
    __shared__ float smem[8704];             // 34 KB; GEMM path uses [0,8192)
    int flat = blockIdx.x, tid = threadIdx.x;
    if (flat < 512) {
        mm4_body(WT, x, part, flat & 31, flat >> 5, 393216, smem);
        return;
    }
    if (!doOut) return;

    // ---- logits GEMM (mm2 body, kc=256) ----
    int li = flat - 512;                     // 0..15
    int ltile = li & 1, lslot = li >> 1;
    int rg = tid & 15, bg = tid >> 4;
    int r0 = ltile * 128 + rg * 8;
    int b0 = bg * 4;
    int k0 = lslot * 256;

    float acc[8][4];
#pragma unroll
    for (int i = 0; i < 8; i++)
#pragma unroll
        for (int j = 0; j < 4; j++) acc[i][j] = 0.f;

    bool fast = (r0 + 7 < MELn);
    for (int ph = 0; ph < 2; ++ph) {
        int kp = k0 + ph * 128;
        __syncthreads();
        {
            const float4* src = (const float4*)(hb_prev + (size_t)kp * 64);
            float4* dst = (float4*)smem;
#pragma unroll
            for (int i = 0; i < 8; i++) dst[tid + i * 256] = src[tid + i * 256];
        }
        __syncthreads();
        if (fast) {
            const float* wp = WTo1 + (size_t)kp * 132 + r0;
#pragma unroll 4
            for (int k = 0; k < 128; ++k) {
                float4 xv = *(const float4*)&smem[k * 64 + b0];
                float w[8];
                *(float4*)&w[0] = *(const float4*)wp;
                *(float4*)&w[4] = *(const float4*)(wp + 4);
                wp += 132;
#pragma unroll
                for (int i = 0; i < 8; i++) {
                    acc[i][0] = fmaf(w[i], xv.x, acc[i][0]);
                    acc[i][1] = fmaf(w[i], xv.y, acc[i][1]);
                    acc[i][2] = fmaf(w[i], xv.z, acc[i][2]);
                    acc[i][3] = fmaf(w[i], xv.w, acc[i][3]);
                }
            }
        } else {
            for (int k = 0; k < 128; ++k) {
                float4 xv = *(const float4*)&smem[k * 64 + b0];
                const float* wrow = WTo1 + (size_t)(kp + k) * 132;
                float w[8];
#pragma unroll
                for (int i = 0; i < 8; i++) {
                    int rc = r0 + i; if (rc > MELn - 1) rc = MELn - 1;
                    w[i] = wrow[rc];
                }
#pragma unroll
                for (int i = 0; i < 8; i++) {
                    acc[i][0] = fmaf(w[i], xv.x, acc[i][0]);
                    acc[i][1] = fmaf(w[i], xv.y, acc[i][1]);
                    acc[i][2] = fmaf(w[i], xv.z, acc[i][2]);
                    acc[i][3] = fmaf(w[i], xv.w, acc[i][3]);
                }
            }
        }
    }
    size_t base = (size_t)lslot * 8320 + b0;
#pragma unroll
    for (int i = 0; i < 8; i++) {
        int prow = ltile * 128 + rg * 8 + i;
        int pc = prow < MELn ? prow : (MELn - 1);
        *(float4*)&lpart[base + (size_t)pc * 64] = *(float4*)acc[i];
    }

    // ---- last-block finalize (fenced) ----
    __shared__ int lastf;
    __threadfence();                          // release this block's stores
    __syncthreads();
    if (tid == 0) lastf = (atomicAdd(cnt, 1) == 15);
    __syncthreads();
    if (!lastf) return;
    __threadfence();                          // acquire other blocks' stores

    for (int e = tid; e < MELn * 64; e += 256) {
        int r = e >> 6, b = e & 63;
        float v = bo1[r];
#pragma unroll
        for (int s = 0; s < 8; s++) v += lpart[s * 8320 + r * 64 + b];
        smem[e] = v;
    }
    __syncthreads();
    if (tid < 64) {
        int b = tid;
        float mx = -1e30f; int am = 0;
        for (int r = 0; r < MELn; r++) {
            float v = smem[r * 64 + b];
            if (v > mx) { mx = v; am = r; }   // first max (matches argmax)
        }
        float ssum = 0.f;
        for (int r = 0; r < MELn; r++) ssum += expf(smem[r * 64 + b] - mx);
        smem[8320 + b] = mx;
        smem[8384 + b] = logf(ssum);
        mel_idx[b] = am;
    }
    __syncthreads();
    for (int e = tid; e < MELn * 64; e += 256) {
        int r = e >> 6, b = e & 63;
        outp[(size_t)b * Tn * MELn + tprev * MELn + r] = smem[e] - smem[8320 + b] - smem[8384 + b];
    }
    __syncthreads();
    if (tid == 0) *cnt = 0;                   // exclusive owner
}

// ---------------------------------------------------------------------------
// mm4_k: fused two-matrix GEMM for GRU2 (unchanged from round 3).
// ---------------------------------------------------------------------------
__global__ __launch_bounds__(256) void mm4_k(
    const float* __restrict__ WTa, const float* __restrict__ xa,
    const float* __restrict__ WTb, const float* __restrict__ xb,
    float* __restrict__ part, int splitTile, int kc, int partStride)
{
    __shared__ float xs[128 * 64];
    int tid = threadIdx.x;
    int tile = blockIdx.x, slot = blockIdx.y;
    const float* WT; const float* x; int tLoc;
    if (tile < splitTile) { WT = WTa; x = xa; tLoc = tile; }
    else                  { WT = WTb; x = xb; tLoc = tile - splitTile; }
    int rg = tid & 15, bg = tid >> 4;
    int r0 = tLoc * 192 + rg * 12;
    int b0 = bg * 4;
    int k0 = slot * kc;

    float acc[12][4];
#pragma unroll
    for (int i = 0; i < 12; i++)
#pragma unroll
        for (int j = 0; j < 4; j++) acc[i][j] = 0.f;

    int nPhase = kc >> 7;
    for (int ph = 0; ph < nPhase; ++ph) {
        int kp = k0 + ph * 128;
        __syncthreads();
        {
            const float4* src = (const float4*)(x + (size_t)kp * 64);
            float4* dst = (float4*)xs;
#pragma unroll
            for (int i = 0; i < 8; i++) dst[tid + i * 256] = src[tid + i * 256];
        }
        __syncthreads();
        const float* wp = WT + (size_t)kp * G3 + r0;
#pragma unroll 2
        for (int k = 0; k < 128; ++k) {
            float4 xv = *(const float4*)&xs[k * 64 + b0];
            float w[12];
            *(float4*)&w[0] = *(const float4*)(wp);
            *(float4*)&w[4] = *(const float4*)(wp + 4);
            *(float4*)&w[8] = *(const float4*)(wp + 8);
            wp += G3;
#pragma unroll
            for (int i = 0; i < 12; i++) {
                acc[i][0] = fmaf(w[i], xv.x, acc[i][0]);
                acc[i][1] = fmaf(w[i], xv.y, acc[i][1]);
                acc[i][2] = fmaf(w[i], xv.z, acc[i][2]);
                acc[i][3] = fmaf(w[i], xv.w, acc[i][3]);
            }
        }
    }

    size_t base = (size_t)slot * partStride + b0;
    int prow0 = tile * 192 + rg * 12;
#pragma unroll
    for (int i = 0; i < 12; i++)
        *(float4*)&part[base + (size_t)(prow0 + i) * 64] = *(float4*)&acc[i][0];
}

// ---------------------------------------------------------------------------
// rhythm epilogue, phase-split (unchanged from round 3)
// ---------------------------------------------------------------------------
__global__ __launch_bounds__(256) void rhy_epi(
    const float* __restrict__ part, const float* __restrict__ gi_c,
    const float* __restrict__ w_ih, const float* __restrict__ b_hh,
    const float* __restrict__ h_in, float* __restrict__ h_out,
    const int* __restrict__ fb_idx)
{
    __shared__ float red[48 * 68];
    int tid = threadIdx.x;
    int wv = tid >> 6, lane = tid & 63;
    int jj = lane >> 4, bq = lane & 15;
    int jbase = blockIdx.x * 4;

    float s0[4], s1[4], s2[4];
#pragma unroll
    for (int q = 0; q < 4; q++) { s0[q] = 0.f; s1[q] = 0.f; s2[q] = 0.f; }
#pragma unroll
    for (int ss = 0; ss < 4; ss++) {
        const float* p = part + (size_t)(wv * 4 + ss) * 393216
                       + (size_t)(jbase + jj) * 64 + bq * 4;
        float4 v0 = *(const float4*)(p);
        float4 v1 = *(const float4*)(p + 2048 * 64);
        float4 v2 = *(const float4*)(p + 4096 * 64);
        s0[0] += v0.x; s0[1] += v0.y; s0[2] += v0.z; s0[3] += v0.w;
        s1[0] += v1.x; s1[1] += v1.y; s1[2] += v1.z; s1[3] += v1.w;
        s2[0] += v2.x; s2[1] += v2.y; s2[2] += v2.z; s2[3] += v2.w;
    }
    int rbase = (wv * 4 + jj) * 3;
    *(float4*)&red[(rbase + 0) * 68 + bq * 4] = make_float4(s0[0], s0[1], s0[2], s0[3]);
    *(float4*)&red[(rbase + 1) * 68 + bq * 4] = make_float4(s1[0], s1[1], s1[2], s1[3]);
    *(float4*)&red[(rbase + 2) * 68 + bq * 4] = make_float4(s2[0], s2[1], s2[2], s2[3]);
    __syncthreads();

    int b = lane, jw = wv;
    int j = jbase + jw;
    float ar = 0.f, az = 0.f, an = 0.f;
#pragma unroll
    for (int ww = 0; ww < 4; ww++) {
        int rb = (ww * 4 + jw) * 3;
        ar += red[(rb + 0) * 68 + b];
        az += red[(rb + 1) * 68 + b];
        an += red[(rb + 2) * 68 + b];
    }
    int oi = fb_idx[b];
    float gir = gi_c[j * 64 + b]            + w_ih[(size_t)j * 131 + oi];
    float giz = gi_c[(j + 2048) * 64 + b]   + w_ih[(size_t)(j + 2048) * 131 + oi];
    float gin = gi_c[(j + 4096) * 64 + b]   + w_ih[(size_t)(j + 4096) * 131 + oi];
    float rg = sigf(gir + ar + b_hh[j]);
    float ug = sigf(giz + az + b_hh[j + 2048]);
    float ng = tanhf(gin + rg * (an + b_hh[j + 4096]));
    float hp = h_in[j * 64 + b];
    h_out[j * 64 + b] = (1.f - ug) * ng + ug * hp;
}

// ---------------------------------------------------------------------------
// standalone rhythm logits (tail for s=31 only)
// ---------------------------------------------------------------------------
__global__ __launch_bounds__(768) void rhy_out_k(
    const float* __restrict__ h, const float* __restrict__ wo0,
    const float* __restrict__ bo0, float* __restrict__ rlo_t, int* __restrict__ rhy_idx)
{
    __shared__ float partl[12 * 64];
    int tid = threadIdx.x, lane = tid & 63, wave = tid >> 6;
    int c = wave >> 2, chunk = wave & 3;
    const float* w = wo0 + c * Hd + chunk * 512;
    const float* hc = h + chunk * 512 * 64;
    float acc = 0.f;
#pragma unroll 4
    for (int k = 0; k < 512; k++) acc = fmaf(hc[k * 64 + lane], w[k], acc);
    partl[wave * 64 + lane] = acc;
    __syncthreads();
    if (wave == 0) {
        float l0 = partl[0 * 64 + lane] + partl[1 * 64 + lane] + partl[2 * 64 + lane] + partl[3 * 64 + lane] + bo0[0];
        float l1 = partl[4 * 64 + lane] + partl[5 * 64 + lane] + partl[6 * 64 + lane] + partl[7 * 64 + lane] + bo0[1];
        float l2 = partl[8 * 64 + lane] + partl[9 * 64 + lane] + partl[10 * 64 + lane] + partl[11 * 64 + lane] + bo0[2];
        int am; float mx;
        if (l0 >= l1 && l0 >= l2) { am = 0; mx = l0; }
        else if (l1 >= l2)        { am = 1; mx = l1; }
        else                      { am = 2; mx = l2; }
        float s = expf(l0 - mx) + expf(l1 - mx) + expf(l2 - mx);
        float ls = logf(s);
        rlo_t[lane * 3 + 0] = l0 - mx - ls;
        rlo_t[lane * 3 + 1] = l1 - mx - ls;
        rlo_t[lane * 3 + 2] = l2 - mx - ls;
        rhy_idx[lane] = am;
    }
}

// ---------------------------------------------------------------------------
// melody GRU1 epilogue, phase-split (unchanged from round 3)
// ---------------------------------------------------------------------------
__global__ __launch_bounds__(256) void mel1_epi(
    const float* __restrict__ part, const float* __restrict__ gi_c,
    const float* __restrict__ w_ih, const float* __restrict__ b_hh,
    const float* __restrict__ h_in, float* __restrict__ h_out,
    const int* __restrict__ mel_idx, const float* __restrict__ rlo,
    const float* __restrict__ cdt)
{
    __shared__ float red[48 * 68];
    int tid = threadIdx.x;
    int wv = tid >> 6, lane = tid & 63;
    int jj = lane >> 4, bq = lane & 15;
    int jbase = blockIdx.x * 4;

    float s0[4], s1[4], s2[4];
#pragma unroll
    for (int q = 0; q < 4; q++) { s0[q] = 0.f; s1[q] = 0.f; s2[q] = 0.f; }
#pragma unroll
    for (int ss = 0; ss < 4; ss++) {
        const float* p = part + (size_t)(wv * 4 + ss) * 393216
                       + (size_t)(jbase + jj) * 64 + bq * 4;
        float4 v0 = *(const float4*)(p);
        float4 v1 = *(const float4*)(p + 2048 * 64);
        float4 v2 = *(const float4*)(p + 4096 * 64);
        s0[0] += v0.x; s0[1] += v0.y; s0[2] += v0.z; s0[3] += v0.w;
        s1[0] += v1.x; s1[1] += v1.y; s1[2] += v1.z; s1[3] += v1.w;
        s2[0] += v2.x; s2[1] += v2.y; s2[2] += v2.z; s2[3] += v2.w;
    }
    int rbase = (wv * 4 + jj) * 3;
    *(float4*)&red[(rbase + 0) * 68 + bq * 4] = make_float4(s0[0], s0[1], s0[2], s0[3]);
    *(float4*)&red[(rbase + 1) * 68 + bq * 4] = make_float4(s1[0], s1[1], s1[2], s1[3]);
    *(float4*)&red[(rbase + 2) * 68 + bq * 4] = make_float4(s2[0], s2[1], s2[2], s2[3]);
    __syncthreads();

    int b = lane, jw = wv;
    int j = jbase + jw;
    float ar = 0.f, az = 0.f, an = 0.f;
#pragma unroll
    for (int ww = 0; ww < 4; ww++) {
        int rb = (ww * 4 + jw) * 3;
        ar += red[(rb + 0) * 68 + b];
        az += red[(rb + 1) * 68 + b];
        an += red[(rb + 2) * 68 + b];
    }
    int oi = mel_idx[b];
    float r0 = rlo[b * 3 + 0], r1 = rlo[b * 3 + 1], r2 = rlo[b * 3 + 2];
    float cd[12];
#pragma unroll
    for (int q = 0; q < 12; q++) cd[q] = cdt[q * 64 + b];
    float gi[3];
#pragma unroll
    for (int g = 0; g < 3; g++) {
        int row = j + g * 2048;
        const float* wrow = w_ih + (size_t)row * 273;
        float v = gi_c[row * 64 + b] + wrow[oi];
        v = fmaf(r0, wrow[130], v);
        v = fmaf(r1, wrow[131], v);
        v = fmaf(r2, wrow[132], v);
#pragma unroll
        for (int q = 0; q < 12; q++) v = fmaf(cd[q], wrow[261 + q], v);
        gi[g] = v;
    }
    float rg = sigf(gi[0] + ar + b_hh[j]);
    float ug = sigf(gi[1] + az + b_hh[j + 2048]);
    float ng = tanhf(gi[2] + rg * (an + b_hh[j + 4096]));
    float hp = h_in[j * 64 + b];
    h_out[j * 64 + b] = (1.f - ug) * ng + ug * hp;
}

// ---------------------------------------------------------------------------
// melody GRU2 epilogue, phase-split (unchanged from round 3)
// ---------------------------------------------------------------------------
__global__ __launch_bounds__(256) void mel2_epi(
    const float* __restrict__ part, const float* __restrict__ b_ih,
    const float* __restrict__ b_hh, const float* __restrict__ hb_in,
    float* __restrict__ hb_out)
{
    __shared__ float red[96 * 68];
    int tid = threadIdx.x;
    int wv = tid >> 6, lane = tid & 63;
    int jj = lane >> 4, bq = lane & 15;
    int jbase = blockIdx.x * 4;

    float s[6][4];
#pragma unroll
    for (int g = 0; g < 6; g++)
#pragma unroll
        for (int q = 0; q < 4; q++) s[g][q] = 0.f;
#pragma unroll
    for (int ss = 0; ss < 2; ss++) {
        const float* p = part + (size_t)(wv * 2 + ss) * 786432
                       + (size_t)(jbase + jj) * 64 + bq * 4;
#pragma unroll
        for (int g = 0; g < 6; g++) {
            float4 v = *(const float4*)(p + (size_t)g * 2048 * 64);
            s[g][0] += v.x; s[g][1] += v.y; s[g][2] += v.z; s[g][3] += v.w;
        }
    }
    int rbase = (wv * 4 + jj) * 6;
#pragma unroll
    for (int g = 0; g < 6; g++)
        *(float4*)&red[(rbase + g) * 68 + bq * 4] = make_float4(s[g][0], s[g][1], s[g][2], s[g][3]);
    __syncthreads();

    int b = lane, jw = wv;
    int j = jbase + jw;
    float air = 0.f, aiz = 0.f, ain = 0.f, ahr = 0.f, ahz = 0.f, ahn = 0.f;
#pragma unroll
    for (int ww = 0; ww < 4; ww++) {
        int rb = (ww * 4 + jw) * 6;
        air += red[(rb + 0) * 68 + b];
        aiz += red[(rb + 1) * 68 + b];
        ain += red[(rb + 2) * 68 + b];
        ahr += red[(rb + 3) * 68 + b];
        ahz += red[(rb + 4) * 68 + b];
        ahn += red[(rb + 5) * 68 + b];
    }
    float rg = sigf(air + b_ih[j] + ahr + b_hh[j]);
    float ug = sigf(aiz + b_ih[j + 2048] + ahz + b_hh[j + 2048]);
    float ng = tanhf(ain + b_ih[j + 4096] + rg * (ahn + b_hh[j + 4096]));
    float hp = hb_in[j * 64 + b];
    hb_out[j * 64 + b] = (1.f - ug) * ng + ug * hp;
}

// ---------------------------------------------------------------------------
// mm2_k: small logits GEMM (tail for t=31 only, 16 slots kc=128)
// ---------------------------------------------------------------------------
__global__ __launch_bounds__(256) void mm2_k(
    const float* __restrict__ WTa, const float* __restrict__ xa,
    const float* __restrict__ WTb, const float* __restrict__ xb,
    float* __restrict__ part, int splitTile, int kc, int nrows, int wstride,
    int partStride)
{
    __shared__ float xs[128 * 64];
    int tid = threadIdx.x;
    int tile = blockIdx.x, slot = blockIdx.y;
    const float* WT; const float* x; int tLoc;
    if (tile < splitTile) { WT = WTa; x = xa; tLoc = tile; }
    else                  { WT = WTb; x = xb; tLoc = tile - splitTile; }
    int rg = tid & 15, bg = tid >> 4;
    int r0 = tLoc * 128 + rg * 8;
    int b0 = bg * 4;
    int k0 = slot * kc;

    float acc[8][4];
#pragma unroll
    for (int i = 0; i < 8; i++)
#pragma unroll
        for (int j = 0; j < 4; j++) acc[i][j] = 0.f;

    bool fast = (r0 + 7 < nrows);
    int nPhase = kc >> 7;
    for (int ph = 0; ph < nPhase; ++ph) {
        int kp = k0 + ph * 128;
        __syncthreads();
        {
            const float4* src = (const float4*)(x + (size_t)kp * 64);
            float4* dst = (float4*)xs;
#pragma unroll
            for (int i = 0; i < 8; i++) dst[tid + i * 256] = src[tid + i * 256];
        }
        __syncthreads();
        if (fast) {
            const float* wp = WT + (size_t)kp * wstride + r0;
#pragma unroll 4
            for (int k = 0; k < 128; ++k) {
                float4 xv = *(const float4*)&xs[k * 64 + b0];
                float w[8];
                *(float4*)&w[0] = *(const float4*)wp;
                *(float4*)&w[4] = *(const float4*)(wp + 4);
                wp += wstride;
#pragma unroll
                for (int i = 0; i < 8; i++) {
                    acc[i][0] = fmaf(w[i], xv.x, acc[i][0]);
                    acc[i][1] = fmaf(w[i], xv.y, acc[i][1]);
                    acc[i][2] = fmaf(w[i], xv.z, acc[i][2]);
                    acc[i][3] = fmaf(w[i], xv.w, acc[i][3]);
                }
            }
        } else {
            for (int k = 0; k < 128; ++k) {
                float4 xv = *(const float4*)&xs[k * 64 + b0];
                const float* wrow = WT + (size_t)(kp + k) * wstride;
                float w[8];
#pragma unroll
                for (int i = 0; i < 8; i++) {
                    int rc = r0 + i; if (rc > nrows - 1) rc = nrows - 1;
                    w[i] = wrow[rc];
                }
#pragma unroll
                for (int i = 0; i < 8; i++) {
                    acc[i][0] = fmaf(w[i], xv.x, acc[i][0]);
                    acc[i][1] = fmaf(w[i], xv.y, acc[i][1]);
                    acc[i][2] = fmaf(w[i], xv.z, acc[i][2]);
                    acc[i][3] = fmaf(w[i], xv.w, acc[i][3]);
                }
            }
        }
    }

    size_t base = (size_t)slot * partStride + b0;
#pragma unroll
    for (int i = 0; i < 8; i++) {
        int prow = tile * 128 + rg * 8 + i;
        int pc = prow < nrows ? prow : (nrows - 1);
        if (tile >= splitTile) pc = prow;
        *(float4*)&part[base + (size_t)pc * 64] = *(float4*)acc[i];
    }
}

// ---------------------------------------------------------------------------
// melody softmax (tail for t=31 only; 16 slots)
// ---------------------------------------------------------------------------
__global__ __launch_bounds__(256) void mel_smax(
    const float* __restrict__ part, const float* __restrict__ bo1,
    float* __restrict__ outp, int t, int* __restrict__ mel_idx)
{
    int b = blockIdx.x, tid = threadIdx.x;
    float v = -1e30f;
    if (tid < MELn) {
        v = bo1[tid];
#pragma unroll
        for (int s = 0; s < 16; s++) v += part[s * 8320 + tid * 64 + b];
    }
    __shared__ float smax[256];
    __shared__ int   sidx[256];
    __shared__ float ssum[256];
    smax[tid] = v; sidx[tid] = tid;
    __syncthreads();
    for (int s = 128; s > 0; s >>= 1) {
        if (tid < s) {
            float a = smax[tid], o = smax[tid + s];
            int ai = sidx[tid], oi = sidx[tid + s];
            if (o > a || (o == a && oi < ai)) { smax[tid] = o; sidx[tid] = oi; }
        }
        __syncthreads();
    }
    float mx = smax[0]; int am = sidx[0];
    ssum[tid] = (tid < MELn) ? expf(v - mx) : 0.f;
    __syncthreads();
    for (int s = 128; s > 0; s >>= 1) {
        if (tid < s) ssum[tid] += ssum[tid + s];
        __syncthreads();
    }
    float ls = logf(ssum[0]);
    if (tid < MELn) outp[(size_t)b * Tn * MELn + t * MELn + tid] = v - mx - ls;
    if (tid == 0) mel_idx[b] = am;
}

// ---------------------------------------------------------------------------
extern "C" void kernel_launch(void* const* d_in, const int* in_sizes, int n_in,
                              void* d_out, int out_size, void* d_ws, size_t ws_size,
                              hipStream_t stream)
{
    (void)in_sizes; (void)n_in; (void)out_size; (void)ws_size;
    const float* z1    = (const float*)d_in[0];
    const float* z2    = (const float*)d_in[1];
    const float* cond  = (const float*)d_in[2];
    const float* w_ih0 = (const float*)d_in[3];
    const float* w_hh0 = (const float*)d_in[4];
    const float* b_ih0 = (const float*)d_in[5];
    const float* b_hh0 = (const float*)d_in[6];
    const float* w_ih1 = (const float*)d_in[7];
    const float* w_hh1 = (const float*)d_in[8];
    const float* b_ih1 = (const float*)d_in[9];
    const float* b_hh1 = (const float*)d_in[10];
    const float* w_ih2 = (const float*)d_in[11];
    const float* w_hh2 = (const float*)d_in[12];
    const float* b_ih2 = (const float*)d_in[13];
    const float* b_hh2 = (const float*)d_in[14];
    const float* wi0   = (const float*)d_in[15];
    const float* bi0   = (const float*)d_in[16];
    const float* wo0   = (const float*)d_in[17];
    const float* bo0   = (const float*)d_in[18];
    const float* wi1   = (const float*)d_in[19];
    const float* bi1   = (const float*)d_in[20];
    const float* wo1   = (const float*)d_in[21];
    const float* bo1   = (const float*)d_in[22];
    float* outp = (float*)d_out;
    float* ws = (float*)d_ws;

    // workspace layout (floats), ~232 MB
    size_t off = 0;
    float* WT0  = ws + off; off += 12582912;   // w_hh0^T [2048][6144]
    float* WT1  = ws + off; off += 12582912;   // w_hh1^T
    float* WTi2 = ws + off; off += 12582912;   // w_ih2^T
    float* WTh2 = ws + off; off += 12582912;   // w_hh2^T
    float* WTo1 = ws + off; off += 270336;     // wo1^T [2048][132] (padded)
    float* part = ws + off; off += 6291456;    // k-split partials (25 MB)
    float* lpart = ws + off; off += 66560;     // inline logits partials (8 slots)
    float* hR[2] = { ws + off, ws + off + 131072 }; off += 262144;
    float* hA[2] = { ws + off, ws + off + 131072 }; off += 262144;
    float* hB[2] = { ws + off, ws + off + 131072 }; off += 262144;
    float* gi0c   = ws + off; off += 393216;
    float* gi1c   = ws + off; off += 393216;
    float* rlo    = ws + off; off += 6144;     // [32][64][3]
    float* cond_t = ws + off; off += 24576;
    float* z1t    = ws + off; off += 8192;
    float* z2t    = ws + off; off += 8192;
    int* rhy_idx  = (int*)(ws + off); off += 64;
    int* mel_idx  = (int*)(ws + off); off += 64;
    int* cnts     = (int*)(ws + off); off += 64;

    // ---- pre-pass ----
    prep_misc<<<96, 256, 0, stream>>>(z1, z2, cond, z1t, z2t, cond_t, rhy_idx, mel_idx, cnts);
    init_h_k<<<dim3(Hd / 4, 2), 256, 0, stream>>>(z1t, z2t, wi0, bi0, wi1, bi1, hR[0], hA[0]);
    gi_const_k<<<dim3(G3 / 4, 2), 256, 0, stream>>>(z1t, z2t, w_ih0, b_ih0, w_ih1, b_ih1, gi0c, gi1c);
    transpose4_k<<<dim3(32, 96, 4), 256, 0, stream>>>(w_hh0, w_hh1, w_ih2, w_hh2,
                                                      WT0, WT1, WTi2, WTh2);
    transpose1_k<<<dim3(32, 3), 256, 0, stream>>>(wo1, WTo1, MELn, Hd, 132);

    // ---- rhythm decoder ----
    for (int s = 0; s < Tn; s++) {
        const float* h_in = hR[s & 1];
        float* h_out = hR[(s + 1) & 1];
        // GEMM + (s>0) prev-step logits in one dispatch
        mm4rhy_k<<<513, 256, 0, stream>>>(WT0, h_in, part, wo0, bo0,
                                          rlo + (s > 0 ? (s - 1) * 192 : 0),
                                          rhy_idx, s > 0);
        rhy_epi<<<512, 256, 0, stream>>>(part, gi0c, w_ih0, b_hh0, h_in, h_out, rhy_idx);
    }
    // tail: logits for s=31 (h_out of step 31 = hR[0])
    rhy_out_k<<<1, 768, 0, stream>>>(hR[0], wo0, bo0, rlo + 31 * 192, rhy_idx);

    // ---- melody decoder ----
    for (int t = 0; t < Tn; t++) {
        const float* ha_in = hA[t & 1];
        float* ha_out = hA[(t + 1) & 1];
        // GRU1 GEMM + (t>0) prev-step melody logits/softmax in one dispatch
        mm4mel_k<<<528, 256, 0, stream>>>(WT1, ha_in, part, WTo1,
                                          (t > 0) ? hB[t & 1] : ha_in, lpart,
                                          bo1, outp, t - 1, mel_idx, cnts + 0, t > 0);
        mel1_epi<<<512, 256, 0, stream>>>(part, gi1c, w_ih1, b_hh1, ha_in, ha_out,
                                          mel_idx, rlo + t * 192, cond_t + t * (CHn * Bsz));
        const float* hb_in = (t == 0) ? (const float*)ha_out : (const float*)hB[t & 1];
        float* hb_out = hB[(t + 1) & 1];
        mm4_k<<<dim3(64, 8), 256, 0, stream>>>(WTi2, ha_out, WTh2, hb_in, part,
                                               32, 256, 786432);
        mel2_epi<<<512, 256, 0, stream>>>(part, b_ih2, b_hh2, hb_in, hb_out);
    }
    // tail: logits + softmax for t=31 (hb_out of step 31 = hB[0])
    mm2_k<<<dim3(2, 16), 256, 0, stream>>>(WTo1, hB[0], WTo1, hB[0], part,
                                           2, 128, MELn, 132, 8320);
    mel_smax<<<Bsz, 256, 0, stream>>>(part, bo1, outp, 31, mel_idx);
}

// Round 5
// 7327.631 us; speedup vs baseline: 1.3982x; 1.0039x over previous
//
#include <hip/hip_runtime.h>
#include <hip/hip_bf16.h>
#include <math.h>

#define Bsz  64
#define Hd   2048
#define G3   6144
#define MELn 130
#define CHn  12
#define RHYn 3
#define Tn   32

__device__ __forceinline__ float sigf(float x) { return 1.0f / (1.0f + expf(-x)); }

// ---------------------------------------------------------------------------
// prep: transpose z1/z2 -> [128][64], condition -> [T][CH][64], init feedback idx
// ---------------------------------------------------------------------------
__global__ void prep_misc(const float* __restrict__ z1, const float* __restrict__ z2,
                          const float* __restrict__ cond,
                          float* __restrict__ z1t, float* __restrict__ z2t,
                          float* __restrict__ cond_t, int* __restrict__ rhy_idx,
                          int* __restrict__ mel_idx, int* __restrict__ cnts)
{
    int idx = blockIdx.x * 256 + threadIdx.x;
    if (idx < 128 * Bsz) {
        int j = idx >> 6, b = idx & 63;
        z1t[idx] = z1[b * 128 + j];
        z2t[idx] = z2[b * 128 + j];
    }
    if (idx < Tn * CHn * Bsz) {
        int t = idx / (CHn * Bsz);
        int r = idx - t * CHn * Bsz;
        int j = r >> 6, b = r & 63;
        cond_t[idx] = cond[b * (Tn * CHn) + t * CHn + j];
    }
    if (idx < Bsz) { rhy_idx[idx] = RHYn - 1; mel_idx[idx] = MELn - 1; }
    if (idx < 4) cnts[idx] = 0;
}

// ---------------------------------------------------------------------------
// h0 = tanh(z2 @ wi0.T + bi0), h1 = tanh(z1 @ wi1.T + bi1); output [j][b]
// ---------------------------------------------------------------------------
__global__ __launch_bounds__(256) void init_h_k(
    const float* __restrict__ z1t, const float* __restrict__ z2t,
    const float* __restrict__ wi0, const float* __restrict__ bi0,
    const float* __restrict__ wi1, const float* __restrict__ bi1,
    float* __restrict__ h0_out, float* __restrict__ h1_out)
{
    int lane = threadIdx.x & 63, wave = threadIdx.x >> 6;
    int j = blockIdx.x * 4 + wave;
    int which = blockIdx.y;
    const float* zt = which ? z1t : z2t;
    const float* wi = which ? wi1 : wi0;
    const float* bi = which ? bi1 : bi0;
    float* outh = which ? h1_out : h0_out;
    const float4* w4 = (const float4*)(wi + (size_t)j * 128);
    float acc = 0.f;
#pragma unroll 8
    for (int i = 0; i < 32; i++) {
        float4 w = w4[i];
        int k = i * 4;
        acc = fmaf(zt[(k + 0) * 64 + lane], w.x, acc);
        acc = fmaf(zt[(k + 1) * 64 + lane], w.y, acc);
        acc = fmaf(zt[(k + 2) * 64 + lane], w.z, acc);
        acc = fmaf(zt[(k + 3) * 64 + lane], w.w, acc);
    }
    outh[j * 64 + lane] = tanhf(acc + bi[j]);
}

// ---------------------------------------------------------------------------
// step-invariant ih parts (z-terms + bias), layout [row][64]
// ---------------------------------------------------------------------------
__global__ __launch_bounds__(256) void gi_const_k(
    const float* __restrict__ z1t, const float* __restrict__ z2t,
    const float* __restrict__ w_ih0, const float* __restrict__ b_ih0,
    const float* __restrict__ w_ih1, const float* __restrict__ b_ih1,
    float* __restrict__ gi0c, float* __restrict__ gi1c)
{
    int lane = threadIdx.x & 63, wave = threadIdx.x >> 6;
    int row = blockIdx.x * 4 + wave;
    int which = blockIdx.y;
    const float* zt; const float* w; float acc; float* dst;
    if (which == 0) { zt = z2t; w = w_ih0 + (size_t)row * 131 + RHYn;          acc = b_ih0[row]; dst = gi0c; }
    else            { zt = z1t; w = w_ih1 + (size_t)row * 273 + (MELn + RHYn); acc = b_ih1[row]; dst = gi1c; }
#pragma unroll 4
    for (int i = 0; i < 128; i++) acc = fmaf(zt[i * 64 + lane], w[i], acc);
    dst[(size_t)row * 64 + lane] = acc;
}

// ---------------------------------------------------------------------------
// 64x64 tile transpose: in [R][C] -> out [C][Rout] (Rout >= R allows padding)
// ---------------------------------------------------------------------------
__device__ __forceinline__ void transpose_body(
    const float* __restrict__ in, float* __restrict__ out, int R, int C, int Rout,
    int bx, int by, float* tile)
{
    int c0 = bx * 64, r0 = by * 64;
    int t = threadIdx.x;
    int cl = t & 63, rw = t >> 6;
#pragma unroll
    for (int i = 0; i < 16; ++i) {
        int rl = rw + i * 4;
        int r = r0 + rl, c = c0 + cl;
        float v = (r < R && c < C) ? in[(size_t)r * C + c] : 0.f;
        tile[rl * 65 + cl] = v;
    }
    __syncthreads();
#pragma unroll
    for (int i = 0; i < 16; ++i) {
        int c_loc = rw + i * 4;
        int r_loc = cl;
        int oc = c0 + c_loc, orow = r0 + r_loc;
        if (oc < C && orow < R)
            out[(size_t)oc * Rout + orow] = tile[r_loc * 65 + c_loc];
    }
}

__global__ __launch_bounds__(256) void transpose4_k(
    const float* __restrict__ a, const float* __restrict__ b,
    const float* __restrict__ c, const float* __restrict__ d,
    float* __restrict__ oa, float* __restrict__ ob,
    float* __restrict__ oc, float* __restrict__ od)
{
    __shared__ float tile[64 * 65];
    const float* in; float* out;
    switch (blockIdx.z) {
        case 0: in = a; out = oa; break;
        case 1: in = b; out = ob; break;
        case 2: in = c; out = oc; break;
        default: in = d; out = od; break;
    }
    transpose_body(in, out, G3, Hd, G3, blockIdx.x, blockIdx.y, tile);
}

__global__ __launch_bounds__(256) void transpose1_k(
    const float* __restrict__ in, float* __restrict__ out, int R, int C, int Rout)
{
    __shared__ float tile[64 * 65];
    transpose_body(in, out, R, C, Rout, blockIdx.x, blockIdx.y, tile);
}

// ---------------------------------------------------------------------------
// mm4 GEMM body (single matrix, kc=128, one phase). Partial layout:
// part[slot*393216 + prow*64 + b]; bit-identical to earlier rounds.
// ---------------------------------------------------------------------------
__device__ __forceinline__ void mm4_body(
    const float* __restrict__ WT, const float* __restrict__ x,
    float* __restrict__ part, int tile, int slot, float* xs)
{
    int tid = threadIdx.x;
    int rg = tid & 15, bg = tid >> 4;
    int r0 = tile * 192 + rg * 12;
    int b0 = bg * 4;
    int kp = slot * 128;

    float acc[12][4];
#pragma unroll
    for (int i = 0; i < 12; i++)
#pragma unroll
        for (int j = 0; j < 4; j++) acc[i][j] = 0.f;

    {
        const float4* src = (const float4*)(x + (size_t)kp * 64);
        float4* dst = (float4*)xs;
#pragma unroll
        for (int i = 0; i < 8; i++) dst[tid + i * 256] = src[tid + i * 256];
    }
    __syncthreads();
    const float* wp = WT + (size_t)kp * G3 + r0;
#pragma unroll 2
    for (int k = 0; k < 128; ++k) {
        float4 xv = *(const float4*)&xs[k * 64 + b0];
        float w[12];
        *(float4*)&w[0] = *(const float4*)(wp);
        *(float4*)&w[4] = *(const float4*)(wp + 4);
        *(float4*)&w[8] = *(const float4*)(wp + 8);
        wp += G3;
#pragma unroll
        for (int i = 0; i < 12; i++) {
            acc[i][0] = fmaf(w[i], xv.x, acc[i][0]);
            acc[i][1] = fmaf(w[i], xv.y, acc[i][1]);
            acc[i][2] = fmaf(w[i], xv.z, acc[i][2]);
            acc[i][3] = fmaf(w[i], xv.w, acc[i][3]);
        }
    }

    size_t base = (size_t)slot * 393216 + b0;
    int prow0 = tile * 192 + rg * 12;
#pragma unroll
    for (int i = 0; i < 12; i++)
        *(float4*)&part[base + (size_t)(prow0 + i) * 64] = *(float4*)&acc[i][0];
}

// ---------------------------------------------------------------------------
// fusedA: rhythm GEMM(u) [blk 0..511] + rhythm logits(u-1) [blk 512] +
//         melody GRU1 GEMM(u-1) [blk 513..1024] + melody logits(u-2)
//         [blk 1025..1040, fenced last-block finalize].
// flags: bit0 doRhy, bit1 doRlog, bit2 doMel, bit3 doMlog
// ---------------------------------------------------------------------------
__global__ __launch_bounds__(256, 4) void fusedA_k(
    const float* __restrict__ WT0h, const float* __restrict__ hr, float* __restrict__ partR,
    const float* __restrict__ wo0, const float* __restrict__ bo0,
    float* __restrict__ rlo_prev, int* __restrict__ rhy_idx,
    const float* __restrict__ WT1h, const float* __restrict__ ha, float* __restrict__ partM,
    const float* __restrict__ WTo1, const float* __restrict__ hbPrev,
    float* __restrict__ lpart, const float* __restrict__ bo1,
    float* __restrict__ outp, int tout, int* __restrict__ mel_idx,
    int* __restrict__ cnt, int flags)
{
    __shared__ float smem[8704];
    int flat = blockIdx.x, tid = threadIdx.x;

    if (flat < 512) {                         // rhythm GEMM
        if (!(flags & 1)) return;
        mm4_body(WT0h, hr, partR, flat & 31, flat >> 5, smem);
        return;
    }
    if (flat == 512) {                        // rhythm logits (step u-1)
        if (!(flags & 2)) return;
        int lane = tid & 63, wv = tid >> 6;
        const float* hc = hr + wv * 512 * 64;
        const float* w0 = wo0 + wv * 512;
        const float* w1 = wo0 + Hd + wv * 512;
        const float* w2 = wo0 + 2 * Hd + wv * 512;
        float a0 = 0.f, a1 = 0.f, a2 = 0.f;
#pragma unroll 4
        for (int k = 0; k < 512; k++) {
            float hv = hc[k * 64 + lane];
            a0 = fmaf(hv, w0[k], a0);
            a1 = fmaf(hv, w1[k], a1);
            a2 = fmaf(hv, w2[k], a2);
        }
        smem[(0 * 4 + wv) * 64 + lane] = a0;
        smem[(1 * 4 + wv) * 64 + lane] = a1;
        smem[(2 * 4 + wv) * 64 + lane] = a2;
        __syncthreads();
        if (wv == 0) {
            float l0 = smem[0 * 64 + lane] + smem[1 * 64 + lane] + smem[2 * 64 + lane] + smem[3 * 64 + lane] + bo0[0];
            float l1 = smem[4 * 64 + lane] + smem[5 * 64 + lane] + smem[6 * 64 + lane] + smem[7 * 64 + lane] + bo0[1];
            float l2 = smem[8 * 64 + lane] + smem[9 * 64 + lane] + smem[10 * 64 + lane] + smem[11 * 64 + lane] + bo0[2];
            int am; float mx;
            if (l0 >= l1 && l0 >= l2) { am = 0; mx = l0; }
            else if (l1 >= l2)        { am = 1; mx = l1; }
            else                      { am = 2; mx = l2; }
            float s = expf(l0 - mx) + expf(l1 - mx) + expf(l2 - mx);
            float ls = logf(s);
            rlo_prev[lane * 3 + 0] = l0 - mx - ls;
            rlo_prev[lane * 3 + 1] = l1 - mx - ls;
            rlo_prev[lane * 3 + 2] = l2 - mx - ls;
            rhy_idx[lane] = am;
        }
        return;
    }
    if (flat < 1025) {                        // melody GRU1 GEMM
        if (!(flags & 4)) return;
        int idx = flat - 513;
        mm4_body(WT1h, ha, partM, idx & 31, idx >> 5, smem);
        return;
    }
    // melody logits (output step u-2)
    if (!(flags & 8)) return;
    int li = flat - 1025;                     // 0..15
    int ltile = li & 1, lslot = li >> 1;
    int rg = tid & 15, bg = tid >> 4;
    int r0 = ltile * 128 + rg * 8;
    int b0 = bg * 4;
    int k0 = lslot * 256;

    float acc[8][4];
#pragma unroll
    for (int i = 0; i < 8; i++)
#pragma unroll
        for (int j = 0; j < 4; j++) acc[i][j] = 0.f;

    bool fast = (r0 + 7 < MELn);
    for (int ph = 0; ph < 2; ++ph) {
        int kp = k0 + ph * 128;
        __syncthreads();
        {
            const float4* src = (const float4*)(hbPrev + (size_t)kp * 64);
            float4* dst = (float4*)smem;
#pragma unroll
            for (int i = 0; i < 8; i++) dst[tid + i * 256] = src[tid + i * 256];
        }
        __syncthreads();
        if (fast) {
            const float* wp = WTo1 + (size_t)kp * 132 + r0;
#pragma unroll 4
            for (int k = 0; k < 128; ++k) {
                float4 xv = *(const float4*)&smem[k * 64 + b0];
                float w[8];
                *(float4*)&w[0] = *(const float4*)wp;
                *(float4*)&w[4] = *(const float4*)(wp + 4);
                wp += 132;
#pragma unroll
                for (int i = 0; i < 8; i++) {
                    acc[i][0] = fmaf(w[i], xv.x, acc[i][0]);
                    acc[i][1] = fmaf(w[i], xv.y, acc[i][1]);
                    acc[i][2] = fmaf(w[i], xv.z, acc[i][2]);
                    acc[i][3] = fmaf(w[i], xv.w, acc[i][3]);
                }
            }
        } else {
            for (int k = 0; k < 128; ++k) {
                float4 xv = *(const float4*)&smem[k * 64 + b0];
                const float* wrow = WTo1 + (size_t)(kp + k) * 132;
                float w[8];
#pragma unroll
                for (int i = 0; i < 8; i++) {
                    int rc = r0 + i; if (rc > MELn - 1) rc = MELn - 1;
                    w[i] = wrow[rc];
                }
#pragma unroll
                for (int i = 0; i < 8; i++) {
                    acc[i][0] = fmaf(w[i], xv.x, acc[i][0]);
                    acc[i][1] = fmaf(w[i], xv.y, acc[i][1]);
                    acc[i][2] = fmaf(w[i], xv.z, acc[i][2]);
                    acc[i][3] = fmaf(w[i], xv.w, acc[i][3]);
                }
            }
        }
    }
    size_t base = (size_t)lslot * 8320 + b0;
#pragma unroll
    for (int i = 0; i < 8; i++) {
        int prow = ltile * 128 + rg * 8 + i;
        int pc = prow < MELn ? prow : (MELn - 1);
        *(float4*)&lpart[base + (size_t)pc * 64] = *(float4*)acc[i];
    }

    // last-block finalize (fenced)
    __shared__ int lastf;
    __threadfence();
    __syncthreads();
    if (tid == 0) lastf = (atomicAdd(cnt, 1) == 15);
    __syncthreads();
    if (!lastf) return;
    __threadfence();

    for (int e = tid; e < MELn * 64; e += 256) {
        int r = e >> 6, b = e & 63;
        float v = bo1[r];
#pragma unroll
        for (int s = 0; s < 8; s++) v += lpart[s * 8320 + r * 64 + b];
        smem[e] = v;
    }
    __syncthreads();
    if (tid < 64) {
        int b = tid;
        float mx = -1e30f; int am = 0;
        for (int r = 0; r < MELn; r++) {
            float v = smem[r * 64 + b];
            if (v > mx) { mx = v; am = r; }
        }
        float ssum = 0.f;
        for (int r = 0; r < MELn; r++) ssum += expf(smem[r * 64 + b] - mx);
        smem[8320 + b] = mx;
        smem[8384 + b] = logf(ssum);
        mel_idx[b] = am;
    }
    __syncthreads();
    for (int e = tid; e < MELn * 64; e += 256) {
        int r = e >> 6, b = e & 63;
        outp[(size_t)b * Tn * MELn + tout * MELn + r] = smem[e] - smem[8320 + b] - smem[8384 + b];
    }
    __syncthreads();
    if (tid == 0) *cnt = 0;
}

// ---------------------------------------------------------------------------
// fusedB: rhy_epi(u) [blk 0..511] + mel1_epi(u-1) [blk 512..1023]
// flags: bit0 rhy, bit1 mel
// ---------------------------------------------------------------------------
__global__ __launch_bounds__(256) void fusedB_k(
    const float* __restrict__ partR, const float* __restrict__ gi0c,
    const float* __restrict__ w_ih0, const float* __restrict__ b_hh0,
    const float* __restrict__ hr_in, float* __restrict__ hr_out,
    const int* __restrict__ rhy_idx,
    const float* __restrict__ partM, const float* __restrict__ gi1c,
    const float* __restrict__ w_ih1, const float* __restrict__ b_hh1,
    const float* __restrict__ ha_in, float* __restrict__ ha_out,
    const int* __restrict__ mel_idx, const float* __restrict__ rlo,
    const float* __restrict__ cdt, int flags)
{
    __shared__ float red[48 * 68];
    int flat = blockIdx.x, tid = threadIdx.x;
    int wv = tid >> 6, lane = tid & 63;
    int jj = lane >> 4, bq = lane & 15;
    int isMel = (flat >= 512);
    if (isMel) { if (!(flags & 2)) return; }
    else       { if (!(flags & 1)) return; }
    int jbase = (isMel ? flat - 512 : flat) * 4;
    const float* part = isMel ? partM : partR;

    float s0[4], s1[4], s2[4];
#pragma unroll
    for (int q = 0; q < 4; q++) { s0[q] = 0.f; s1[q] = 0.f; s2[q] = 0.f; }
#pragma unroll
    for (int ss = 0; ss < 4; ss++) {
        const float* p = part + (size_t)(wv * 4 + ss) * 393216
                       + (size_t)(jbase + jj) * 64 + bq * 4;
        float4 v0 = *(const float4*)(p);
        float4 v1 = *(const float4*)(p + 2048 * 64);
        float4 v2 = *(const float4*)(p + 4096 * 64);
        s0[0] += v0.x; s0[1] += v0.y; s0[2] += v0.z; s0[3] += v0.w;
        s1[0] += v1.x; s1[1] += v1.y; s1[2] += v1.z; s1[3] += v1.w;
        s2[0] += v2.x; s2[1] += v2.y; s2[2] += v2.z; s2[3] += v2.w;
    }
    int rbase = (wv * 4 + jj) * 3;
    *(float4*)&red[(rbase + 0) * 68 + bq * 4] = make_float4(s0[0], s0[1], s0[2], s0[3]);
    *(float4*)&red[(rbase + 1) * 68 + bq * 4] = make_float4(s1[0], s1[1], s1[2], s1[3]);
    *(float4*)&red[(rbase + 2) * 68 + bq * 4] = make_float4(s2[0], s2[1], s2[2], s2[3]);
    __syncthreads();

    int b = lane, jw = wv;
    int j = jbase + jw;
    float ar = 0.f, az = 0.f, an = 0.f;
#pragma unroll
    for (int ww = 0; ww < 4; ww++) {
        int rb = (ww * 4 + jw) * 3;
        ar += red[(rb + 0) * 68 + b];
        az += red[(rb + 1) * 68 + b];
        an += red[(rb + 2) * 68 + b];
    }

    if (!isMel) {
        int oi = rhy_idx[b];
        float gir = gi0c[j * 64 + b]            + w_ih0[(size_t)j * 131 + oi];
        float giz = gi0c[(j + 2048) * 64 + b]   + w_ih0[(size_t)(j + 2048) * 131 + oi];
        float gin = gi0c[(j + 4096) * 64 + b]   + w_ih0[(size_t)(j + 4096) * 131 + oi];
        float rg = sigf(gir + ar + b_hh0[j]);
        float ug = sigf(giz + az + b_hh0[j + 2048]);
        float ng = tanhf(gin + rg * (an + b_hh0[j + 4096]));
        float hp = hr_in[j * 64 + b];
        hr_out[j * 64 + b] = (1.f - ug) * ng + ug * hp;
    } else {
        int oi = mel_idx[b];
        float r0 = rlo[b * 3 + 0], r1 = rlo[b * 3 + 1], r2 = rlo[b * 3 + 2];
        float cd[12];
#pragma unroll
        for (int q = 0; q < 12; q++) cd[q] = cdt[q * 64 + b];
        float gi[3];
#pragma unroll
        for (int g = 0; g < 3; g++) {
            int row = j + g * 2048;
            const float* wrow = w_ih1 + (size_t)row * 273;
            float v = gi1c[row * 64 + b] + wrow[oi];
            v = fmaf(r0, wrow[130], v);
            v = fmaf(r1, wrow[131], v);
            v = fmaf(r2, wrow[132], v);
#pragma unroll
            for (int q = 0; q < 12; q++) v = fmaf(cd[q], wrow[261 + q], v);
            gi[g] = v;
        }
        float rg = sigf(gi[0] + ar + b_hh1[j]);
        float ug = sigf(gi[1] + az + b_hh1[j + 2048]);
        float ng = tanhf(gi[2] + rg * (an + b_hh1[j + 4096]));
        float hp = ha_in[j * 64 + b];
        ha_out[j * 64 + b] = (1.f - ug) * ng + ug * hp;
    }
}

// ---------------------------------------------------------------------------
// GRU2 fused two-matrix GEMM, retiled 96 tiles(128 rows) x 8 slots = 768 blk
// (3/CU). Per-(row,b,slot) sums bitwise identical to the 192-row tiling.
// ---------------------------------------------------------------------------
__global__ __launch_bounds__(256, 4) void mm4g2_k(
    const float* __restrict__ WTa, const float* __restrict__ xa,
    const float* __restrict__ WTb, const float* __restrict__ xb,
    float* __restrict__ part)
{
    __shared__ float xs[128 * 64];
    int tid = threadIdx.x;
    int tile = blockIdx.x, slot = blockIdx.y;
    const float* WT; const float* x; int tLoc;
    if (tile < 48) { WT = WTa; x = xa; tLoc = tile; }
    else           { WT = WTb; x = xb; tLoc = tile - 48; }
    int rg = tid & 15, bg = tid >> 4;
    int r0 = tLoc * 128 + rg * 8;
    int b0 = bg * 4;
    int k0 = slot * 256;

    float acc[8][4];
#pragma unroll
    for (int i = 0; i < 8; i++)
#pragma unroll
        for (int j = 0; j < 4; j++) acc[i][j] = 0.f;

    for (int ph = 0; ph < 2; ++ph) {
        int kp = k0 + ph * 128;
        __syncthreads();
        {
            const float4* src = (const float4*)(x + (size_t)kp * 64);
            float4* dst = (float4*)xs;
#pragma unroll
            for (int i = 0; i < 8; i++) dst[tid + i * 256] = src[tid + i * 256];
        }
        __syncthreads();
        const float* wp = WT + (size_t)kp * G3 + r0;
#pragma unroll 2
        for (int k = 0; k < 128; ++k) {
            float4 xv = *(const float4*)&xs[k * 64 + b0];
            float w[8];
            *(float4*)&w[0] = *(const float4*)wp;
            *(float4*)&w[4] = *(const float4*)(wp + 4);
            wp += G3;
#pragma unroll
            for (int i = 0; i < 8; i++) {
                acc[i][0] = fmaf(w[i], xv.x, acc[i][0]);
                acc[i][1] = fmaf(w[i], xv.y, acc[i][1]);
                acc[i][2] = fmaf(w[i], xv.z, acc[i][2]);
                acc[i][3] = fmaf(w[i], xv.w, acc[i][3]);
            }
        }
    }

    size_t base = (size_t)slot * 786432 + b0;
    int prow0 = tile * 128 + rg * 8;
#pragma unroll
    for (int i = 0; i < 8; i++)
        *(float4*)&part[base + (size_t)(prow0 + i) * 64] = *(float4*)acc[i];
}

// ---------------------------------------------------------------------------
// melody GRU2 epilogue, phase-split (unchanged)
// ---------------------------------------------------------------------------
__global__ __launch_bounds__(256) void mel2_epi(
    const float* __restrict__ part, const float* __restrict__ b_ih,
    const float* __restrict__ b_hh, const float* __restrict__ hb_in,
    float* __restrict__ hb_out)
{
    __shared__ float red[96 * 68];
    int tid = threadIdx.x;
    int wv = tid >> 6, lane = tid & 63;
    int jj = lane >> 4, bq = lane & 15;
    int jbase = blockIdx.x * 4;

    float s[6][4];
#pragma unroll
    for (int g = 0; g < 6; g++)
#pragma unroll
        for (int q = 0; q < 4; q++) s[g][q] = 0.f;
#pragma unroll
    for (int ss = 0; ss < 2; ss++) {
        const float* p = part + (size_t)(wv * 2 + ss) * 786432
                       + (size_t)(jbase + jj) * 64 + bq * 4;
#pragma unroll
        for (int g = 0; g < 6; g++) {
            float4 v = *(const float4*)(p + (size_t)g * 2048 * 64);
            s[g][0] += v.x; s[g][1] += v.y; s[g][2] += v.z; s[g][3] += v.w;
        }
    }
    int rbase = (wv * 4 + jj) * 6;
#pragma unroll
    for (int g = 0; g < 6; g++)
        *(float4*)&red[(rbase + g) * 68 + bq * 4] = make_float4(s[g][0], s[g][1], s[g][2], s[g][3]);
    __syncthreads();

    int b = lane, jw = wv;
    int j = jbase + jw;
    float air = 0.f, aiz = 0.f, ain = 0.f, ahr = 0.f, ahz = 0.f, ahn = 0.f;
#pragma unroll
    for (int ww = 0; ww < 4; ww++) {
        int rb = (ww * 4 + jw) * 6;
        air += red[(rb + 0) * 68 + b];
        aiz += red[(rb + 1) * 68 + b];
        ain += red[(rb + 2) * 68 + b];
        ahr += red[(rb + 3) * 68 + b];
        ahz += red[(rb + 4) * 68 + b];
        ahn += red[(rb + 5) * 68 + b];
    }
    float rg = sigf(air + b_ih[j] + ahr + b_hh[j]);
    float ug = sigf(aiz + b_ih[j + 2048] + ahz + b_hh[j + 2048]);
    float ng = tanhf(ain + b_ih[j + 4096] + rg * (ahn + b_hh[j + 4096]));
    float hp = hb_in[j * 64 + b];
    hb_out[j * 64 + b] = (1.f - ug) * ng + ug * hp;
}

// ---------------------------------------------------------------------------
// mm2_k: small logits GEMM (tail for t=31, 16 slots kc=128)
// ---------------------------------------------------------------------------
__global__ __launch_bounds__(256) void mm2_k(
    const float* __restrict__ WTa, const float* __restrict__ xa,
    const float* __restrict__ WTb, const float* __restrict__ xb,
    float* __restrict__ part, int splitTile, int kc, int nrows, int wstride,
    int partStride)
{
    __shared__ float xs[128 * 64];
    int tid = threadIdx.x;
    int tile = blockIdx.x, slot = blockIdx.y;
    const float* WT; const float* x; int tLoc;
    if (tile < splitTile) { WT = WTa; x = xa; tLoc = tile; }
    else                  { WT = WTb; x = xb; tLoc = tile - splitTile; }
    int rg = tid & 15, bg = tid >> 4;
    int r0 = tLoc * 128 + rg * 8;
    int b0 = bg * 4;
    int k0 = slot * kc;

    float acc[8][4];
#pragma unroll
    for (int i = 0; i < 8; i++)
#pragma unroll
        for (int j = 0; j < 4; j++) acc[i][j] = 0.f;

    bool fast = (r0 + 7 < nrows);
    int nPhase = kc >> 7;
    for (int ph = 0; ph < nPhase; ++ph) {
        int kp = k0 + ph * 128;
        __syncthreads();
        {
            const float4* src = (const float4*)(x + (size_t)kp * 64);
            float4* dst = (float4*)xs;
#pragma unroll
            for (int i = 0; i < 8; i++) dst[tid + i * 256] = src[tid + i * 256];
        }
        __syncthreads();
        if (fast) {
            const float* wp = WT + (size_t)kp * wstride + r0;
#pragma unroll 4
            for (int k = 0; k < 128; ++k) {
                float4 xv = *(const float4*)&xs[k * 64 + b0];
                float w[8];
                *(float4*)&w[0] = *(const float4*)wp;
                *(float4*)&w[4] = *(const float4*)(wp + 4);
                wp += wstride;
#pragma unroll
                for (int i = 0; i < 8; i++) {
                    acc[i][0] = fmaf(w[i], xv.x, acc[i][0]);
                    acc[i][1] = fmaf(w[i], xv.y, acc[i][1]);
                    acc[i][2] = fmaf(w[i], xv.z, acc[i][2]);
                    acc[i][3] = fmaf(w[i], xv.w, acc[i][3]);
                }
            }
        } else {
            for (int k = 0; k < 128; ++k) {
                float4 xv = *(const float4*)&xs[k * 64 + b0];
                const float* wrow = WT + (size_t)(kp + k) * wstride;
                float w[8];
#pragma unroll
                for (int i = 0; i < 8; i++) {
                    int rc = r0 + i; if (rc > nrows - 1) rc = nrows - 1;
                    w[i] = wrow[rc];
                }
#pragma unroll
                for (int i = 0; i < 8; i++) {
                    acc[i][0] = fmaf(w[i], xv.x, acc[i][0]);
                    acc[i][1] = fmaf(w[i], xv.y, acc[i][1]);
                    acc[i][2] = fmaf(w[i], xv.z, acc[i][2]);
                    acc[i][3] = fmaf(w[i], xv.w, acc[i][3]);
                }
            }
        }
    }

    size_t base = (size_t)slot * partStride + b0;
#pragma unroll
    for (int i = 0; i < 8; i++) {
        int prow = tile * 128 + rg * 8 + i;
        int pc = prow < nrows ? prow : (nrows - 1);
        if (tile >= splitTile) pc = prow;
        *(float4*)&part[base + (size_t)pc * 64] = *(float4*)acc[i];
    }
}

// ---------------------------------------------------------------------------
// melody softmax (tail for t=31; 16 slots)
// ---------------------------------------------------------------------------
__global__ __launch_bounds__(256) void mel_smax(
    const float* __restrict__ part, const float* __restrict__ bo1,
    float* __restrict__ outp, int t, int* __restrict__ mel_idx)
{
    int b = blockIdx.x, tid = threadIdx.x;
    float v = -1e30f;
    if (tid < MELn) {
        v = bo1[tid];
#pragma unroll
        for (int s = 0; s < 16; s++) v += part[s * 8320 + tid * 64 + b];
    }
    __shared__ float smax[256];
    __shared__ int   sidx[256];
    __shared__ float ssum[256];
    smax[tid] = v; sidx[tid] = tid;
    __syncthreads();
    for (int s = 128; s > 0; s >>= 1) {
        if (tid < s) {
            float a = smax[tid], o = smax[tid + s];
            int ai = sidx[tid], oi = sidx[tid + s];
            if (o > a || (o == a && oi < ai)) { smax[tid] = o; sidx[tid] = oi; }
        }
        __syncthreads();
    }
    float mx = smax[0]; int am = sidx[0];
    ssum[tid] = (tid < MELn) ? expf(v - mx) : 0.f;
    __syncthreads();
    for (int s = 128; s > 0; s >>= 1) {
        if (tid < s) ssum[tid] += ssum[tid + s];
        __syncthreads();
    }
    float ls = logf(ssum[0]);
    if (tid < MELn) outp[(size_t)b * Tn * MELn + t * MELn + tid] = v - mx - ls;
    if (tid == 0) mel_idx[b] = am;
}

// ---------------------------------------------------------------------------
extern "C" void kernel_launch(void* const* d_in, const int* in_sizes, int n_in,
                              void* d_out, int out_size, void* d_ws, size_t ws_size,
                              hipStream_t stream)
{
    (void)in_sizes; (void)n_in; (void)out_size; (void)ws_size;
    const float* z1    = (const float*)d_in[0];
    const float* z2    = (const float*)d_in[1];
    const float* cond  = (const float*)d_in[2];
    const float* w_ih0 = (const float*)d_in[3];
    const float* w_hh0 = (const float*)d_in[4];
    const float* b_ih0 = (const float*)d_in[5];
    const float* b_hh0 = (const float*)d_in[6];
    const float* w_ih1 = (const float*)d_in[7];
    const float* w_hh1 = (const float*)d_in[8];
    const float* b_ih1 = (const float*)d_in[9];
    const float* b_hh1 = (const float*)d_in[10];
    const float* w_ih2 = (const float*)d_in[11];
    const float* w_hh2 = (const float*)d_in[12];
    const float* b_ih2 = (const float*)d_in[13];
    const float* b_hh2 = (const float*)d_in[14];
    const float* wi0   = (const float*)d_in[15];
    const float* bi0   = (const float*)d_in[16];
    const float* wo0   = (const float*)d_in[17];
    const float* bo0   = (const float*)d_in[18];
    const float* wi1   = (const float*)d_in[19];
    const float* bi1   = (const float*)d_in[20];
    const float* wo1   = (const float*)d_in[21];
    const float* bo1   = (const float*)d_in[22];
    float* outp = (float*)d_out;
    float* ws = (float*)d_ws;

    // workspace layout (floats), ~260 MB
    size_t off = 0;
    float* WT0  = ws + off; off += 12582912;   // w_hh0^T [2048][6144]
    float* WT1  = ws + off; off += 12582912;   // w_hh1^T
    float* WTi2 = ws + off; off += 12582912;   // w_ih2^T
    float* WTh2 = ws + off; off += 12582912;   // w_hh2^T
    float* WTo1 = ws + off; off += 270336;     // wo1^T [2048][132] (padded)
    float* bufR  = ws + off; off += 6291456;   // rhythm partials (16 slots)
    float* bufMG = ws + off; off += 6291456;   // GRU1 partials / GRU2 partials (time-shared)
    float* lpart = ws + off; off += 66560;     // inline logits partials (8 slots)
    float* hR[2] = { ws + off, ws + off + 131072 }; off += 262144;
    float* hA[2] = { ws + off, ws + off + 131072 }; off += 262144;
    float* hB[2] = { ws + off, ws + off + 131072 }; off += 262144;
    float* gi0c   = ws + off; off += 393216;
    float* gi1c   = ws + off; off += 393216;
    float* rlo    = ws + off; off += 6144;     // [32][64][3]
    float* cond_t = ws + off; off += 24576;
    float* z1t    = ws + off; off += 8192;
    float* z2t    = ws + off; off += 8192;
    int* rhy_idx  = (int*)(ws + off); off += 64;
    int* mel_idx  = (int*)(ws + off); off += 64;
    int* cnts     = (int*)(ws + off); off += 64;

    // ---- pre-pass ----
    prep_misc<<<96, 256, 0, stream>>>(z1, z2, cond, z1t, z2t, cond_t, rhy_idx, mel_idx, cnts);
    init_h_k<<<dim3(Hd / 4, 2), 256, 0, stream>>>(z1t, z2t, wi0, bi0, wi1, bi1, hR[0], hA[0]);
    gi_const_k<<<dim3(G3 / 4, 2), 256, 0, stream>>>(z1t, z2t, w_ih0, b_ih0, w_ih1, b_ih1, gi0c, gi1c);
    transpose4_k<<<dim3(32, 96, 4), 256, 0, stream>>>(w_hh0, w_hh1, w_ih2, w_hh2,
                                                      WT0, WT1, WTi2, WTh2);
    transpose1_k<<<dim3(32, 3), 256, 0, stream>>>(wo1, WTo1, MELn, Hd, 132);

    // ---- merged decoder pipeline: iteration u runs rhythm step u and melody step u-1 ----
    for (int u = 0; u <= Tn; u++) {
        int doRhy  = (u < Tn) ? 1 : 0;
        int doRlog = (u >= 1) ? 1 : 0;
        int doMel  = (u >= 1) ? 1 : 0;
        int doMlog = (u >= 2) ? 1 : 0;
        int flagsA = doRhy | (doRlog << 1) | (doMel << 2) | (doMlog << 3);

        const float* hr = hR[u & 1];
        const float* ha_in = (u >= 1) ? hA[(u - 1) & 1] : hA[0];
        const float* hbPrev = (u >= 2) ? hB[(u - 1) & 1] : hB[0];
        float* rloPrev = rlo + (size_t)(u >= 1 ? u - 1 : 0) * 192;

        fusedA_k<<<1041, 256, 0, stream>>>(WT0, hr, bufR, wo0, bo0, rloPrev, rhy_idx,
                                           WT1, ha_in, bufMG, WTo1, hbPrev, lpart, bo1,
                                           outp, u - 2, mel_idx, cnts + 0, flagsA);

        fusedB_k<<<1024, 256, 0, stream>>>(bufR, gi0c, w_ih0, b_hh0, hr, hR[(u + 1) & 1],
                                           rhy_idx, bufMG, gi1c, w_ih1, b_hh1,
                                           ha_in, hA[u & 1], mel_idx, rloPrev,
                                           cond_t + (size_t)(u >= 1 ? u - 1 : 0) * (CHn * Bsz),
                                           doRhy | (doMel << 1));

        if (u >= 1) {
            // melody step t = u-1 GRU2: ih2 x ha(t+1) fused with hh2 x hb(t)
            const float* hbop = (u == 1) ? (const float*)hA[u & 1] : (const float*)hB[(u - 1) & 1];
            mm4g2_k<<<dim3(96, 8), 256, 0, stream>>>(WTi2, hA[u & 1], WTh2, hbop, bufMG);
            mel2_epi<<<512, 256, 0, stream>>>(bufMG, b_ih2, b_hh2, hbop, hB[u & 1]);
        }
    }

    // ---- tail: melody logits + softmax for t=31 (hbState(32) = hB[0]) ----
    mm2_k<<<dim3(2, 16), 256, 0, stream>>>(WTo1, hB[0], WTo1, hB[0], bufR,
                                           2, 128, MELn, 132, 8320);
    mel_smax<<<Bsz, 256, 0, stream>>>(bufR, bo1, outp, 31, mel_idx);
}

// Round 6
// 5888.235 us; speedup vs baseline: 1.7400x; 1.2445x over previous
//
#include <hip/hip_runtime.h>
#include <hip/hip_bf16.h>
#include <math.h>

#define Bsz  64
#define Hd   2048
#define G3   6144
#define MELn 130
#define CHn  12
#define RHYn 3
#define Tn   32

__device__ __forceinline__ float sigf(float x) { return 1.0f / (1.0f + expf(-x)); }

// ---------------------------------------------------------------------------
// prep: transpose z1/z2 -> [128][64], condition -> [T][CH][64], init feedback idx
// ---------------------------------------------------------------------------
__global__ void prep_misc(const float* __restrict__ z1, const float* __restrict__ z2,
                          const float* __restrict__ cond,
                          float* __restrict__ z1t, float* __restrict__ z2t,
                          float* __restrict__ cond_t, int* __restrict__ rhy_idx,
                          int* __restrict__ mel_idx, int* __restrict__ cnts)
{
    int idx = blockIdx.x * 256 + threadIdx.x;
    if (idx < 128 * Bsz) {
        int j = idx >> 6, b = idx & 63;
        z1t[idx] = z1[b * 128 + j];
        z2t[idx] = z2[b * 128 + j];
    }
    if (idx < Tn * CHn * Bsz) {
        int t = idx / (CHn * Bsz);
        int r = idx - t * CHn * Bsz;
        int j = r >> 6, b = r & 63;
        cond_t[idx] = cond[b * (Tn * CHn) + t * CHn + j];
    }
    if (idx < Bsz) { rhy_idx[idx] = RHYn - 1; mel_idx[idx] = MELn - 1; }
    if (idx < 4) cnts[idx] = 0;
}

// ---------------------------------------------------------------------------
// h0 = tanh(z2 @ wi0.T + bi0), h1 = tanh(z1 @ wi1.T + bi1); output [j][b]
// ---------------------------------------------------------------------------
__global__ __launch_bounds__(256) void init_h_k(
    const float* __restrict__ z1t, const float* __restrict__ z2t,
    const float* __restrict__ wi0, const float* __restrict__ bi0,
    const float* __restrict__ wi1, const float* __restrict__ bi1,
    float* __restrict__ h0_out, float* __restrict__ h1_out)
{
    int lane = threadIdx.x & 63, wave = threadIdx.x >> 6;
    int j = blockIdx.x * 4 + wave;
    int which = blockIdx.y;
    const float* zt = which ? z1t : z2t;
    const float* wi = which ? wi1 : wi0;
    const float* bi = which ? bi1 : bi0;
    float* outh = which ? h1_out : h0_out;
    const float4* w4 = (const float4*)(wi + (size_t)j * 128);
    float acc = 0.f;
#pragma unroll 8
    for (int i = 0; i < 32; i++) {
        float4 w = w4[i];
        int k = i * 4;
        acc = fmaf(zt[(k + 0) * 64 + lane], w.x, acc);
        acc = fmaf(zt[(k + 1) * 64 + lane], w.y, acc);
        acc = fmaf(zt[(k + 2) * 64 + lane], w.z, acc);
        acc = fmaf(zt[(k + 3) * 64 + lane], w.w, acc);
    }
    outh[j * 64 + lane] = tanhf(acc + bi[j]);
}

// ---------------------------------------------------------------------------
// step-invariant ih parts (z-terms + bias), layout [row][64]
// ---------------------------------------------------------------------------
__global__ __launch_bounds__(256) void gi_const_k(
    const float* __restrict__ z1t, const float* __restrict__ z2t,
    const float* __restrict__ w_ih0, const float* __restrict__ b_ih0,
    const float* __restrict__ w_ih1, const float* __restrict__ b_ih1,
    float* __restrict__ gi0c, float* __restrict__ gi1c)
{
    int lane = threadIdx.x & 63, wave = threadIdx.x >> 6;
    int row = blockIdx.x * 4 + wave;
    int which = blockIdx.y;
    const float* zt; const float* w; float acc; float* dst;
    if (which == 0) { zt = z2t; w = w_ih0 + (size_t)row * 131 + RHYn;          acc = b_ih0[row]; dst = gi0c; }
    else            { zt = z1t; w = w_ih1 + (size_t)row * 273 + (MELn + RHYn); acc = b_ih1[row]; dst = gi1c; }
#pragma unroll 4
    for (int i = 0; i < 128; i++) acc = fmaf(zt[i * 64 + lane], w[i], acc);
    dst[(size_t)row * 64 + lane] = acc;
}

// ---------------------------------------------------------------------------
// 64x64 tile transpose: in [R][C] -> out [C][Rout] (Rout >= R allows padding)
// ---------------------------------------------------------------------------
__device__ __forceinline__ void transpose_body(
    const float* __restrict__ in, float* __restrict__ out, int R, int C, int Rout,
    int bx, int by, float* tile)
{
    int c0 = bx * 64, r0 = by * 64;
    int t = threadIdx.x;
    int cl = t & 63, rw = t >> 6;
#pragma unroll
    for (int i = 0; i < 16; ++i) {
        int rl = rw + i * 4;
        int r = r0 + rl, c = c0 + cl;
        float v = (r < R && c < C) ? in[(size_t)r * C + c] : 0.f;
        tile[rl * 65 + cl] = v;
    }
    __syncthreads();
#pragma unroll
    for (int i = 0; i < 16; ++i) {
        int c_loc = rw + i * 4;
        int r_loc = cl;
        int oc = c0 + c_loc, orow = r0 + r_loc;
        if (oc < C && orow < R)
            out[(size_t)oc * Rout + orow] = tile[r_loc * 65 + c_loc];
    }
}

__global__ __launch_bounds__(256) void transpose4_k(
    const float* __restrict__ a, const float* __restrict__ b,
    const float* __restrict__ c, const float* __restrict__ d,
    float* __restrict__ oa, float* __restrict__ ob,
    float* __restrict__ oc, float* __restrict__ od)
{
    __shared__ float tile[64 * 65];
    const float* in; float* out;
    switch (blockIdx.z) {
        case 0: in = a; out = oa; break;
        case 1: in = b; out = ob; break;
        case 2: in = c; out = oc; break;
        default: in = d; out = od; break;
    }
    transpose_body(in, out, G3, Hd, G3, blockIdx.x, blockIdx.y, tile);
}

__global__ __launch_bounds__(256) void transpose1_k(
    const float* __restrict__ in, float* __restrict__ out, int R, int C, int Rout)
{
    __shared__ float tile[64 * 65];
    transpose_body(in, out, R, C, Rout, blockIdx.x, blockIdx.y, tile);
}

// ---------------------------------------------------------------------------
// mm8_body: GEMM partial, 128-row tile x 64 b, kc=256 (2 phases), thread 8r x 4b.
// part[slot*393216 + prow*64 + b]; per-(row,b) k-order identical to before.
// ---------------------------------------------------------------------------
__device__ __forceinline__ void mm8_body(
    const float* __restrict__ WT, const float* __restrict__ x,
    float* __restrict__ part, int tile, int slot, float* xs)
{
    int tid = threadIdx.x;
    int rg = tid & 15, bg = tid >> 4;
    int r0 = tile * 128 + rg * 8;
    int b0 = bg * 4;

    float acc[8][4];
#pragma unroll
    for (int i = 0; i < 8; i++)
#pragma unroll
        for (int j = 0; j < 4; j++) acc[i][j] = 0.f;

    for (int ph = 0; ph < 2; ++ph) {
        int kp = slot * 256 + ph * 128;
        __syncthreads();
        {
            const float4* src = (const float4*)(x + (size_t)kp * 64);
            float4* dst = (float4*)xs;
#pragma unroll
            for (int i = 0; i < 8; i++) dst[tid + i * 256] = src[tid + i * 256];
        }
        __syncthreads();
        const float* wp = WT + (size_t)kp * G3 + r0;
#pragma unroll 4
        for (int k = 0; k < 128; ++k) {
            float4 xv = *(const float4*)&xs[k * 64 + b0];
            float w[8];
            *(float4*)&w[0] = *(const float4*)wp;
            *(float4*)&w[4] = *(const float4*)(wp + 4);
            wp += G3;
#pragma unroll
            for (int i = 0; i < 8; i++) {
                acc[i][0] = fmaf(w[i], xv.x, acc[i][0]);
                acc[i][1] = fmaf(w[i], xv.y, acc[i][1]);
                acc[i][2] = fmaf(w[i], xv.z, acc[i][2]);
                acc[i][3] = fmaf(w[i], xv.w, acc[i][3]);
            }
        }
    }

    size_t base = (size_t)slot * 393216 + b0;
    int prow0 = tile * 128 + rg * 8;
#pragma unroll
    for (int i = 0; i < 8; i++)
        *(float4*)&part[base + (size_t)(prow0 + i) * 64] = *(float4*)acc[i];
}

// ---------------------------------------------------------------------------
// fusedA: [0] rhythm logits(u-1); [1..16] melody logits(u-2) w/ fenced
// finalize; [17..400] rhythm GEMM(u) (48 tiles x 8 slots); [401..784] melody
// GRU1 GEMM(u-1). Small blocks first so they schedule in the first round.
// flags: bit0 doRhy, bit1 doRlog, bit2 doMel, bit3 doMlog
// ---------------------------------------------------------------------------
__global__ __launch_bounds__(256) void fusedA_k(
    const float* __restrict__ WT0h, const float* __restrict__ hr, float* __restrict__ partR,
    const float* __restrict__ wo0, const float* __restrict__ bo0,
    float* __restrict__ rlo_prev, int* __restrict__ rhy_idx,
    const float* __restrict__ WT1h, const float* __restrict__ ha, float* __restrict__ partM,
    const float* __restrict__ WTo1, const float* __restrict__ hbPrev,
    float* __restrict__ lpart, const float* __restrict__ bo1,
    float* __restrict__ outp, int tout, int* __restrict__ mel_idx,
    int* __restrict__ cnt, int flags)
{
    __shared__ float smem[8192];             // 32 KB
    int flat = blockIdx.x, tid = threadIdx.x;

    if (flat == 0) {                          // rhythm logits (step u-1)
        if (!(flags & 2)) return;
        int lane = tid & 63, wv = tid >> 6;
        const float* hc = hr + wv * 512 * 64;
        const float* w0 = wo0 + wv * 512;
        const float* w1 = wo0 + Hd + wv * 512;
        const float* w2 = wo0 + 2 * Hd + wv * 512;
        float a0 = 0.f, a1 = 0.f, a2 = 0.f;
#pragma unroll 4
        for (int k = 0; k < 512; k++) {
            float hv = hc[k * 64 + lane];
            a0 = fmaf(hv, w0[k], a0);
            a1 = fmaf(hv, w1[k], a1);
            a2 = fmaf(hv, w2[k], a2);
        }
        smem[(0 * 4 + wv) * 64 + lane] = a0;
        smem[(1 * 4 + wv) * 64 + lane] = a1;
        smem[(2 * 4 + wv) * 64 + lane] = a2;
        __syncthreads();
        if (wv == 0) {
            float l0 = smem[0 * 64 + lane] + smem[1 * 64 + lane] + smem[2 * 64 + lane] + smem[3 * 64 + lane] + bo0[0];
            float l1 = smem[4 * 64 + lane] + smem[5 * 64 + lane] + smem[6 * 64 + lane] + smem[7 * 64 + lane] + bo0[1];
            float l2 = smem[8 * 64 + lane] + smem[9 * 64 + lane] + smem[10 * 64 + lane] + smem[11 * 64 + lane] + bo0[2];
            int am; float mx;
            if (l0 >= l1 && l0 >= l2) { am = 0; mx = l0; }
            else if (l1 >= l2)        { am = 1; mx = l1; }
            else                      { am = 2; mx = l2; }
            float s = expf(l0 - mx) + expf(l1 - mx) + expf(l2 - mx);
            float ls = logf(s);
            rlo_prev[lane * 3 + 0] = l0 - mx - ls;
            rlo_prev[lane * 3 + 1] = l1 - mx - ls;
            rlo_prev[lane * 3 + 2] = l2 - mx - ls;
            rhy_idx[lane] = am;
        }
        return;
    }

    if (flat <= 16) {                         // melody logits (output step u-2)
        if (!(flags & 8)) return;
        int li = flat - 1;                    // 0..15
        int ltile = li & 1, lslot = li >> 1;
        int rg = tid & 15, bg = tid >> 4;
        int r0 = ltile * 128 + rg * 8;
        int b0 = bg * 4;
        int k0 = lslot * 256;

        float acc[8][4];
#pragma unroll
        for (int i = 0; i < 8; i++)
#pragma unroll
            for (int j = 0; j < 4; j++) acc[i][j] = 0.f;

        bool fast = (r0 + 7 < MELn);
        for (int ph = 0; ph < 2; ++ph) {
            int kp = k0 + ph * 128;
            __syncthreads();
            {
                const float4* src = (const float4*)(hbPrev + (size_t)kp * 64);
                float4* dst = (float4*)smem;
#pragma unroll
                for (int i = 0; i < 8; i++) dst[tid + i * 256] = src[tid + i * 256];
            }
            __syncthreads();
            if (fast) {
                const float* wp = WTo1 + (size_t)kp * 132 + r0;
#pragma unroll 4
                for (int k = 0; k < 128; ++k) {
                    float4 xv = *(const float4*)&smem[k * 64 + b0];
                    float w[8];
                    *(float4*)&w[0] = *(const float4*)wp;
                    *(float4*)&w[4] = *(const float4*)(wp + 4);
                    wp += 132;
#pragma unroll
                    for (int i = 0; i < 8; i++) {
                        acc[i][0] = fmaf(w[i], xv.x, acc[i][0]);
                        acc[i][1] = fmaf(w[i], xv.y, acc[i][1]);
                        acc[i][2] = fmaf(w[i], xv.z, acc[i][2]);
                        acc[i][3] = fmaf(w[i], xv.w, acc[i][3]);
                    }
                }
            } else {
                for (int k = 0; k < 128; ++k) {
                    float4 xv = *(const float4*)&smem[k * 64 + b0];
                    const float* wrow = WTo1 + (size_t)(k0 + ph * 128 + k) * 132;
                    float w[8];
#pragma unroll
                    for (int i = 0; i < 8; i++) {
                        int rc = r0 + i; if (rc > MELn - 1) rc = MELn - 1;
                        w[i] = wrow[rc];
                    }
#pragma unroll
                    for (int i = 0; i < 8; i++) {
                        acc[i][0] = fmaf(w[i], xv.x, acc[i][0]);
                        acc[i][1] = fmaf(w[i], xv.y, acc[i][1]);
                        acc[i][2] = fmaf(w[i], xv.z, acc[i][2]);
                        acc[i][3] = fmaf(w[i], xv.w, acc[i][3]);
                    }
                }
            }
        }
        size_t base = (size_t)lslot * 8320 + b0;
#pragma unroll
        for (int i = 0; i < 8; i++) {
            int prow = ltile * 128 + rg * 8 + i;
            int pc = prow < MELn ? prow : (MELn - 1);
            *(float4*)&lpart[base + (size_t)pc * 64] = *(float4*)acc[i];
        }

        // ---- last-block finalize (fenced), small-LDS 3-pass ----
        __shared__ int lastf;
        __threadfence();
        __syncthreads();
        if (tid == 0) lastf = (atomicAdd(cnt, 1) == 15);
        __syncthreads();
        if (!lastf) return;
        __threadfence();

        int b = tid & 63, q = tid >> 6;
        int rLo = q * 33, rHi = rLo + 33; if (rHi > MELn) rHi = MELn;
        // pass 1: v = bias + sum of 8 slots; cache v into lpart slot-0; quarter max
        float mx = -1e30f; int am = MELn;
        for (int r = rLo; r < rHi; r++) {
            float v = bo1[r];
#pragma unroll
            for (int s = 0; s < 8; s++) v += lpart[s * 8320 + r * 64 + b];
            lpart[r * 64 + b] = v;            // own (r,b): safe overwrite
            if (v > mx) { mx = v; am = r; }   // first max within quarter
        }
        float* qmax = smem;                   // [4][64]
        int*   qam  = (int*)(smem + 256);     // [4][64]
        float* qsum = smem + 512;             // [4][64]
        qmax[q * 64 + b] = mx; qam[q * 64 + b] = am;
        __syncthreads();
        float gm = qmax[b]; int ga = qam[b];
#pragma unroll
        for (int qq = 1; qq < 4; qq++) {
            float v = qmax[qq * 64 + b];
            if (v > gm) { gm = v; ga = qam[qq * 64 + b]; }   // earlier quarter wins ties
        }
        // pass 2: quarter exp-sums
        float ps = 0.f;
        for (int r = rLo; r < rHi; r++) ps += expf(lpart[r * 64 + b] - gm);
        qsum[q * 64 + b] = ps;
        __syncthreads();
        float ls = logf(qsum[b] + qsum[64 + b] + qsum[128 + b] + qsum[192 + b]);
        if (tid < 64) mel_idx[b] = ga;
        // pass 3: write log-probs
        for (int r = rLo; r < rHi; r++)
            outp[(size_t)b * Tn * MELn + tout * MELn + r] = lpart[r * 64 + b] - gm - ls;
        __syncthreads();
        if (tid == 0) *cnt = 0;
        return;
    }

    if (flat < 401) {                         // rhythm GEMM: 48 tiles x 8 slots
        if (!(flags & 1)) return;
        int e = flat - 17;
        mm8_body(WT0h, hr, partR, e % 48, e / 48, smem);
        return;
    }
    {                                         // melody GRU1 GEMM
        if (!(flags & 4)) return;
        int e = flat - 401;
        mm8_body(WT1h, ha, partM, e % 48, e / 48, smem);
    }
}

// ---------------------------------------------------------------------------
// fusedB: rhy_epi(u) [blk 0..511] + mel1_epi(u-1) [blk 512..1023].
// 8-slot reduce: wave wv sums slots {2wv, 2wv+1}.
// flags: bit0 rhy, bit1 mel
// ---------------------------------------------------------------------------
__global__ __launch_bounds__(256) void fusedB_k(
    const float* __restrict__ partR, const float* __restrict__ gi0c,
    const float* __restrict__ w_ih0, const float* __restrict__ b_hh0,
    const float* __restrict__ hr_in, float* __restrict__ hr_out,
    const int* __restrict__ rhy_idx,
    const float* __restrict__ partM, const float* __restrict__ gi1c,
    const float* __restrict__ w_ih1, const float* __restrict__ b_hh1,
    const float* __restrict__ ha_in, float* __restrict__ ha_out,
    const int* __restrict__ mel_idx, const float* __restrict__ rlo,
    const float* __restrict__ cdt, int flags)
{
    __shared__ float red[48 * 68];
    int flat = blockIdx.x, tid = threadIdx.x;
    int wv = tid >> 6, lane = tid & 63;
    int jj = lane >> 4, bq = lane & 15;
    int isMel = (flat >= 512);
    if (isMel) { if (!(flags & 2)) return; }
    else       { if (!(flags & 1)) return; }
    int jbase = (isMel ? flat - 512 : flat) * 4;
    const float* part = isMel ? partM : partR;

    float s0[4], s1[4], s2[4];
#pragma unroll
    for (int q = 0; q < 4; q++) { s0[q] = 0.f; s1[q] = 0.f; s2[q] = 0.f; }
#pragma unroll
    for (int ss = 0; ss < 2; ss++) {
        const float* p = part + (size_t)(wv * 2 + ss) * 393216
                       + (size_t)(jbase + jj) * 64 + bq * 4;
        float4 v0 = *(const float4*)(p);
        float4 v1 = *(const float4*)(p + 2048 * 64);
        float4 v2 = *(const float4*)(p + 4096 * 64);
        s0[0] += v0.x; s0[1] += v0.y; s0[2] += v0.z; s0[3] += v0.w;
        s1[0] += v1.x; s1[1] += v1.y; s1[2] += v1.z; s1[3] += v1.w;
        s2[0] += v2.x; s2[1] += v2.y; s2[2] += v2.z; s2[3] += v2.w;
    }
    int rbase = (wv * 4 + jj) * 3;
    *(float4*)&red[(rbase + 0) * 68 + bq * 4] = make_float4(s0[0], s0[1], s0[2], s0[3]);
    *(float4*)&red[(rbase + 1) * 68 + bq * 4] = make_float4(s1[0], s1[1], s1[2], s1[3]);
    *(float4*)&red[(rbase + 2) * 68 + bq * 4] = make_float4(s2[0], s2[1], s2[2], s2[3]);
    __syncthreads();

    int b = lane, jw = wv;
    int j = jbase + jw;
    float ar = 0.f, az = 0.f, an = 0.f;
#pragma unroll
    for (int ww = 0; ww < 4; ww++) {
        int rb = (ww * 4 + jw) * 3;
        ar += red[(rb + 0) * 68 + b];
        az += red[(rb + 1) * 68 + b];
        an += red[(rb + 2) * 68 + b];
    }

    if (!isMel) {
        int oi = rhy_idx[b];
        float gir = gi0c[j * 64 + b]            + w_ih0[(size_t)j * 131 + oi];
        float giz = gi0c[(j + 2048) * 64 + b]   + w_ih0[(size_t)(j + 2048) * 131 + oi];
        float gin = gi0c[(j + 4096) * 64 + b]   + w_ih0[(size_t)(j + 4096) * 131 + oi];
        float rg = sigf(gir + ar + b_hh0[j]);
        float ug = sigf(giz + az + b_hh0[j + 2048]);
        float ng = tanhf(gin + rg * (an + b_hh0[j + 4096]));
        float hp = hr_in[j * 64 + b];
        hr_out[j * 64 + b] = (1.f - ug) * ng + ug * hp;
    } else {
        int oi = mel_idx[b];
        float r0 = rlo[b * 3 + 0], r1 = rlo[b * 3 + 1], r2 = rlo[b * 3 + 2];
        float cd[12];
#pragma unroll
        for (int q = 0; q < 12; q++) cd[q] = cdt[q * 64 + b];
        float gi[3];
#pragma unroll
        for (int g = 0; g < 3; g++) {
            int row = j + g * 2048;
            const float* wrow = w_ih1 + (size_t)row * 273;
            float v = gi1c[row * 64 + b] + wrow[oi];
            v = fmaf(r0, wrow[130], v);
            v = fmaf(r1, wrow[131], v);
            v = fmaf(r2, wrow[132], v);
#pragma unroll
            for (int q = 0; q < 12; q++) v = fmaf(cd[q], wrow[261 + q], v);
            gi[g] = v;
        }
        float rg = sigf(gi[0] + ar + b_hh1[j]);
        float ug = sigf(gi[1] + az + b_hh1[j + 2048]);
        float ng = tanhf(gi[2] + rg * (an + b_hh1[j + 4096]));
        float hp = ha_in[j * 64 + b];
        ha_out[j * 64 + b] = (1.f - ug) * ng + ug * hp;
    }
}

// ---------------------------------------------------------------------------
// GRU2 fused two-matrix GEMM: 96 tiles(128 rows) x 4 slots (kc=512) = 384 blk.
// Partial = 4 x 786432 floats (12.6 MB).
// ---------------------------------------------------------------------------
__global__ __launch_bounds__(256) void mmg2_k(
    const float* __restrict__ WTa, const float* __restrict__ xa,
    const float* __restrict__ WTb, const float* __restrict__ xb,
    float* __restrict__ part)
{
    __shared__ float xs[128 * 64];
    int tid = threadIdx.x;
    int tile = blockIdx.x, slot = blockIdx.y;
    const float* WT; const float* x; int tLoc;
    if (tile < 48) { WT = WTa; x = xa; tLoc = tile; }
    else           { WT = WTb; x = xb; tLoc = tile - 48; }
    int rg = tid & 15, bg = tid >> 4;
    int r0 = tLoc * 128 + rg * 8;
    int b0 = bg * 4;
    int k0 = slot * 512;

    float acc[8][4];
#pragma unroll
    for (int i = 0; i < 8; i++)
#pragma unroll
        for (int j = 0; j < 4; j++) acc[i][j] = 0.f;

    for (int ph = 0; ph < 4; ++ph) {
        int kp = k0 + ph * 128;
        __syncthreads();
        {
            const float4* src = (const float4*)(x + (size_t)kp * 64);
            float4* dst = (float4*)xs;
#pragma unroll
            for (int i = 0; i < 8; i++) dst[tid + i * 256] = src[tid + i * 256];
        }
        __syncthreads();
        const float* wp = WT + (size_t)kp * G3 + r0;
#pragma unroll 4
        for (int k = 0; k < 128; ++k) {
            float4 xv = *(const float4*)&xs[k * 64 + b0];
            float w[8];
            *(float4*)&w[0] = *(const float4*)wp;
            *(float4*)&w[4] = *(const float4*)(wp + 4);
            wp += G3;
#pragma unroll
            for (int i = 0; i < 8; i++) {
                acc[i][0] = fmaf(w[i], xv.x, acc[i][0]);
                acc[i][1] = fmaf(w[i], xv.y, acc[i][1]);
                acc[i][2] = fmaf(w[i], xv.z, acc[i][2]);
                acc[i][3] = fmaf(w[i], xv.w, acc[i][3]);
            }
        }
    }

    size_t base = (size_t)slot * 786432 + b0;
    int prow0 = tile * 128 + rg * 8;
#pragma unroll
    for (int i = 0; i < 8; i++)
        *(float4*)&part[base + (size_t)(prow0 + i) * 64] = *(float4*)acc[i];
}

// ---------------------------------------------------------------------------
// melody GRU2 epilogue, 4-slot: wave wv reads slot wv directly
// ---------------------------------------------------------------------------
__global__ __launch_bounds__(256) void mel2_epi(
    const float* __restrict__ part, const float* __restrict__ b_ih,
    const float* __restrict__ b_hh, const float* __restrict__ hb_in,
    float* __restrict__ hb_out)
{
    __shared__ float red[96 * 68];
    int tid = threadIdx.x;
    int wv = tid >> 6, lane = tid & 63;
    int jj = lane >> 4, bq = lane & 15;
    int jbase = blockIdx.x * 4;

    float s[6][4];
    {
        const float* p = part + (size_t)wv * 786432
                       + (size_t)(jbase + jj) * 64 + bq * 4;
#pragma unroll
        for (int g = 0; g < 6; g++) {
            float4 v = *(const float4*)(p + (size_t)g * 2048 * 64);
            s[g][0] = v.x; s[g][1] = v.y; s[g][2] = v.z; s[g][3] = v.w;
        }
    }
    int rbase = (wv * 4 + jj) * 6;
#pragma unroll
    for (int g = 0; g < 6; g++)
        *(float4*)&red[(rbase + g) * 68 + bq * 4] = make_float4(s[g][0], s[g][1], s[g][2], s[g][3]);
    __syncthreads();

    int b = lane, jw = wv;
    int j = jbase + jw;
    float air = 0.f, aiz = 0.f, ain = 0.f, ahr = 0.f, ahz = 0.f, ahn = 0.f;
#pragma unroll
    for (int ww = 0; ww < 4; ww++) {
        int rb = (ww * 4 + jw) * 6;
        air += red[(rb + 0) * 68 + b];
        aiz += red[(rb + 1) * 68 + b];
        ain += red[(rb + 2) * 68 + b];
        ahr += red[(rb + 3) * 68 + b];
        ahz += red[(rb + 4) * 68 + b];
        ahn += red[(rb + 5) * 68 + b];
    }
    float rg = sigf(air + b_ih[j] + ahr + b_hh[j]);
    float ug = sigf(aiz + b_ih[j + 2048] + ahz + b_hh[j + 2048]);
    float ng = tanhf(ain + b_ih[j + 4096] + rg * (ahn + b_hh[j + 4096]));
    float hp = hb_in[j * 64 + b];
    hb_out[j * 64 + b] = (1.f - ug) * ng + ug * hp;
}

// ---------------------------------------------------------------------------
// mm2_k: small logits GEMM (tail for t=31, 16 slots kc=128)
// ---------------------------------------------------------------------------
__global__ __launch_bounds__(256) void mm2_k(
    const float* __restrict__ WTa, const float* __restrict__ xa,
    const float* __restrict__ WTb, const float* __restrict__ xb,
    float* __restrict__ part, int splitTile, int kc, int nrows, int wstride,
    int partStride)
{
    __shared__ float xs[128 * 64];
    int tid = threadIdx.x;
    int tile = blockIdx.x, slot = blockIdx.y;
    const float* WT; const float* x; int tLoc;
    if (tile < splitTile) { WT = WTa; x = xa; tLoc = tile; }
    else                  { WT = WTb; x = xb; tLoc = tile - splitTile; }
    int rg = tid & 15, bg = tid >> 4;
    int r0 = tLoc * 128 + rg * 8;
    int b0 = bg * 4;
    int k0 = slot * kc;

    float acc[8][4];
#pragma unroll
    for (int i = 0; i < 8; i++)
#pragma unroll
        for (int j = 0; j < 4; j++) acc[i][j] = 0.f;

    bool fast = (r0 + 7 < nrows);
    int nPhase = kc >> 7;
    for (int ph = 0; ph < nPhase; ++ph) {
        int kp = k0 + ph * 128;
        __syncthreads();
        {
            const float4* src = (const float4*)(x + (size_t)kp * 64);
            float4* dst = (float4*)xs;
#pragma unroll
            for (int i = 0; i < 8; i++) dst[tid + i * 256] = src[tid + i * 256];
        }
        __syncthreads();
        if (fast) {
            const float* wp = WT + (size_t)kp * wstride + r0;
#pragma unroll 4
            for (int k = 0; k < 128; ++k) {
                float4 xv = *(const float4*)&xs[k * 64 + b0];
                float w[8];
                *(float4*)&w[0] = *(const float4*)wp;
                *(float4*)&w[4] = *(const float4*)(wp + 4);
                wp += wstride;
#pragma unroll
                for (int i = 0; i < 8; i++) {
                    acc[i][0] = fmaf(w[i], xv.x, acc[i][0]);
                    acc[i][1] = fmaf(w[i], xv.y, acc[i][1]);
                    acc[i][2] = fmaf(w[i], xv.z, acc[i][2]);
                    acc[i][3] = fmaf(w[i], xv.w, acc[i][3]);
                }
            }
        } else {
            for (int k = 0; k < 128; ++k) {
                float4 xv = *(const float4*)&xs[k * 64 + b0];
                const float* wrow = WT + (size_t)(kp + k) * wstride;
                float w[8];
#pragma unroll
                for (int i = 0; i < 8; i++) {
                    int rc = r0 + i; if (rc > nrows - 1) rc = nrows - 1;
                    w[i] = wrow[rc];
                }
#pragma unroll
                for (int i = 0; i < 8; i++) {
                    acc[i][0] = fmaf(w[i], xv.x, acc[i][0]);
                    acc[i][1] = fmaf(w[i], xv.y, acc[i][1]);
                    acc[i][2] = fmaf(w[i], xv.z, acc[i][2]);
                    acc[i][3] = fmaf(w[i], xv.w, acc[i][3]);
                }
            }
        }
    }

    size_t base = (size_t)slot * partStride + b0;
#pragma unroll
    for (int i = 0; i < 8; i++) {
        int prow = tile * 128 + rg * 8 + i;
        int pc = prow < nrows ? prow : (nrows - 1);
        if (tile >= splitTile) pc = prow;
        *(float4*)&part[base + (size_t)pc * 64] = *(float4*)acc[i];
    }
}

// ---------------------------------------------------------------------------
// melody softmax (tail for t=31; 16 slots)
// ---------------------------------------------------------------------------
__global__ __launch_bounds__(256) void mel_smax(
    const float* __restrict__ part, const float* __restrict__ bo1,
    float* __restrict__ outp, int t, int* __restrict__ mel_idx)
{
    int b = blockIdx.x, tid = threadIdx.x;
    float v = -1e30f;
    if (tid < MELn) {
        v = bo1[tid];
#pragma unroll
        for (int s = 0; s < 16; s++) v += part[s * 8320 + tid * 64 + b];
    }
    __shared__ float smax[256];
    __shared__ int   sidx[256];
    __shared__ float ssum[256];
    smax[tid] = v; sidx[tid] = tid;
    __syncthreads();
    for (int s = 128; s > 0; s >>= 1) {
        if (tid < s) {
            float a = smax[tid], o = smax[tid + s];
            int ai = sidx[tid], oi = sidx[tid + s];
            if (o > a || (o == a && oi < ai)) { smax[tid] = o; sidx[tid] = oi; }
        }
        __syncthreads();
    }
    float mx = smax[0]; int am = sidx[0];
    ssum[tid] = (tid < MELn) ? expf(v - mx) : 0.f;
    __syncthreads();
    for (int s = 128; s > 0; s >>= 1) {
        if (tid < s) ssum[tid] += ssum[tid + s];
        __syncthreads();
    }
    float ls = logf(ssum[0]);
    if (tid < MELn) outp[(size_t)b * Tn * MELn + t * MELn + tid] = v - mx - ls;
    if (tid == 0) mel_idx[b] = am;
}

// ---------------------------------------------------------------------------
extern "C" void kernel_launch(void* const* d_in, const int* in_sizes, int n_in,
                              void* d_out, int out_size, void* d_ws, size_t ws_size,
                              hipStream_t stream)
{
    (void)in_sizes; (void)n_in; (void)out_size; (void)ws_size;
    const float* z1    = (const float*)d_in[0];
    const float* z2    = (const float*)d_in[1];
    const float* cond  = (const float*)d_in[2];
    const float* w_ih0 = (const float*)d_in[3];
    const float* w_hh0 = (const float*)d_in[4];
    const float* b_ih0 = (const float*)d_in[5];
    const float* b_hh0 = (const float*)d_in[6];
    const float* w_ih1 = (const float*)d_in[7];
    const float* w_hh1 = (const float*)d_in[8];
    const float* b_ih1 = (const float*)d_in[9];
    const float* b_hh1 = (const float*)d_in[10];
    const float* w_ih2 = (const float*)d_in[11];
    const float* w_hh2 = (const float*)d_in[12];
    const float* b_ih2 = (const float*)d_in[13];
    const float* b_hh2 = (const float*)d_in[14];
    const float* wi0   = (const float*)d_in[15];
    const float* bi0   = (const float*)d_in[16];
    const float* wo0   = (const float*)d_in[17];
    const float* bo0   = (const float*)d_in[18];
    const float* wi1   = (const float*)d_in[19];
    const float* bi1   = (const float*)d_in[20];
    const float* wo1   = (const float*)d_in[21];
    const float* bo1   = (const float*)d_in[22];
    float* outp = (float*)d_out;
    float* ws = (float*)d_ws;

    // workspace layout (floats), ~235 MB; live set now fits the 256 MB L3
    size_t off = 0;
    float* WT0  = ws + off; off += 12582912;   // w_hh0^T [2048][6144]
    float* WT1  = ws + off; off += 12582912;   // w_hh1^T
    float* WTi2 = ws + off; off += 12582912;   // w_ih2^T
    float* WTh2 = ws + off; off += 12582912;   // w_hh2^T
    float* WTo1 = ws + off; off += 270336;     // wo1^T [2048][132] (padded)
    float* bufR  = ws + off; off += 3145728;   // rhythm partials (8 slots, 12.6 MB)
    float* bufMG = ws + off; off += 3145728;   // GRU1 (8 slots) / GRU2 (4 slots) time-shared
    float* lpart = ws + off; off += 66560;     // inline logits partials (8 slots)
    float* hR[2] = { ws + off, ws + off + 131072 }; off += 262144;
    float* hA[2] = { ws + off, ws + off + 131072 }; off += 262144;
    float* hB[2] = { ws + off, ws + off + 131072 }; off += 262144;
    float* gi0c   = ws + off; off += 393216;
    float* gi1c   = ws + off; off += 393216;
    float* rlo    = ws + off; off += 6144;     // [32][64][3]
    float* cond_t = ws + off; off += 24576;
    float* z1t    = ws + off; off += 8192;
    float* z2t    = ws + off; off += 8192;
    int* rhy_idx  = (int*)(ws + off); off += 64;
    int* mel_idx  = (int*)(ws + off); off += 64;
    int* cnts     = (int*)(ws + off); off += 64;

    // ---- pre-pass ----
    prep_misc<<<96, 256, 0, stream>>>(z1, z2, cond, z1t, z2t, cond_t, rhy_idx, mel_idx, cnts);
    init_h_k<<<dim3(Hd / 4, 2), 256, 0, stream>>>(z1t, z2t, wi0, bi0, wi1, bi1, hR[0], hA[0]);
    gi_const_k<<<dim3(G3 / 4, 2), 256, 0, stream>>>(z1t, z2t, w_ih0, b_ih0, w_ih1, b_ih1, gi0c, gi1c);
    transpose4_k<<<dim3(32, 96, 4), 256, 0, stream>>>(w_hh0, w_hh1, w_ih2, w_hh2,
                                                      WT0, WT1, WTi2, WTh2);
    transpose1_k<<<dim3(32, 3), 256, 0, stream>>>(wo1, WTo1, MELn, Hd, 132);

    // ---- merged decoder pipeline: iteration u = rhythm step u + melody step u-1 ----
    for (int u = 0; u <= Tn; u++) {
        int doRhy  = (u < Tn) ? 1 : 0;
        int doRlog = (u >= 1) ? 1 : 0;
        int doMel  = (u >= 1) ? 1 : 0;
        int doMlog = (u >= 2) ? 1 : 0;
        int flagsA = doRhy | (doRlog << 1) | (doMel << 2) | (doMlog << 3);

        const float* hr = hR[u & 1];
        const float* ha_in = (u >= 1) ? hA[(u - 1) & 1] : hA[0];
        const float* hbPrev = (u >= 2) ? hB[(u - 1) & 1] : hB[0];
        float* rloPrev = rlo + (size_t)(u >= 1 ? u - 1 : 0) * 192;

        fusedA_k<<<785, 256, 0, stream>>>(WT0, hr, bufR, wo0, bo0, rloPrev, rhy_idx,
                                          WT1, ha_in, bufMG, WTo1, hbPrev, lpart, bo1,
                                          outp, u - 2, mel_idx, cnts + 0, flagsA);

        fusedB_k<<<1024, 256, 0, stream>>>(bufR, gi0c, w_ih0, b_hh0, hr, hR[(u + 1) & 1],
                                           rhy_idx, bufMG, gi1c, w_ih1, b_hh1,
                                           ha_in, hA[u & 1], mel_idx, rloPrev,
                                           cond_t + (size_t)(u >= 1 ? u - 1 : 0) * (CHn * Bsz),
                                           doRhy | (doMel << 1));

        if (u >= 1) {
            // melody step t = u-1 GRU2: ih2 x ha(t+1) fused with hh2 x hb(t)
            const float* hbop = (u == 1) ? (const float*)hA[u & 1] : (const float*)hB[(u - 1) & 1];
            mmg2_k<<<dim3(96, 4), 256, 0, stream>>>(WTi2, hA[u & 1], WTh2, hbop, bufMG);
            mel2_epi<<<512, 256, 0, stream>>>(bufMG, b_ih2, b_hh2, hbop, hB[u & 1]);
        }
    }

    // ---- tail: melody logits + softmax for t=31 (hbState(32) = hB[0]) ----
    mm2_k<<<dim3(2, 16), 256, 0, stream>>>(WTo1, hB[0], WTo1, hB[0], bufR,
                                           2, 128, MELn, 132, 8320);
    mel_smax<<<Bsz, 256, 0, stream>>>(bufR, bo1, outp, 31, mel_idx);
}

// Round 7
// 5773.716 us; speedup vs baseline: 1.7745x; 1.0198x over previous
//
#include <hip/hip_runtime.h>
#include <hip/hip_bf16.h>
#include <math.h>

#define Bsz  64
#define Hd   2048
#define G3   6144
#define MELn 130
#define CHn  12
#define RHYn 3
#define Tn   32

__device__ __forceinline__ float sigf(float x) { return 1.0f / (1.0f + expf(-x)); }

// ---------------------------------------------------------------------------
// prep: transpose z1/z2 -> [128][64], condition -> [T][CH][64], init feedback idx
// ---------------------------------------------------------------------------
__global__ void prep_misc(const float* __restrict__ z1, const float* __restrict__ z2,
                          const float* __restrict__ cond,
                          float* __restrict__ z1t, float* __restrict__ z2t,
                          float* __restrict__ cond_t, int* __restrict__ rhy_idx,
                          int* __restrict__ mel_idx, int* __restrict__ cnts)
{
    int idx = blockIdx.x * 256 + threadIdx.x;
    if (idx < 128 * Bsz) {
        int j = idx >> 6, b = idx & 63;
        z1t[idx] = z1[b * 128 + j];
        z2t[idx] = z2[b * 128 + j];
    }
    if (idx < Tn * CHn * Bsz) {
        int t = idx / (CHn * Bsz);
        int r = idx - t * CHn * Bsz;
        int j = r >> 6, b = r & 63;
        cond_t[idx] = cond[b * (Tn * CHn) + t * CHn + j];
    }
    if (idx < Bsz) { rhy_idx[idx] = RHYn - 1; mel_idx[idx] = MELn - 1; }
    if (idx < 4) cnts[idx] = 0;
}

// ---------------------------------------------------------------------------
// h0 = tanh(z2 @ wi0.T + bi0), h1 = tanh(z1 @ wi1.T + bi1); output [j][b]
// ---------------------------------------------------------------------------
__global__ __launch_bounds__(256) void init_h_k(
    const float* __restrict__ z1t, const float* __restrict__ z2t,
    const float* __restrict__ wi0, const float* __restrict__ bi0,
    const float* __restrict__ wi1, const float* __restrict__ bi1,
    float* __restrict__ h0_out, float* __restrict__ h1_out)
{
    int lane = threadIdx.x & 63, wave = threadIdx.x >> 6;
    int j = blockIdx.x * 4 + wave;
    int which = blockIdx.y;
    const float* zt = which ? z1t : z2t;
    const float* wi = which ? wi1 : wi0;
    const float* bi = which ? bi1 : bi0;
    float* outh = which ? h1_out : h0_out;
    const float4* w4 = (const float4*)(wi + (size_t)j * 128);
    float acc = 0.f;
#pragma unroll 8
    for (int i = 0; i < 32; i++) {
        float4 w = w4[i];
        int k = i * 4;
        acc = fmaf(zt[(k + 0) * 64 + lane], w.x, acc);
        acc = fmaf(zt[(k + 1) * 64 + lane], w.y, acc);
        acc = fmaf(zt[(k + 2) * 64 + lane], w.z, acc);
        acc = fmaf(zt[(k + 3) * 64 + lane], w.w, acc);
    }
    outh[j * 64 + lane] = tanhf(acc + bi[j]);
}

// ---------------------------------------------------------------------------
// step-invariant ih parts (z-terms + bias), layout [row][64]
// ---------------------------------------------------------------------------
__global__ __launch_bounds__(256) void gi_const_k(
    const float* __restrict__ z1t, const float* __restrict__ z2t,
    const float* __restrict__ w_ih0, const float* __restrict__ b_ih0,
    const float* __restrict__ w_ih1, const float* __restrict__ b_ih1,
    float* __restrict__ gi0c, float* __restrict__ gi1c)
{
    int lane = threadIdx.x & 63, wave = threadIdx.x >> 6;
    int row = blockIdx.x * 4 + wave;
    int which = blockIdx.y;
    const float* zt; const float* w; float acc; float* dst;
    if (which == 0) { zt = z2t; w = w_ih0 + (size_t)row * 131 + RHYn;          acc = b_ih0[row]; dst = gi0c; }
    else            { zt = z1t; w = w_ih1 + (size_t)row * 273 + (MELn + RHYn); acc = b_ih1[row]; dst = gi1c; }
#pragma unroll 4
    for (int i = 0; i < 128; i++) acc = fmaf(zt[i * 64 + lane], w[i], acc);
    dst[(size_t)row * 64 + lane] = acc;
}

// ---------------------------------------------------------------------------
// vectorized 64x64 transpose for the 4 big [6144][2048] weight matrices
// ---------------------------------------------------------------------------
__global__ __launch_bounds__(256) void transpose4v_k(
    const float* __restrict__ a, const float* __restrict__ b,
    const float* __restrict__ c, const float* __restrict__ d,
    float* __restrict__ oa, float* __restrict__ ob,
    float* __restrict__ oc, float* __restrict__ od)
{
    __shared__ float tile[64 * 65];
    const float* in; float* out;
    switch (blockIdx.z) {
        case 0: in = a; out = oa; break;
        case 1: in = b; out = ob; break;
        case 2: in = c; out = oc; break;
        default: in = d; out = od; break;
    }
    int c0 = blockIdx.x * 64, r0 = blockIdx.y * 64;
    int t = threadIdx.x;
    int rq = t & 15, rw = t >> 4;
#pragma unroll
    for (int i = 0; i < 4; i++) {
        int rl = rw + i * 16;
        float4 v = *(const float4*)&in[(size_t)(r0 + rl) * 2048 + c0 + rq * 4];
        tile[rl * 65 + rq * 4 + 0] = v.x;
        tile[rl * 65 + rq * 4 + 1] = v.y;
        tile[rl * 65 + rq * 4 + 2] = v.z;
        tile[rl * 65 + rq * 4 + 3] = v.w;
    }
    __syncthreads();
#pragma unroll
    for (int i = 0; i < 4; i++) {
        int cl = rw + i * 16;
        int r4 = rq * 4;
        float4 w;
        w.x = tile[(r4 + 0) * 65 + cl];
        w.y = tile[(r4 + 1) * 65 + cl];
        w.z = tile[(r4 + 2) * 65 + cl];
        w.w = tile[(r4 + 3) * 65 + cl];
        *(float4*)&out[(size_t)(c0 + cl) * G3 + r0 + r4] = w;
    }
}

// ---------------------------------------------------------------------------
// scalar transpose (wo1 130x2048 -> [2048][132])
// ---------------------------------------------------------------------------
__global__ __launch_bounds__(256) void transpose1_k(
    const float* __restrict__ in, float* __restrict__ out, int R, int C, int Rout)
{
    __shared__ float tile[64 * 65];
    int c0 = blockIdx.x * 64, r0 = blockIdx.y * 64;
    int t = threadIdx.x;
    int cl = t & 63, rw = t >> 6;
#pragma unroll
    for (int i = 0; i < 16; ++i) {
        int rl = rw + i * 4;
        int r = r0 + rl, c = c0 + cl;
        float v = (r < R && c < C) ? in[(size_t)r * C + c] : 0.f;
        tile[rl * 65 + cl] = v;
    }
    __syncthreads();
#pragma unroll
    for (int i = 0; i < 16; ++i) {
        int c_loc = rw + i * 4;
        int r_loc = cl;
        int oc = c0 + c_loc, orow = r0 + r_loc;
        if (oc < C && orow < R)
            out[(size_t)oc * Rout + orow] = tile[r_loc * 65 + c_loc];
    }
}

// ---------------------------------------------------------------------------
// mmP_body: GEMM partial, 128-row tile x 64 b, nPhase x 128 k, thread 8r x 4b.
// partSlot already offset to the slot; per-(row,b) k-order ascending.
// ---------------------------------------------------------------------------
__device__ __forceinline__ void mmP_body(
    const float* __restrict__ WT, const float* __restrict__ x,
    float* __restrict__ partSlot, int tile, int k0, int nPhase, float* xs)
{
    int tid = threadIdx.x;
    int rg = tid & 15, bg = tid >> 4;
    int r0 = tile * 128 + rg * 8;
    int b0 = bg * 4;

    float acc[8][4];
#pragma unroll
    for (int i = 0; i < 8; i++)
#pragma unroll
        for (int j = 0; j < 4; j++) acc[i][j] = 0.f;

    for (int ph = 0; ph < nPhase; ++ph) {
        int kp = k0 + ph * 128;
        __syncthreads();
        {
            const float4* src = (const float4*)(x + (size_t)kp * 64);
            float4* dst = (float4*)xs;
#pragma unroll
            for (int i = 0; i < 8; i++) dst[tid + i * 256] = src[tid + i * 256];
        }
        __syncthreads();
        const float* wp = WT + (size_t)kp * G3 + r0;
#pragma unroll 4
        for (int k = 0; k < 128; ++k) {
            float4 xv = *(const float4*)&xs[k * 64 + b0];
            float w[8];
            *(float4*)&w[0] = *(const float4*)wp;
            *(float4*)&w[4] = *(const float4*)(wp + 4);
            wp += G3;
#pragma unroll
            for (int i = 0; i < 8; i++) {
                acc[i][0] = fmaf(w[i], xv.x, acc[i][0]);
                acc[i][1] = fmaf(w[i], xv.y, acc[i][1]);
                acc[i][2] = fmaf(w[i], xv.z, acc[i][2]);
                acc[i][3] = fmaf(w[i], xv.w, acc[i][3]);
            }
        }
    }

    int prow0 = tile * 128 + rg * 8;
#pragma unroll
    for (int i = 0; i < 8; i++)
        *(float4*)&partSlot[(size_t)(prow0 + i) * 64 + b0] = *(float4*)acc[i];
}

// ---------------------------------------------------------------------------
// fusedA: [0] rhythm logits(u-1); [1..16] melody logits(u-2) fenced finalize;
// [17..400] rhythm GEMM (48tx8s); [401..784] GRU1 GEMM (48tx8s);
// [785..976] G2-hh GEMM (48tx4s kc=512, input hbPrev = hB state of step u-2).
// flags: bit0 doRhy, bit1 doRlog, bit2 doMel, bit3 doMlog, bit4 doG2h
// ---------------------------------------------------------------------------
__global__ __launch_bounds__(256) void fusedA_k(
    const float* __restrict__ WT0h, const float* __restrict__ hr, float* __restrict__ partR,
    const float* __restrict__ wo0, const float* __restrict__ bo0,
    float* __restrict__ rlo_prev, int* __restrict__ rhy_idx,
    const float* __restrict__ WT1h, const float* __restrict__ ha, float* __restrict__ partM,
    const float* __restrict__ WTo1, const float* __restrict__ hbPrev,
    float* __restrict__ lpart, const float* __restrict__ bo1,
    float* __restrict__ outp, int tout, int* __restrict__ mel_idx,
    int* __restrict__ cnt,
    const float* __restrict__ WTh2, float* __restrict__ partGh, int flags)
{
    __shared__ float smem[8192];             // 32 KB
    int flat = blockIdx.x, tid = threadIdx.x;

    if (flat == 0) {                          // rhythm logits (step u-1)
        if (!(flags & 2)) return;
        int lane = tid & 63, wv = tid >> 6;
        const float* hc = hr + wv * 512 * 64;
        const float* w0 = wo0 + wv * 512;
        const float* w1 = wo0 + Hd + wv * 512;
        const float* w2 = wo0 + 2 * Hd + wv * 512;
        float a0 = 0.f, a1 = 0.f, a2 = 0.f;
#pragma unroll 4
        for (int k = 0; k < 512; k++) {
            float hv = hc[k * 64 + lane];
            a0 = fmaf(hv, w0[k], a0);
            a1 = fmaf(hv, w1[k], a1);
            a2 = fmaf(hv, w2[k], a2);
        }
        smem[(0 * 4 + wv) * 64 + lane] = a0;
        smem[(1 * 4 + wv) * 64 + lane] = a1;
        smem[(2 * 4 + wv) * 64 + lane] = a2;
        __syncthreads();
        if (wv == 0) {
            float l0 = smem[0 * 64 + lane] + smem[1 * 64 + lane] + smem[2 * 64 + lane] + smem[3 * 64 + lane] + bo0[0];
            float l1 = smem[4 * 64 + lane] + smem[5 * 64 + lane] + smem[6 * 64 + lane] + smem[7 * 64 + lane] + bo0[1];
            float l2 = smem[8 * 64 + lane] + smem[9 * 64 + lane] + smem[10 * 64 + lane] + smem[11 * 64 + lane] + bo0[2];
            int am; float mx;
            if (l0 >= l1 && l0 >= l2) { am = 0; mx = l0; }
            else if (l1 >= l2)        { am = 1; mx = l1; }
            else                      { am = 2; mx = l2; }
            float s = expf(l0 - mx) + expf(l1 - mx) + expf(l2 - mx);
            float ls = logf(s);
            rlo_prev[lane * 3 + 0] = l0 - mx - ls;
            rlo_prev[lane * 3 + 1] = l1 - mx - ls;
            rlo_prev[lane * 3 + 2] = l2 - mx - ls;
            rhy_idx[lane] = am;
        }
        return;
    }

    if (flat <= 16) {                         // melody logits (output step u-2)
        if (!(flags & 8)) return;
        int li = flat - 1;                    // 0..15
        int ltile = li & 1, lslot = li >> 1;
        int rg = tid & 15, bg = tid >> 4;
        int r0 = ltile * 128 + rg * 8;
        int b0 = bg * 4;
        int k0 = lslot * 256;

        float acc[8][4];
#pragma unroll
        for (int i = 0; i < 8; i++)
#pragma unroll
            for (int j = 0; j < 4; j++) acc[i][j] = 0.f;

        bool fast = (r0 + 7 < MELn);
        for (int ph = 0; ph < 2; ++ph) {
            int kp = k0 + ph * 128;
            __syncthreads();
            {
                const float4* src = (const float4*)(hbPrev + (size_t)kp * 64);
                float4* dst = (float4*)smem;
#pragma unroll
                for (int i = 0; i < 8; i++) dst[tid + i * 256] = src[tid + i * 256];
            }
            __syncthreads();
            if (fast) {
                const float* wp = WTo1 + (size_t)kp * 132 + r0;
#pragma unroll 4
                for (int k = 0; k < 128; ++k) {
                    float4 xv = *(const float4*)&smem[k * 64 + b0];
                    float w[8];
                    *(float4*)&w[0] = *(const float4*)wp;
                    *(float4*)&w[4] = *(const float4*)(wp + 4);
                    wp += 132;
#pragma unroll
                    for (int i = 0; i < 8; i++) {
                        acc[i][0] = fmaf(w[i], xv.x, acc[i][0]);
                        acc[i][1] = fmaf(w[i], xv.y, acc[i][1]);
                        acc[i][2] = fmaf(w[i], xv.z, acc[i][2]);
                        acc[i][3] = fmaf(w[i], xv.w, acc[i][3]);
                    }
                }
            } else {
                for (int k = 0; k < 128; ++k) {
                    float4 xv = *(const float4*)&smem[k * 64 + b0];
                    const float* wrow = WTo1 + (size_t)(kp + k) * 132;
                    float w[8];
#pragma unroll
                    for (int i = 0; i < 8; i++) {
                        int rc = r0 + i; if (rc > MELn - 1) rc = MELn - 1;
                        w[i] = wrow[rc];
                    }
#pragma unroll
                    for (int i = 0; i < 8; i++) {
                        acc[i][0] = fmaf(w[i], xv.x, acc[i][0]);
                        acc[i][1] = fmaf(w[i], xv.y, acc[i][1]);
                        acc[i][2] = fmaf(w[i], xv.z, acc[i][2]);
                        acc[i][3] = fmaf(w[i], xv.w, acc[i][3]);
                    }
                }
            }
        }
        size_t base = (size_t)lslot * 8320 + b0;
#pragma unroll
        for (int i = 0; i < 8; i++) {
            int prow = ltile * 128 + rg * 8 + i;
            int pc = prow < MELn ? prow : (MELn - 1);
            *(float4*)&lpart[base + (size_t)pc * 64] = *(float4*)acc[i];
        }

        // ---- last-block finalize (fenced), small-LDS 3-pass ----
        __shared__ int lastf;
        __threadfence();
        __syncthreads();
        if (tid == 0) lastf = (atomicAdd(cnt, 1) == 15);
        __syncthreads();
        if (!lastf) return;
        __threadfence();

        int b = tid & 63, q = tid >> 6;
        int rLo = q * 33, rHi = rLo + 33; if (rHi > MELn) rHi = MELn;
        float mx = -1e30f; int am = MELn;
        for (int r = rLo; r < rHi; r++) {
            float v = bo1[r];
#pragma unroll
            for (int s = 0; s < 8; s++) v += lpart[s * 8320 + r * 64 + b];
            lpart[r * 64 + b] = v;
            if (v > mx) { mx = v; am = r; }
        }
        float* qmax = smem;
        int*   qam  = (int*)(smem + 256);
        float* qsum = smem + 512;
        qmax[q * 64 + b] = mx; qam[q * 64 + b] = am;
        __syncthreads();
        float gm = qmax[b]; int ga = qam[b];
#pragma unroll
        for (int qq = 1; qq < 4; qq++) {
            float v = qmax[qq * 64 + b];
            if (v > gm) { gm = v; ga = qam[qq * 64 + b]; }
        }
        float ps = 0.f;
        for (int r = rLo; r < rHi; r++) ps += expf(lpart[r * 64 + b] - gm);
        qsum[q * 64 + b] = ps;
        __syncthreads();
        float ls = logf(qsum[b] + qsum[64 + b] + qsum[128 + b] + qsum[192 + b]);
        if (tid < 64) mel_idx[b] = ga;
        for (int r = rLo; r < rHi; r++)
            outp[(size_t)b * Tn * MELn + tout * MELn + r] = lpart[r * 64 + b] - gm - ls;
        __syncthreads();
        if (tid == 0) *cnt = 0;
        return;
    }

    if (flat < 401) {                         // rhythm GEMM: 48 tiles x 8 slots
        if (!(flags & 1)) return;
        int e = flat - 17;
        int slot = e / 48;
        mmP_body(WT0h, hr, partR + (size_t)slot * 393216, e % 48, slot * 256, 2, smem);
        return;
    }
    if (flat < 785) {                         // melody GRU1 GEMM
        if (!(flags & 4)) return;
        int e = flat - 401;
        int slot = e / 48;
        mmP_body(WT1h, ha, partM + (size_t)slot * 393216, e % 48, slot * 256, 2, smem);
        return;
    }
    {                                         // G2 hh-half: 48 tiles x 4 slots kc=512
        if (!(flags & 16)) return;
        int e = flat - 785;
        int slot = e / 48;
        mmP_body(WTh2, hbPrev, partGh + (size_t)slot * 393216, e % 48, slot * 512, 4, smem);
    }
}

// ---------------------------------------------------------------------------
// mmG_k: standalone GEMM partial dispatch. grid (48, nSlots); kc in {256,512}.
// ---------------------------------------------------------------------------
__global__ __launch_bounds__(256) void mmG_k(
    const float* __restrict__ WT, const float* __restrict__ x,
    float* __restrict__ part, int kc)
{
    __shared__ float xs[8192];
    int slot = blockIdx.y;
    mmP_body(WT, x, part + (size_t)slot * 393216, blockIdx.x, slot * kc, kc >> 7, xs);
}

// ---------------------------------------------------------------------------
// fusedB: rhy_epi(u) [blk 0..511] + mel1_epi(u-1) [blk 512..1023].
// 8-slot reduce: wave wv sums slots {2wv, 2wv+1}.
// flags: bit0 rhy, bit1 mel
// ---------------------------------------------------------------------------
__global__ __launch_bounds__(256) void fusedB_k(
    const float* __restrict__ partR, const float* __restrict__ gi0c,
    const float* __restrict__ w_ih0, const float* __restrict__ b_hh0,
    const float* __restrict__ hr_in, float* __restrict__ hr_out,
    const int* __restrict__ rhy_idx,
    const float* __restrict__ partM, const float* __restrict__ gi1c,
    const float* __restrict__ w_ih1, const float* __restrict__ b_hh1,
    const float* __restrict__ ha_in, float* __restrict__ ha_out,
    const int* __restrict__ mel_idx, const float* __restrict__ rlo,
    const float* __restrict__ cdt, int flags)
{
    __shared__ float red[48 * 68];
    int flat = blockIdx.x, tid = threadIdx.x;
    int wv = tid >> 6, lane = tid & 63;
    int jj = lane >> 4, bq = lane & 15;
    int isMel = (flat >= 512);
    if (isMel) { if (!(flags & 2)) return; }
    else       { if (!(flags & 1)) return; }
    int jbase = (isMel ? flat - 512 : flat) * 4;
    const float* part = isMel ? partM : partR;

    float s0[4], s1[4], s2[4];
#pragma unroll
    for (int q = 0; q < 4; q++) { s0[q] = 0.f; s1[q] = 0.f; s2[q] = 0.f; }
#pragma unroll
    for (int ss = 0; ss < 2; ss++) {
        const float* p = part + (size_t)(wv * 2 + ss) * 393216
                       + (size_t)(jbase + jj) * 64 + bq * 4;
        float4 v0 = *(const float4*)(p);
        float4 v1 = *(const float4*)(p + 2048 * 64);
        float4 v2 = *(const float4*)(p + 4096 * 64);
        s0[0] += v0.x; s0[1] += v0.y; s0[2] += v0.z; s0[3] += v0.w;
        s1[0] += v1.x; s1[1] += v1.y; s1[2] += v1.z; s1[3] += v1.w;
        s2[0] += v2.x; s2[1] += v2.y; s2[2] += v2.z; s2[3] += v2.w;
    }
    int rbase = (wv * 4 + jj) * 3;
    *(float4*)&red[(rbase + 0) * 68 + bq * 4] = make_float4(s0[0], s0[1], s0[2], s0[3]);
    *(float4*)&red[(rbase + 1) * 68 + bq * 4] = make_float4(s1[0], s1[1], s1[2], s1[3]);
    *(float4*)&red[(rbase + 2) * 68 + bq * 4] = make_float4(s2[0], s2[1], s2[2], s2[3]);
    __syncthreads();

    int b = lane, jw = wv;
    int j = jbase + jw;
    float ar = 0.f, az = 0.f, an = 0.f;
#pragma unroll
    for (int ww = 0; ww < 4; ww++) {
        int rb = (ww * 4 + jw) * 3;
        ar += red[(rb + 0) * 68 + b];
        az += red[(rb + 1) * 68 + b];
        an += red[(rb + 2) * 68 + b];
    }

    if (!isMel) {
        int oi = rhy_idx[b];
        float gir = gi0c[j * 64 + b]            + w_ih0[(size_t)j * 131 + oi];
        float giz = gi0c[(j + 2048) * 64 + b]   + w_ih0[(size_t)(j + 2048) * 131 + oi];
        float gin = gi0c[(j + 4096) * 64 + b]   + w_ih0[(size_t)(j + 4096) * 131 + oi];
        float rg = sigf(gir + ar + b_hh0[j]);
        float ug = sigf(giz + az + b_hh0[j + 2048]);
        float ng = tanhf(gin + rg * (an + b_hh0[j + 4096]));
        float hp = hr_in[j * 64 + b];
        hr_out[j * 64 + b] = (1.f - ug) * ng + ug * hp;
    } else {
        int oi = mel_idx[b];
        float r0 = rlo[b * 3 + 0], r1 = rlo[b * 3 + 1], r2 = rlo[b * 3 + 2];
        float cd[12];
#pragma unroll
        for (int q = 0; q < 12; q++) cd[q] = cdt[q * 64 + b];
        float gi[3];
#pragma unroll
        for (int g = 0; g < 3; g++) {
            int row = j + g * 2048;
            const float* wrow = w_ih1 + (size_t)row * 273;
            float v = gi1c[row * 64 + b] + wrow[oi];
            v = fmaf(r0, wrow[130], v);
            v = fmaf(r1, wrow[131], v);
            v = fmaf(r2, wrow[132], v);
#pragma unroll
            for (int q = 0; q < 12; q++) v = fmaf(cd[q], wrow[261 + q], v);
            gi[g] = v;
        }
        float rg = sigf(gi[0] + ar + b_hh1[j]);
        float ug = sigf(gi[1] + az + b_hh1[j + 2048]);
        float ng = tanhf(gi[2] + rg * (an + b_hh1[j + 4096]));
        float hp = ha_in[j * 64 + b];
        ha_out[j * 64 + b] = (1.f - ug) * ng + ug * hp;
    }
}

// ---------------------------------------------------------------------------
// melody GRU2 epilogue: gi from 8-slot buffer (wave sums 2), gh from 4-slot
// buffer (wave reads 1; rows remapped 0..6143 = orig 6144..12287)
// ---------------------------------------------------------------------------
__global__ __launch_bounds__(256) void mel2_epi(
    const float* __restrict__ gi, const float* __restrict__ gh,
    const float* __restrict__ b_ih, const float* __restrict__ b_hh,
    const float* __restrict__ hb_in, float* __restrict__ hb_out)
{
    __shared__ float red[96 * 68];
    int tid = threadIdx.x;
    int wv = tid >> 6, lane = tid & 63;
    int jj = lane >> 4, bq = lane & 15;
    int jbase = blockIdx.x * 4;

    float s[6][4];
#pragma unroll
    for (int g = 0; g < 6; g++)
#pragma unroll
        for (int q = 0; q < 4; q++) s[g][q] = 0.f;
#pragma unroll
    for (int ss = 0; ss < 2; ss++) {
        const float* p = gi + (size_t)(wv * 2 + ss) * 393216
                       + (size_t)(jbase + jj) * 64 + bq * 4;
#pragma unroll
        for (int g = 0; g < 3; g++) {
            float4 v = *(const float4*)(p + (size_t)g * 2048 * 64);
            s[g][0] += v.x; s[g][1] += v.y; s[g][2] += v.z; s[g][3] += v.w;
        }
    }
    {
        const float* p = gh + (size_t)wv * 393216
                       + (size_t)(jbase + jj) * 64 + bq * 4;
#pragma unroll
        for (int g = 0; g < 3; g++) {
            float4 v = *(const float4*)(p + (size_t)g * 2048 * 64);
            s[3 + g][0] = v.x; s[3 + g][1] = v.y; s[3 + g][2] = v.z; s[3 + g][3] = v.w;
        }
    }
    int rbase = (wv * 4 + jj) * 6;
#pragma unroll
    for (int g = 0; g < 6; g++)
        *(float4*)&red[(rbase + g) * 68 + bq * 4] = make_float4(s[g][0], s[g][1], s[g][2], s[g][3]);
    __syncthreads();

    int b = lane, jw = wv;
    int j = jbase + jw;
    float air = 0.f, aiz = 0.f, ain = 0.f, ahr = 0.f, ahz = 0.f, ahn = 0.f;
#pragma unroll
    for (int ww = 0; ww < 4; ww++) {
        int rb = (ww * 4 + jw) * 6;
        air += red[(rb + 0) * 68 + b];
        aiz += red[(rb + 1) * 68 + b];
        ain += red[(rb + 2) * 68 + b];
        ahr += red[(rb + 3) * 68 + b];
        ahz += red[(rb + 4) * 68 + b];
        ahn += red[(rb + 5) * 68 + b];
    }
    float rg = sigf(air + b_ih[j] + ahr + b_hh[j]);
    float ug = sigf(aiz + b_ih[j + 2048] + ahz + b_hh[j + 2048]);
    float ng = tanhf(ain + b_ih[j + 4096] + rg * (ahn + b_hh[j + 4096]));
    float hp = hb_in[j * 64 + b];
    hb_out[j * 64 + b] = (1.f - ug) * ng + ug * hp;
}

// ---------------------------------------------------------------------------
// mm2_k: small logits GEMM (tail for t=31, 16 slots kc=128)
// ---------------------------------------------------------------------------
__global__ __launch_bounds__(256) void mm2_k(
    const float* __restrict__ WTa, const float* __restrict__ xa,
    const float* __restrict__ WTb, const float* __restrict__ xb,
    float* __restrict__ part, int splitTile, int kc, int nrows, int wstride,
    int partStride)
{
    __shared__ float xs[128 * 64];
    int tid = threadIdx.x;
    int tile = blockIdx.x, slot = blockIdx.y;
    const float* WT; const float* x; int tLoc;
    if (tile < splitTile) { WT = WTa; x = xa; tLoc = tile; }
    else                  { WT = WTb; x = xb; tLoc = tile - splitTile; }
    int rg = tid & 15, bg = tid >> 4;
    int r0 = tLoc * 128 + rg * 8;
    int b0 = bg * 4;
    int k0 = slot * kc;

    float acc[8][4];
#pragma unroll
    for (int i = 0; i < 8; i++)
#pragma unroll
        for (int j = 0; j < 4; j++) acc[i][j] = 0.f;

    bool fast = (r0 + 7 < nrows);
    int nPhase = kc >> 7;
    for (int ph = 0; ph < nPhase; ++ph) {
        int kp = k0 + ph * 128;
        __syncthreads();
        {
            const float4* src = (const float4*)(x + (size_t)kp * 64);
            float4* dst = (float4*)xs;
#pragma unroll
            for (int i = 0; i < 8; i++) dst[tid + i * 256] = src[tid + i * 256];
        }
        __syncthreads();
        if (fast) {
            const float* wp = WT + (size_t)kp * wstride + r0;
#pragma unroll 4
            for (int k = 0; k < 128; ++k) {
                float4 xv = *(const float4*)&xs[k * 64 + b0];
                float w[8];
                *(float4*)&w[0] = *(const float4*)wp;
                *(float4*)&w[4] = *(const float4*)(wp + 4);
                wp += wstride;
#pragma unroll
                for (int i = 0; i < 8; i++) {
                    acc[i][0] = fmaf(w[i], xv.x, acc[i][0]);
                    acc[i][1] = fmaf(w[i], xv.y, acc[i][1]);
                    acc[i][2] = fmaf(w[i], xv.z, acc[i][2]);
                    acc[i][3] = fmaf(w[i], xv.w, acc[i][3]);
                }
            }
        } else {
            for (int k = 0; k < 128; ++k) {
                float4 xv = *(const float4*)&xs[k * 64 + b0];
                const float* wrow = WT + (size_t)(kp + k) * wstride;
                float w[8];
#pragma unroll
                for (int i = 0; i < 8; i++) {
                    int rc = r0 + i; if (rc > nrows - 1) rc = nrows - 1;
                    w[i] = wrow[rc];
                }
#pragma unroll
                for (int i = 0; i < 8; i++) {
                    acc[i][0] = fmaf(w[i], xv.x, acc[i][0]);
                    acc[i][1] = fmaf(w[i], xv.y, acc[i][1]);
                    acc[i][2] = fmaf(w[i], xv.z, acc[i][2]);
                    acc[i][3] = fmaf(w[i], xv.w, acc[i][3]);
                }
            }
        }
    }

    size_t base = (size_t)slot * partStride + b0;
#pragma unroll
    for (int i = 0; i < 8; i++) {
        int prow = tile * 128 + rg * 8 + i;
        int pc = prow < nrows ? prow : (nrows - 1);
        if (tile >= splitTile) pc = prow;
        *(float4*)&part[base + (size_t)pc * 64] = *(float4*)acc[i];
    }
}

// ---------------------------------------------------------------------------
// melody softmax (tail for t=31; 16 slots)
// ---------------------------------------------------------------------------
__global__ __launch_bounds__(256) void mel_smax(
    const float* __restrict__ part, const float* __restrict__ bo1,
    float* __restrict__ outp, int t, int* __restrict__ mel_idx)
{
    int b = blockIdx.x, tid = threadIdx.x;
    float v = -1e30f;
    if (tid < MELn) {
        v = bo1[tid];
#pragma unroll
        for (int s = 0; s < 16; s++) v += part[s * 8320 + tid * 64 + b];
    }
    __shared__ float smax[256];
    __shared__ int   sidx[256];
    __shared__ float ssum[256];
    smax[tid] = v; sidx[tid] = tid;
    __syncthreads();
    for (int s = 128; s > 0; s >>= 1) {
        if (tid < s) {
            float a = smax[tid], o = smax[tid + s];
            int ai = sidx[tid], oi = sidx[tid + s];
            if (o > a || (o == a && oi < ai)) { smax[tid] = o; sidx[tid] = oi; }
        }
        __syncthreads();
    }
    float mx = smax[0]; int am = sidx[0];
    ssum[tid] = (tid < MELn) ? expf(v - mx) : 0.f;
    __syncthreads();
    for (int s = 128; s > 0; s >>= 1) {
        if (tid < s) ssum[tid] += ssum[tid + s];
        __syncthreads();
    }
    float ls = logf(ssum[0]);
    if (tid < MELn) outp[(size_t)b * Tn * MELn + t * MELn + tid] = v - mx - ls;
    if (tid == 0) mel_idx[b] = am;
}

// ---------------------------------------------------------------------------
extern "C" void kernel_launch(void* const* d_in, const int* in_sizes, int n_in,
                              void* d_out, int out_size, void* d_ws, size_t ws_size,
                              hipStream_t stream)
{
    (void)in_sizes; (void)n_in; (void)out_size; (void)ws_size;
    const float* z1    = (const float*)d_in[0];
    const float* z2    = (const float*)d_in[1];
    const float* cond  = (const float*)d_in[2];
    const float* w_ih0 = (const float*)d_in[3];
    const float* w_hh0 = (const float*)d_in[4];
    const float* b_ih0 = (const float*)d_in[5];
    const float* b_hh0 = (const float*)d_in[6];
    const float* w_ih1 = (const float*)d_in[7];
    const float* w_hh1 = (const float*)d_in[8];
    const float* b_ih1 = (const float*)d_in[9];
    const float* b_hh1 = (const float*)d_in[10];
    const float* w_ih2 = (const float*)d_in[11];
    const float* w_hh2 = (const float*)d_in[12];
    const float* b_ih2 = (const float*)d_in[13];
    const float* b_hh2 = (const float*)d_in[14];
    const float* wi0   = (const float*)d_in[15];
    const float* bi0   = (const float*)d_in[16];
    const float* wo0   = (const float*)d_in[17];
    const float* bo0   = (const float*)d_in[18];
    const float* wi1   = (const float*)d_in[19];
    const float* bi1   = (const float*)d_in[20];
    const float* wo1   = (const float*)d_in[21];
    const float* bo1   = (const float*)d_in[22];
    float* outp = (float*)d_out;
    float* ws = (float*)d_ws;

    // workspace layout (floats), ~238 MB; live set fits the 256 MB L3
    size_t off = 0;
    float* WT0  = ws + off; off += 12582912;   // w_hh0^T [2048][6144]
    float* WT1  = ws + off; off += 12582912;   // w_hh1^T
    float* WTi2 = ws + off; off += 12582912;   // w_ih2^T
    float* WTh2 = ws + off; off += 12582912;   // w_hh2^T
    float* WTo1 = ws + off; off += 270336;     // wo1^T [2048][132] (padded)
    float* bufR  = ws + off; off += 3145728;   // rhythm partials (8 slots) / G2-gi partials (aliased)
    float* bufM  = ws + off; off += 3145728;   // GRU1 partials (8 slots)
    float* bufGh = ws + off; off += 1572864;   // G2-gh partials (4 slots, rows remapped)
    float* lpart = ws + off; off += 66560;     // inline logits partials (8 slots)
    float* hR[2] = { ws + off, ws + off + 131072 }; off += 262144;
    float* hA[2] = { ws + off, ws + off + 131072 }; off += 262144;
    float* hB[2] = { ws + off, ws + off + 131072 }; off += 262144;
    float* gi0c   = ws + off; off += 393216;
    float* gi1c   = ws + off; off += 393216;
    float* rlo    = ws + off; off += 6144;     // [32][64][3]
    float* cond_t = ws + off; off += 24576;
    float* z1t    = ws + off; off += 8192;
    float* z2t    = ws + off; off += 8192;
    int* rhy_idx  = (int*)(ws + off); off += 64;
    int* mel_idx  = (int*)(ws + off); off += 64;
    int* cnts     = (int*)(ws + off); off += 64;
    float* bufGi = bufR;                       // lifetime-disjoint alias

    // ---- pre-pass ----
    prep_misc<<<96, 256, 0, stream>>>(z1, z2, cond, z1t, z2t, cond_t, rhy_idx, mel_idx, cnts);
    init_h_k<<<dim3(Hd / 4, 2), 256, 0, stream>>>(z1t, z2t, wi0, bi0, wi1, bi1, hR[0], hA[0]);
    gi_const_k<<<dim3(G3 / 4, 2), 256, 0, stream>>>(z1t, z2t, w_ih0, b_ih0, w_ih1, b_ih1, gi0c, gi1c);
    transpose4v_k<<<dim3(32, 96, 4), 256, 0, stream>>>(w_hh0, w_hh1, w_ih2, w_hh2,
                                                       WT0, WT1, WTi2, WTh2);
    transpose1_k<<<dim3(32, 3), 256, 0, stream>>>(wo1, WTo1, MELn, Hd, 132);

    // ---- merged decoder pipeline: iteration u = rhythm step u + melody step u-1 ----
    for (int u = 0; u <= Tn; u++) {
        int doRhy  = (u < Tn) ? 1 : 0;
        int doRlog = (u >= 1) ? 1 : 0;
        int doMel  = (u >= 1) ? 1 : 0;
        int doMlog = (u >= 2) ? 1 : 0;
        int doG2h  = (u >= 2) ? 1 : 0;
        int flagsA = doRhy | (doRlog << 1) | (doMel << 2) | (doMlog << 3) | (doG2h << 4);

        const float* hr = hR[u & 1];
        const float* ha_in = (u >= 1) ? hA[(u - 1) & 1] : hA[0];
        const float* hbPrev = (u >= 2) ? hB[(u - 1) & 1] : hB[0];
        float* rloPrev = rlo + (size_t)(u >= 1 ? u - 1 : 0) * 192;

        fusedA_k<<<977, 256, 0, stream>>>(WT0, hr, bufR, wo0, bo0, rloPrev, rhy_idx,
                                          WT1, ha_in, bufM, WTo1, hbPrev, lpart, bo1,
                                          outp, u - 2, mel_idx, cnts + 0,
                                          WTh2, bufGh, flagsA);

        fusedB_k<<<1024, 256, 0, stream>>>(bufR, gi0c, w_ih0, b_hh0, hr, hR[(u + 1) & 1],
                                           rhy_idx, bufM, gi1c, w_ih1, b_hh1,
                                           ha_in, hA[u & 1], mel_idx, rloPrev,
                                           cond_t + (size_t)(u >= 1 ? u - 1 : 0) * (CHn * Bsz),
                                           doRhy | (doMel << 1));

        if (u >= 1) {
            const float* hbop = (u == 1) ? (const float*)hA[u & 1] : (const float*)hB[(u - 1) & 1];
            if (u == 1)   // hh-half for step 0 needs hA from B(1); can't ride in A(1)
                mmG_k<<<dim3(48, 4), 256, 0, stream>>>(WTh2, hbop, bufGh, 512);
            // ih-half: WTi2 x ha(step u-1 output)
            mmG_k<<<dim3(48, 8), 256, 0, stream>>>(WTi2, hA[u & 1], bufGi, 256);
            mel2_epi<<<512, 256, 0, stream>>>(bufGi, bufGh, b_ih2, b_hh2, hbop, hB[u & 1]);
        }
    }

    // ---- tail: melody logits + softmax for t=31 (hbState(32) = hB[0]) ----
    mm2_k<<<dim3(2, 16), 256, 0, stream>>>(WTo1, hB[0], WTo1, hB[0], bufR,
                                           2, 128, MELn, 132, 8320);
    mel_smax<<<Bsz, 256, 0, stream>>>(bufR, bo1, outp, 31, mel_idx);
}

// Round 9
// 5746.893 us; speedup vs baseline: 1.7828x; 1.0047x over previous
//
#include <hip/hip_runtime.h>
#include <hip/hip_bf16.h>
#include <math.h>

#define Bsz  64
#define Hd   2048
#define G3   6144
#define MELn 130
#define CHn  12
#define RHYn 3
#define Tn   32

typedef float f4v __attribute__((ext_vector_type(4)));  // NT-builtin-compatible float4

__device__ __forceinline__ float sigf(float x) { return 1.0f / (1.0f + expf(-x)); }

// ---------------------------------------------------------------------------
// prep: transpose z1/z2 -> [128][64], condition -> [T][CH][64], init feedback idx
// ---------------------------------------------------------------------------
__global__ void prep_misc(const float* __restrict__ z1, const float* __restrict__ z2,
                          const float* __restrict__ cond,
                          float* __restrict__ z1t, float* __restrict__ z2t,
                          float* __restrict__ cond_t, int* __restrict__ rhy_idx,
                          int* __restrict__ mel_idx, int* __restrict__ cnts)
{
    int idx = blockIdx.x * 256 + threadIdx.x;
    if (idx < 128 * Bsz) {
        int j = idx >> 6, b = idx & 63;
        z1t[idx] = z1[b * 128 + j];
        z2t[idx] = z2[b * 128 + j];
    }
    if (idx < Tn * CHn * Bsz) {
        int t = idx / (CHn * Bsz);
        int r = idx - t * CHn * Bsz;
        int j = r >> 6, b = r & 63;
        cond_t[idx] = cond[b * (Tn * CHn) + t * CHn + j];
    }
    if (idx < Bsz) { rhy_idx[idx] = RHYn - 1; mel_idx[idx] = MELn - 1; }
    if (idx < 4) cnts[idx] = 0;
}

// ---------------------------------------------------------------------------
// h0 = tanh(z2 @ wi0.T + bi0), h1 = tanh(z1 @ wi1.T + bi1); output [j][b]
// ---------------------------------------------------------------------------
__global__ __launch_bounds__(256) void init_h_k(
    const float* __restrict__ z1t, const float* __restrict__ z2t,
    const float* __restrict__ wi0, const float* __restrict__ bi0,
    const float* __restrict__ wi1, const float* __restrict__ bi1,
    float* __restrict__ h0_out, float* __restrict__ h1_out)
{
    int lane = threadIdx.x & 63, wave = threadIdx.x >> 6;
    int j = blockIdx.x * 4 + wave;
    int which = blockIdx.y;
    const float* zt = which ? z1t : z2t;
    const float* wi = which ? wi1 : wi0;
    const float* bi = which ? bi1 : bi0;
    float* outh = which ? h1_out : h0_out;
    const float4* w4 = (const float4*)(wi + (size_t)j * 128);
    float acc = 0.f;
#pragma unroll 8
    for (int i = 0; i < 32; i++) {
        float4 w = w4[i];
        int k = i * 4;
        acc = fmaf(zt[(k + 0) * 64 + lane], w.x, acc);
        acc = fmaf(zt[(k + 1) * 64 + lane], w.y, acc);
        acc = fmaf(zt[(k + 2) * 64 + lane], w.z, acc);
        acc = fmaf(zt[(k + 3) * 64 + lane], w.w, acc);
    }
    outh[j * 64 + lane] = tanhf(acc + bi[j]);
}

// ---------------------------------------------------------------------------
// step-invariant ih parts (z-terms + bias), layout [row][64]
// ---------------------------------------------------------------------------
__global__ __launch_bounds__(256) void gi_const_k(
    const float* __restrict__ z1t, const float* __restrict__ z2t,
    const float* __restrict__ w_ih0, const float* __restrict__ b_ih0,
    const float* __restrict__ w_ih1, const float* __restrict__ b_ih1,
    float* __restrict__ gi0c, float* __restrict__ gi1c)
{
    int lane = threadIdx.x & 63, wave = threadIdx.x >> 6;
    int row = blockIdx.x * 4 + wave;
    int which = blockIdx.y;
    const float* zt; const float* w; float acc; float* dst;
    if (which == 0) { zt = z2t; w = w_ih0 + (size_t)row * 131 + RHYn;          acc = b_ih0[row]; dst = gi0c; }
    else            { zt = z1t; w = w_ih1 + (size_t)row * 273 + (MELn + RHYn); acc = b_ih1[row]; dst = gi1c; }
#pragma unroll 4
    for (int i = 0; i < 128; i++) acc = fmaf(zt[i * 64 + lane], w[i], acc);
    dst[(size_t)row * 64 + lane] = acc;
}

// ---------------------------------------------------------------------------
// vectorized 64x64 transpose for the 4 big [6144][2048] weight matrices
// ---------------------------------------------------------------------------
__global__ __launch_bounds__(256) void transpose4v_k(
    const float* __restrict__ a, const float* __restrict__ b,
    const float* __restrict__ c, const float* __restrict__ d,
    float* __restrict__ oa, float* __restrict__ ob,
    float* __restrict__ oc, float* __restrict__ od)
{
    __shared__ float tile[64 * 65];
    const float* in; float* out;
    switch (blockIdx.z) {
        case 0: in = a; out = oa; break;
        case 1: in = b; out = ob; break;
        case 2: in = c; out = oc; break;
        default: in = d; out = od; break;
    }
    int c0 = blockIdx.x * 64, r0 = blockIdx.y * 64;
    int t = threadIdx.x;
    int rq = t & 15, rw = t >> 4;
#pragma unroll
    for (int i = 0; i < 4; i++) {
        int rl = rw + i * 16;
        float4 v = *(const float4*)&in[(size_t)(r0 + rl) * 2048 + c0 + rq * 4];
        tile[rl * 65 + rq * 4 + 0] = v.x;
        tile[rl * 65 + rq * 4 + 1] = v.y;
        tile[rl * 65 + rq * 4 + 2] = v.z;
        tile[rl * 65 + rq * 4 + 3] = v.w;
    }
    __syncthreads();
#pragma unroll
    for (int i = 0; i < 4; i++) {
        int cl = rw + i * 16;
        int r4 = rq * 4;
        float4 w;
        w.x = tile[(r4 + 0) * 65 + cl];
        w.y = tile[(r4 + 1) * 65 + cl];
        w.z = tile[(r4 + 2) * 65 + cl];
        w.w = tile[(r4 + 3) * 65 + cl];
        *(float4*)&out[(size_t)(c0 + cl) * G3 + r0 + r4] = w;
    }
}

// ---------------------------------------------------------------------------
// scalar transpose (wo1 130x2048 -> [2048][132])
// ---------------------------------------------------------------------------
__global__ __launch_bounds__(256) void transpose1_k(
    const float* __restrict__ in, float* __restrict__ out, int R, int C, int Rout)
{
    __shared__ float tile[64 * 65];
    int c0 = blockIdx.x * 64, r0 = blockIdx.y * 64;
    int t = threadIdx.x;
    int cl = t & 63, rw = t >> 6;
#pragma unroll
    for (int i = 0; i < 16; ++i) {
        int rl = rw + i * 4;
        int r = r0 + rl, c = c0 + cl;
        float v = (r < R && c < C) ? in[(size_t)r * C + c] : 0.f;
        tile[rl * 65 + cl] = v;
    }
    __syncthreads();
#pragma unroll
    for (int i = 0; i < 16; ++i) {
        int c_loc = rw + i * 4;
        int r_loc = cl;
        int oc = c0 + c_loc, orow = r0 + r_loc;
        if (oc < C && orow < R)
            out[(size_t)oc * Rout + orow] = tile[r_loc * 65 + c_loc];
    }
}

// ---------------------------------------------------------------------------
// mmP_body: GEMM partial, 128-row tile x 64 b, nPhase x 128 k, thread 8r x 4b.
// Partial stores are NON-TEMPORAL (evict-first): written once, read once next
// dispatch — keeps the 201 MB weight set resident in the Infinity Cache.
// ---------------------------------------------------------------------------
__device__ __forceinline__ void mmP_body(
    const float* __restrict__ WT, const float* __restrict__ x,
    float* __restrict__ partSlot, int tile, int k0, int nPhase, float* xs)
{
    int tid = threadIdx.x;
    int rg = tid & 15, bg = tid >> 4;
    int r0 = tile * 128 + rg * 8;
    int b0 = bg * 4;

    float acc[8][4];
#pragma unroll
    for (int i = 0; i < 8; i++)
#pragma unroll
        for (int j = 0; j < 4; j++) acc[i][j] = 0.f;

    for (int ph = 0; ph < nPhase; ++ph) {
        int kp = k0 + ph * 128;
        __syncthreads();
        {
            const float4* src = (const float4*)(x + (size_t)kp * 64);
            float4* dst = (float4*)xs;
#pragma unroll
            for (int i = 0; i < 8; i++) dst[tid + i * 256] = src[tid + i * 256];
        }
        __syncthreads();
        const float* wp = WT + (size_t)kp * G3 + r0;
#pragma unroll 4
        for (int k = 0; k < 128; ++k) {
            float4 xv = *(const float4*)&xs[k * 64 + b0];
            float w[8];
            *(float4*)&w[0] = *(const float4*)wp;
            *(float4*)&w[4] = *(const float4*)(wp + 4);
            wp += G3;
#pragma unroll
            for (int i = 0; i < 8; i++) {
                acc[i][0] = fmaf(w[i], xv.x, acc[i][0]);
                acc[i][1] = fmaf(w[i], xv.y, acc[i][1]);
                acc[i][2] = fmaf(w[i], xv.z, acc[i][2]);
                acc[i][3] = fmaf(w[i], xv.w, acc[i][3]);
            }
        }
    }

    int prow0 = tile * 128 + rg * 8;
#pragma unroll
    for (int i = 0; i < 8; i++)
        __builtin_nontemporal_store(*(f4v*)acc[i],
            (f4v*)&partSlot[(size_t)(prow0 + i) * 64 + b0]);
}

// ---------------------------------------------------------------------------
// fusedA: [0] rhythm logits(u-1); [1..16] melody logits(u-2) fenced finalize;
// [17..400] rhythm GEMM (48tx8s); [401..784] GRU1 GEMM (48tx8s);
// [785..976] G2-hh GEMM (48tx4s kc=512, input hbPrev = hB state of step u-2).
// flags: bit0 doRhy, bit1 doRlog, bit2 doMel, bit3 doMlog, bit4 doG2h
// ---------------------------------------------------------------------------
__global__ __launch_bounds__(256) void fusedA_k(
    const float* __restrict__ WT0h, const float* __restrict__ hr, float* __restrict__ partR,
    const float* __restrict__ wo0, const float* __restrict__ bo0,
    float* __restrict__ rlo_prev, int* __restrict__ rhy_idx,
    const float* __restrict__ WT1h, const float* __restrict__ ha, float* __restrict__ partM,
    const float* __restrict__ WTo1, const float* __restrict__ hbPrev,
    float* __restrict__ lpart, const float* __restrict__ bo1,
    float* __restrict__ outp, int tout, int* __restrict__ mel_idx,
    int* __restrict__ cnt,
    const float* __restrict__ WTh2, float* __restrict__ partGh, int flags)
{
    __shared__ float smem[8192];             // 32 KB
    int flat = blockIdx.x, tid = threadIdx.x;

    if (flat == 0) {                          // rhythm logits (step u-1)
        if (!(flags & 2)) return;
        int lane = tid & 63, wv = tid >> 6;
        const float* hc = hr + wv * 512 * 64;
        const float* w0 = wo0 + wv * 512;
        const float* w1 = wo0 + Hd + wv * 512;
        const float* w2 = wo0 + 2 * Hd + wv * 512;
        float a0 = 0.f, a1 = 0.f, a2 = 0.f;
#pragma unroll 4
        for (int k = 0; k < 512; k++) {
            float hv = hc[k * 64 + lane];
            a0 = fmaf(hv, w0[k], a0);
            a1 = fmaf(hv, w1[k], a1);
            a2 = fmaf(hv, w2[k], a2);
        }
        smem[(0 * 4 + wv) * 64 + lane] = a0;
        smem[(1 * 4 + wv) * 64 + lane] = a1;
        smem[(2 * 4 + wv) * 64 + lane] = a2;
        __syncthreads();
        if (wv == 0) {
            float l0 = smem[0 * 64 + lane] + smem[1 * 64 + lane] + smem[2 * 64 + lane] + smem[3 * 64 + lane] + bo0[0];
            float l1 = smem[4 * 64 + lane] + smem[5 * 64 + lane] + smem[6 * 64 + lane] + smem[7 * 64 + lane] + bo0[1];
            float l2 = smem[8 * 64 + lane] + smem[9 * 64 + lane] + smem[10 * 64 + lane] + smem[11 * 64 + lane] + bo0[2];
            int am; float mx;
            if (l0 >= l1 && l0 >= l2) { am = 0; mx = l0; }
            else if (l1 >= l2)        { am = 1; mx = l1; }
            else                      { am = 2; mx = l2; }
            float s = expf(l0 - mx) + expf(l1 - mx) + expf(l2 - mx);
            float ls = logf(s);
            rlo_prev[lane * 3 + 0] = l0 - mx - ls;
            rlo_prev[lane * 3 + 1] = l1 - mx - ls;
            rlo_prev[lane * 3 + 2] = l2 - mx - ls;
            rhy_idx[lane] = am;
        }
        return;
    }

    if (flat <= 16) {                         // melody logits (output step u-2)
        if (!(flags & 8)) return;
        int li = flat - 1;                    // 0..15
        int ltile = li & 1, lslot = li >> 1;
        int rg = tid & 15, bg = tid >> 4;
        int r0 = ltile * 128 + rg * 8;
        int b0 = bg * 4;
        int k0 = lslot * 256;

        float acc[8][4];
#pragma unroll
        for (int i = 0; i < 8; i++)
#pragma unroll
            for (int j = 0; j < 4; j++) acc[i][j] = 0.f;

        bool fast = (r0 + 7 < MELn);
        for (int ph = 0; ph < 2; ++ph) {
            int kp = k0 + ph * 128;
            __syncthreads();
            {
                const float4* src = (const float4*)(hbPrev + (size_t)kp * 64);
                float4* dst = (float4*)smem;
#pragma unroll
                for (int i = 0; i < 8; i++) dst[tid + i * 256] = src[tid + i * 256];
            }
            __syncthreads();
            if (fast) {
                const float* wp = WTo1 + (size_t)kp * 132 + r0;
#pragma unroll 4
                for (int k = 0; k < 128; ++k) {
                    float4 xv = *(const float4*)&smem[k * 64 + b0];
                    float w[8];
                    *(float4*)&w[0] = *(const float4*)wp;
                    *(float4*)&w[4] = *(const float4*)(wp + 4);
                    wp += 132;
#pragma unroll
                    for (int i = 0; i < 8; i++) {
                        acc[i][0] = fmaf(w[i], xv.x, acc[i][0]);
                        acc[i][1] = fmaf(w[i], xv.y, acc[i][1]);
                        acc[i][2] = fmaf(w[i], xv.z, acc[i][2]);
                        acc[i][3] = fmaf(w[i], xv.w, acc[i][3]);
                    }
                }
            } else {
                for (int k = 0; k < 128; ++k) {
                    float4 xv = *(const float4*)&smem[k * 64 + b0];
                    const float* wrow = WTo1 + (size_t)(kp + k) * 132;
                    float w[8];
#pragma unroll
                    for (int i = 0; i < 8; i++) {
                        int rc = r0 + i; if (rc > MELn - 1) rc = MELn - 1;
                        w[i] = wrow[rc];
                    }
#pragma unroll
                    for (int i = 0; i < 8; i++) {
                        acc[i][0] = fmaf(w[i], xv.x, acc[i][0]);
                        acc[i][1] = fmaf(w[i], xv.y, acc[i][1]);
                        acc[i][2] = fmaf(w[i], xv.z, acc[i][2]);
                        acc[i][3] = fmaf(w[i], xv.w, acc[i][3]);
                    }
                }
            }
        }
        size_t base = (size_t)lslot * 8320 + b0;
#pragma unroll
        for (int i = 0; i < 8; i++) {
            int prow = ltile * 128 + rg * 8 + i;
            int pc = prow < MELn ? prow : (MELn - 1);
            *(float4*)&lpart[base + (size_t)pc * 64] = *(float4*)acc[i];
        }

        // ---- last-block finalize (fenced), small-LDS 3-pass ----
        __shared__ int lastf;
        __threadfence();
        __syncthreads();
        if (tid == 0) lastf = (atomicAdd(cnt, 1) == 15);
        __syncthreads();
        if (!lastf) return;
        __threadfence();

        int b = tid & 63, q = tid >> 6;
        int rLo = q * 33, rHi = rLo + 33; if (rHi > MELn) rHi = MELn;
        float mx = -1e30f; int am = MELn;
        for (int r = rLo; r < rHi; r++) {
            float v = bo1[r];
#pragma unroll
            for (int s = 0; s < 8; s++) v += lpart[s * 8320 + r * 64 + b];
            lpart[r * 64 + b] = v;
            if (v > mx) { mx = v; am = r; }
        }
        float* qmax = smem;
        int*   qam  = (int*)(smem + 256);
        float* qsum = smem + 512;
        qmax[q * 64 + b] = mx; qam[q * 64 + b] = am;
        __syncthreads();
        float gm = qmax[b]; int ga = qam[b];
#pragma unroll
        for (int qq = 1; qq < 4; qq++) {
            float v = qmax[qq * 64 + b];
            if (v > gm) { gm = v; ga = qam[qq * 64 + b]; }
        }
        float ps = 0.f;
        for (int r = rLo; r < rHi; r++) ps += expf(lpart[r * 64 + b] - gm);
        qsum[q * 64 + b] = ps;
        __syncthreads();
        float ls = logf(qsum[b] + qsum[64 + b] + qsum[128 + b] + qsum[192 + b]);
        if (tid < 64) mel_idx[b] = ga;
        for (int r = rLo; r < rHi; r++)
            outp[(size_t)b * Tn * MELn + tout * MELn + r] = lpart[r * 64 + b] - gm - ls;
        __syncthreads();
        if (tid == 0) *cnt = 0;
        return;
    }

    if (flat < 401) {                         // rhythm GEMM: 48 tiles x 8 slots
        if (!(flags & 1)) return;
        int e = flat - 17;
        int slot = e / 48;
        mmP_body(WT0h, hr, partR + (size_t)slot * 393216, e % 48, slot * 256, 2, smem);
        return;
    }
    if (flat < 785) {                         // melody GRU1 GEMM
        if (!(flags & 4)) return;
        int e = flat - 401;
        int slot = e / 48;
        mmP_body(WT1h, ha, partM + (size_t)slot * 393216, e % 48, slot * 256, 2, smem);
        return;
    }
    {                                         // G2 hh-half: 48 tiles x 4 slots kc=512
        if (!(flags & 16)) return;
        int e = flat - 785;
        int slot = e / 48;
        mmP_body(WTh2, hbPrev, partGh + (size_t)slot * 393216, e % 48, slot * 512, 4, smem);
    }
}

// ---------------------------------------------------------------------------
// mmG_k: standalone GEMM partial dispatch. grid (48, nSlots); kc in {256,512}.
// ---------------------------------------------------------------------------
__global__ __launch_bounds__(256) void mmG_k(
    const float* __restrict__ WT, const float* __restrict__ x,
    float* __restrict__ part, int kc)
{
    __shared__ float xs[8192];
    int slot = blockIdx.y;
    mmP_body(WT, x, part + (size_t)slot * 393216, blockIdx.x, slot * kc, kc >> 7, xs);
}

// ---------------------------------------------------------------------------
// fusedB: rhy_epi(u) [blk 0..511] + mel1_epi(u-1) [blk 512..1023].
// 8-slot reduce: wave wv sums slots {2wv, 2wv+1}. Partial reads NON-TEMPORAL.
// flags: bit0 rhy, bit1 mel
// ---------------------------------------------------------------------------
__global__ __launch_bounds__(256) void fusedB_k(
    const float* __restrict__ partR, const float* __restrict__ gi0c,
    const float* __restrict__ w_ih0, const float* __restrict__ b_hh0,
    const float* __restrict__ hr_in, float* __restrict__ hr_out,
    const int* __restrict__ rhy_idx,
    const float* __restrict__ partM, const float* __restrict__ gi1c,
    const float* __restrict__ w_ih1, const float* __restrict__ b_hh1,
    const float* __restrict__ ha_in, float* __restrict__ ha_out,
    const int* __restrict__ mel_idx, const float* __restrict__ rlo,
    const float* __restrict__ cdt, int flags)
{
    __shared__ float red[48 * 68];
    int flat = blockIdx.x, tid = threadIdx.x;
    int wv = tid >> 6, lane = tid & 63;
    int jj = lane >> 4, bq = lane & 15;
    int isMel = (flat >= 512);
    if (isMel) { if (!(flags & 2)) return; }
    else       { if (!(flags & 1)) return; }
    int jbase = (isMel ? flat - 512 : flat) * 4;
    const float* part = isMel ? partM : partR;

    float s0[4], s1[4], s2[4];
#pragma unroll
    for (int q = 0; q < 4; q++) { s0[q] = 0.f; s1[q] = 0.f; s2[q] = 0.f; }
#pragma unroll
    for (int ss = 0; ss < 2; ss++) {
        const float* p = part + (size_t)(wv * 2 + ss) * 393216
                       + (size_t)(jbase + jj) * 64 + bq * 4;
        f4v v0 = __builtin_nontemporal_load((const f4v*)(p));
        f4v v1 = __builtin_nontemporal_load((const f4v*)(p + 2048 * 64));
        f4v v2 = __builtin_nontemporal_load((const f4v*)(p + 4096 * 64));
        s0[0] += v0.x; s0[1] += v0.y; s0[2] += v0.z; s0[3] += v0.w;
        s1[0] += v1.x; s1[1] += v1.y; s1[2] += v1.z; s1[3] += v1.w;
        s2[0] += v2.x; s2[1] += v2.y; s2[2] += v2.z; s2[3] += v2.w;
    }
    int rbase = (wv * 4 + jj) * 3;
    *(float4*)&red[(rbase + 0) * 68 + bq * 4] = make_float4(s0[0], s0[1], s0[2], s0[3]);
    *(float4*)&red[(rbase + 1) * 68 + bq * 4] = make_float4(s1[0], s1[1], s1[2], s1[3]);
    *(float4*)&red[(rbase + 2) * 68 + bq * 4] = make_float4(s2[0], s2[1], s2[2], s2[3]);
    __syncthreads();

    int b = lane, jw = wv;
    int j = jbase + jw;
    float ar = 0.f, az = 0.f, an = 0.f;
#pragma unroll
    for (int ww = 0; ww < 4; ww++) {
        int rb = (ww * 4 + jw) * 3;
        ar += red[(rb + 0) * 68 + b];
        az += red[(rb + 1) * 68 + b];
        an += red[(rb + 2) * 68 + b];
    }

    if (!isMel) {
        int oi = rhy_idx[b];
        float gir = gi0c[j * 64 + b]            + w_ih0[(size_t)j * 131 + oi];
        float giz = gi0c[(j + 2048) * 64 + b]   + w_ih0[(size_t)(j + 2048) * 131 + oi];
        float gin = gi0c[(j + 4096) * 64 + b]   + w_ih0[(size_t)(j + 4096) * 131 + oi];
        float rg = sigf(gir + ar + b_hh0[j]);
        float ug = sigf(giz + az + b_hh0[j + 2048]);
        float ng = tanhf(gin + rg * (an + b_hh0[j + 4096]));
        float hp = hr_in[j * 64 + b];
        hr_out[j * 64 + b] = (1.f - ug) * ng + ug * hp;
    } else {
        int oi = mel_idx[b];
        float r0 = rlo[b * 3 + 0], r1 = rlo[b * 3 + 1], r2 = rlo[b * 3 + 2];
        float cd[12];
#pragma unroll
        for (int q = 0; q < 12; q++) cd[q] = cdt[q * 64 + b];
        float gi[3];
#pragma unroll
        for (int g = 0; g < 3; g++) {
            int row = j + g * 2048;
            const float* wrow = w_ih1 + (size_t)row * 273;
            float v = gi1c[row * 64 + b] + wrow[oi];
            v = fmaf(r0, wrow[130], v);
            v = fmaf(r1, wrow[131], v);
            v = fmaf(r2, wrow[132], v);
#pragma unroll
            for (int q = 0; q < 12; q++) v = fmaf(cd[q], wrow[261 + q], v);
            gi[g] = v;
        }
        float rg = sigf(gi[0] + ar + b_hh1[j]);
        float ug = sigf(gi[1] + az + b_hh1[j + 2048]);
        float ng = tanhf(gi[2] + rg * (an + b_hh1[j + 4096]));
        float hp = ha_in[j * 64 + b];
        ha_out[j * 64 + b] = (1.f - ug) * ng + ug * hp;
    }
}

// ---------------------------------------------------------------------------
// melody GRU2 epilogue: gi from 8-slot buffer (wave sums 2), gh from 4-slot
// buffer (wave reads 1; rows remapped). Partial reads NON-TEMPORAL.
// ---------------------------------------------------------------------------
__global__ __launch_bounds__(256) void mel2_epi(
    const float* __restrict__ gi, const float* __restrict__ gh,
    const float* __restrict__ b_ih, const float* __restrict__ b_hh,
    const float* __restrict__ hb_in, float* __restrict__ hb_out)
{
    __shared__ float red[96 * 68];
    int tid = threadIdx.x;
    int wv = tid >> 6, lane = tid & 63;
    int jj = lane >> 4, bq = lane & 15;
    int jbase = blockIdx.x * 4;

    float s[6][4];
#pragma unroll
    for (int g = 0; g < 6; g++)
#pragma unroll
        for (int q = 0; q < 4; q++) s[g][q] = 0.f;
#pragma unroll
    for (int ss = 0; ss < 2; ss++) {
        const float* p = gi + (size_t)(wv * 2 + ss) * 393216
                       + (size_t)(jbase + jj) * 64 + bq * 4;
#pragma unroll
        for (int g = 0; g < 3; g++) {
            f4v v = __builtin_nontemporal_load((const f4v*)(p + (size_t)g * 2048 * 64));
            s[g][0] += v.x; s[g][1] += v.y; s[g][2] += v.z; s[g][3] += v.w;
        }
    }
    {
        const float* p = gh + (size_t)wv * 393216
                       + (size_t)(jbase + jj) * 64 + bq * 4;
#pragma unroll
        for (int g = 0; g < 3; g++) {
            f4v v = __builtin_nontemporal_load((const f4v*)(p + (size_t)g * 2048 * 64));
            s[3 + g][0] = v.x; s[3 + g][1] = v.y; s[3 + g][2] = v.z; s[3 + g][3] = v.w;
        }
    }
    int rbase = (wv * 4 + jj) * 6;
#pragma unroll
    for (int g = 0; g < 6; g++)
        *(float4*)&red[(rbase + g) * 68 + bq * 4] = make_float4(s[g][0], s[g][1], s[g][2], s[g][3]);
    __syncthreads();

    int b = lane, jw = wv;
    int j = jbase + jw;
    float air = 0.f, aiz = 0.f, ain = 0.f, ahr = 0.f, ahz = 0.f, ahn = 0.f;
#pragma unroll
    for (int ww = 0; ww < 4; ww++) {
        int rb = (ww * 4 + jw) * 6;
        air += red[(rb + 0) * 68 + b];
        aiz += red[(rb + 1) * 68 + b];
        ain += red[(rb + 2) * 68 + b];
        ahr += red[(rb + 3) * 68 + b];
        ahz += red[(rb + 4) * 68 + b];
        ahn += red[(rb + 5) * 68 + b];
    }
    float rg = sigf(air + b_ih[j] + ahr + b_hh[j]);
    float ug = sigf(aiz + b_ih[j + 2048] + ahz + b_hh[j + 2048]);
    float ng = tanhf(ain + b_ih[j + 4096] + rg * (ahn + b_hh[j + 4096]));
    float hp = hb_in[j * 64 + b];
    hb_out[j * 64 + b] = (1.f - ug) * ng + ug * hp;
}

// ---------------------------------------------------------------------------
// mm2_k: small logits GEMM (tail for t=31, 16 slots kc=128)
// ---------------------------------------------------------------------------
__global__ __launch_bounds__(256) void mm2_k(
    const float* __restrict__ WTa, const float* __restrict__ xa,
    const float* __restrict__ WTb, const float* __restrict__ xb,
    float* __restrict__ part, int splitTile, int kc, int nrows, int wstride,
    int partStride)
{
    __shared__ float xs[128 * 64];
    int tid = threadIdx.x;
    int tile = blockIdx.x, slot = blockIdx.y;
    const float* WT; const float* x; int tLoc;
    if (tile < splitTile) { WT = WTa; x = xa; tLoc = tile; }
    else                  { WT = WTb; x = xb; tLoc = tile - splitTile; }
    int rg = tid & 15, bg = tid >> 4;
    int r0 = tLoc * 128 + rg * 8;
    int b0 = bg * 4;
    int k0 = slot * kc;

    float acc[8][4];
#pragma unroll
    for (int i = 0; i < 8; i++)
#pragma unroll
        for (int j = 0; j < 4; j++) acc[i][j] = 0.f;

    bool fast = (r0 + 7 < nrows);
    int nPhase = kc >> 7;
    for (int ph = 0; ph < nPhase; ++ph) {
        int kp = k0 + ph * 128;
        __syncthreads();
        {
            const float4* src = (const float4*)(x + (size_t)kp * 64);
            float4* dst = (float4*)xs;
#pragma unroll
            for (int i = 0; i < 8; i++) dst[tid + i * 256] = src[tid + i * 256];
        }
        __syncthreads();
        if (fast) {
            const float* wp = WT + (size_t)kp * wstride + r0;
#pragma unroll 4
            for (int k = 0; k < 128; ++k) {
                float4 xv = *(const float4*)&xs[k * 64 + b0];
                float w[8];
                *(float4*)&w[0] = *(const float4*)wp;
                *(float4*)&w[4] = *(const float4*)(wp + 4);
                wp += wstride;
#pragma unroll
                for (int i = 0; i < 8; i++) {
                    acc[i][0] = fmaf(w[i], xv.x, acc[i][0]);
                    acc[i][1] = fmaf(w[i], xv.y, acc[i][1]);
                    acc[i][2] = fmaf(w[i], xv.z, acc[i][2]);
                    acc[i][3] = fmaf(w[i], xv.w, acc[i][3]);
                }
            }
        } else {
            for (int k = 0; k < 128; ++k) {
                float4 xv = *(const float4*)&xs[k * 64 + b0];
                const float* wrow = WT + (size_t)(kp + k) * wstride;
                float w[8];
#pragma unroll
                for (int i = 0; i < 8; i++) {
                    int rc = r0 + i; if (rc > nrows - 1) rc = nrows - 1;
                    w[i] = wrow[rc];
                }
#pragma unroll
                for (int i = 0; i < 8; i++) {
                    acc[i][0] = fmaf(w[i], xv.x, acc[i][0]);
                    acc[i][1] = fmaf(w[i], xv.y, acc[i][1]);
                    acc[i][2] = fmaf(w[i], xv.z, acc[i][2]);
                    acc[i][3] = fmaf(w[i], xv.w, acc[i][3]);
                }
            }
        }
    }

    size_t base = (size_t)slot * partStride + b0;
#pragma unroll
    for (int i = 0; i < 8; i++) {
        int prow = tile * 128 + rg * 8 + i;
        int pc = prow < nrows ? prow : (nrows - 1);
        if (tile >= splitTile) pc = prow;
        *(float4*)&part[base + (size_t)pc * 64] = *(float4*)acc[i];
    }
}

// ---------------------------------------------------------------------------
// melody softmax (tail for t=31; 16 slots)
// ---------------------------------------------------------------------------
__global__ __launch_bounds__(256) void mel_smax(
    const float* __restrict__ part, const float* __restrict__ bo1,
    float* __restrict__ outp, int t, int* __restrict__ mel_idx)
{
    int b = blockIdx.x, tid = threadIdx.x;
    float v = -1e30f;
    if (tid < MELn) {
        v = bo1[tid];
#pragma unroll
        for (int s = 0; s < 16; s++) v += part[s * 8320 + tid * 64 + b];
    }
    __shared__ float smax[256];
    __shared__ int   sidx[256];
    __shared__ float ssum[256];
    smax[tid] = v; sidx[tid] = tid;
    __syncthreads();
    for (int s = 128; s > 0; s >>= 1) {
        if (tid < s) {
            float a = smax[tid], o = smax[tid + s];
            int ai = sidx[tid], oi = sidx[tid + s];
            if (o > a || (o == a && oi < ai)) { smax[tid] = o; sidx[tid] = oi; }
        }
        __syncthreads();
    }
    float mx = smax[0]; int am = sidx[0];
    ssum[tid] = (tid < MELn) ? expf(v - mx) : 0.f;
    __syncthreads();
    for (int s = 128; s > 0; s >>= 1) {
        if (tid < s) ssum[tid] += ssum[tid + s];
        __syncthreads();
    }
    float ls = logf(ssum[0]);
    if (tid < MELn) outp[(size_t)b * Tn * MELn + t * MELn + tid] = v - mx - ls;
    if (tid == 0) mel_idx[b] = am;
}

// ---------------------------------------------------------------------------
extern "C" void kernel_launch(void* const* d_in, const int* in_sizes, int n_in,
                              void* d_out, int out_size, void* d_ws, size_t ws_size,
                              hipStream_t stream)
{
    (void)in_sizes; (void)n_in; (void)out_size; (void)ws_size;
    const float* z1    = (const float*)d_in[0];
    const float* z2    = (const float*)d_in[1];
    const float* cond  = (const float*)d_in[2];
    const float* w_ih0 = (const float*)d_in[3];
    const float* w_hh0 = (const float*)d_in[4];
    const float* b_ih0 = (const float*)d_in[5];
    const float* b_hh0 = (const float*)d_in[6];
    const float* w_ih1 = (const float*)d_in[7];
    const float* w_hh1 = (const float*)d_in[8];
    const float* b_ih1 = (const float*)d_in[9];
    const float* b_hh1 = (const float*)d_in[10];
    const float* w_ih2 = (const float*)d_in[11];
    const float* w_hh2 = (const float*)d_in[12];
    const float* b_ih2 = (const float*)d_in[13];
    const float* b_hh2 = (const float*)d_in[14];
    const float* wi0   = (const float*)d_in[15];
    const float* bi0   = (const float*)d_in[16];
    const float* wo0   = (const float*)d_in[17];
    const float* bo0   = (const float*)d_in[18];
    const float* wi1   = (const float*)d_in[19];
    const float* bi1   = (const float*)d_in[20];
    const float* wo1   = (const float*)d_in[21];
    const float* bo1   = (const float*)d_in[22];
    float* outp = (float*)d_out;
    float* ws = (float*)d_ws;

    // workspace layout (floats), ~238 MB; weights stay L3-resident (NT partials)
    size_t off = 0;
    float* WT0  = ws + off; off += 12582912;   // w_hh0^T [2048][6144]
    float* WT1  = ws + off; off += 12582912;   // w_hh1^T
    float* WTi2 = ws + off; off += 12582912;   // w_ih2^T
    float* WTh2 = ws + off; off += 12582912;   // w_hh2^T
    float* WTo1 = ws + off; off += 270336;     // wo1^T [2048][132] (padded)
    float* bufR  = ws + off; off += 3145728;   // rhythm partials (8 slots) / G2-gi partials (aliased)
    float* bufM  = ws + off; off += 3145728;   // GRU1 partials (8 slots)
    float* bufGh = ws + off; off += 1572864;   // G2-gh partials (4 slots, rows remapped)
    float* lpart = ws + off; off += 66560;     // inline logits partials (8 slots)
    float* hR[2] = { ws + off, ws + off + 131072 }; off += 262144;
    float* hA[2] = { ws + off, ws + off + 131072 }; off += 262144;
    float* hB[2] = { ws + off, ws + off + 131072 }; off += 262144;
    float* gi0c   = ws + off; off += 393216;
    float* gi1c   = ws + off; off += 393216;
    float* rlo    = ws + off; off += 6144;     // [32][64][3]
    float* cond_t = ws + off; off += 24576;
    float* z1t    = ws + off; off += 8192;
    float* z2t    = ws + off; off += 8192;
    int* rhy_idx  = (int*)(ws + off); off += 64;
    int* mel_idx  = (int*)(ws + off); off += 64;
    int* cnts     = (int*)(ws + off); off += 64;
    float* bufGi = bufR;                       // lifetime-disjoint alias

    // ---- pre-pass ----
    prep_misc<<<96, 256, 0, stream>>>(z1, z2, cond, z1t, z2t, cond_t, rhy_idx, mel_idx, cnts);
    init_h_k<<<dim3(Hd / 4, 2), 256, 0, stream>>>(z1t, z2t, wi0, bi0, wi1, bi1, hR[0], hA[0]);
    gi_const_k<<<dim3(G3 / 4, 2), 256, 0, stream>>>(z1t, z2t, w_ih0, b_ih0, w_ih1, b_ih1, gi0c, gi1c);
    transpose4v_k<<<dim3(32, 96, 4), 256, 0, stream>>>(w_hh0, w_hh1, w_ih2, w_hh2,
                                                       WT0, WT1, WTi2, WTh2);
    transpose1_k<<<dim3(32, 3), 256, 0, stream>>>(wo1, WTo1, MELn, Hd, 132);

    // ---- merged decoder pipeline: iteration u = rhythm step u + melody step u-1 ----
    for (int u = 0; u <= Tn; u++) {
        int doRhy  = (u < Tn) ? 1 : 0;
        int doRlog = (u >= 1) ? 1 : 0;
        int doMel  = (u >= 1) ? 1 : 0;
        int doMlog = (u >= 2) ? 1 : 0;
        int doG2h  = (u >= 2) ? 1 : 0;
        int flagsA = doRhy | (doRlog << 1) | (doMel << 2) | (doMlog << 3) | (doG2h << 4);

        const float* hr = hR[u & 1];
        const float* ha_in = (u >= 1) ? hA[(u - 1) & 1] : hA[0];
        const float* hbPrev = (u >= 2) ? hB[(u - 1) & 1] : hB[0];
        float* rloPrev = rlo + (size_t)(u >= 1 ? u - 1 : 0) * 192;

        fusedA_k<<<977, 256, 0, stream>>>(WT0, hr, bufR, wo0, bo0, rloPrev, rhy_idx,
                                          WT1, ha_in, bufM, WTo1, hbPrev, lpart, bo1,
                                          outp, u - 2, mel_idx, cnts + 0,
                                          WTh2, bufGh, flagsA);

        fusedB_k<<<1024, 256, 0, stream>>>(bufR, gi0c, w_ih0, b_hh0, hr, hR[(u + 1) & 1],
                                           rhy_idx, bufM, gi1c, w_ih1, b_hh1,
                                           ha_in, hA[u & 1], mel_idx, rloPrev,
                                           cond_t + (size_t)(u >= 1 ? u - 1 : 0) * (CHn * Bsz),
                                           doRhy | (doMel << 1));

        if (u >= 1) {
            const float* hbop = (u == 1) ? (const float*)hA[u & 1] : (const float*)hB[(u - 1) & 1];
            if (u == 1)   // hh-half for step 0 needs hA from B(1); can't ride in A(1)
                mmG_k<<<dim3(48, 4), 256, 0, stream>>>(WTh2, hbop, bufGh, 512);
            // ih-half: WTi2 x ha(step u-1 output)
            mmG_k<<<dim3(48, 8), 256, 0, stream>>>(WTi2, hA[u & 1], bufGi, 256);
            mel2_epi<<<512, 256, 0, stream>>>(bufGi, bufGh, b_ih2, b_hh2, hbop, hB[u & 1]);
        }
    }

    // ---- tail: melody logits + softmax for t=31 (hbState(32) = hB[0]) ----
    mm2_k<<<dim3(2, 16), 256, 0, stream>>>(WTo1, hB[0], WTo1, hB[0], bufR,
                                           2, 128, MELn, 132, 8320);
    mel_smax<<<Bsz, 256, 0, stream>>>(bufR, bo1, outp, 31, mel_idx);
}